// Round 6
// baseline (720.594 us; speedup 1.0000x reference)
//
#include <hip/hip_runtime.h>
#include <hip/hip_bf16.h>

#define NP 100000
#define NL 10000
#define ND 500
#define H 128
#define HH (H * H)
#define E1 2000000
#define E2 500000
#define NOUT 10
#define NCNT (NL + ND + 2 * NP)
#define NROW (NL + ND)
#define CHUNK 16384
#define LABHB ((E1 + CHUNK - 1) / CHUNK)
#define DISHB ((E2 + CHUNK - 1) / CHUNK)
#define CNT_BLOCKS ((E1 + E2 + 255) / 256)
#define EMBP ((NP * H + 255) / 256)
#define RED_LAB ((NL + 255) / 256)
#define RED_DIS ((ND + 255) / 256)
#define PAT_BLOCKS (NP / 16)

// patient-side chunked LDS histogram sort (replaces global atomics)
#define CHP 62500
#define NCH1 (E1 / CHP) /* 32 */
#define NCH2 (E2 / CHP) /* 8 */
#define NPW (NP / 4)    /* 25000 packed-byte words = 100 KB LDS */
#define RPW ((NPW + 255) / 256)

typedef __hip_bfloat16 bf16;
typedef __attribute__((ext_vector_type(8))) short bf16x8;
typedef __attribute__((ext_vector_type(4))) float f32x4;

__device__ __forceinline__ float bfbits2f(unsigned short s) {
    union { unsigned int u; float f; } v;
    v.u = (unsigned int)s << 16;
    return v.f;
}
__device__ __forceinline__ float2 ld_bf2(const bf16* p) {
    unsigned int u = *(const unsigned int*)p;
    return make_float2(bfbits2f((unsigned short)(u & 0xFFFFu)), bfbits2f((unsigned short)(u >> 16)));
}
__device__ __forceinline__ float2 ld_bf2_nt(const bf16* p) {
    unsigned int u = __builtin_nontemporal_load((const unsigned int*)p);
    return make_float2(bfbits2f((unsigned short)(u & 0xFFFFu)), bfbits2f((unsigned short)(u >> 16)));
}
__device__ __forceinline__ void st_bf2(bf16* p, float2 v) {
    union { unsigned int u; bf16 b[2]; } t;
    t.b[0] = __float2bfloat16(v.x);
    t.b[1] = __float2bfloat16(v.y);
    *(unsigned int*)p = t.u;
}
__device__ __forceinline__ float ldin(const void* p, size_t i, int f32m) {
    return f32m ? ((const float*)p)[i] : __bfloat162float(((const bf16*)p)[i]);
}
// accumulate 2 packed bf16 (one u32) into two f32 accumulators: 2 unpack + 2 add VALU
__device__ __forceinline__ void bfacc2(float& x, float& y, unsigned int u) {
    union { unsigned int q; float f; } lo, hi;
    lo.q = u << 16;
    hi.q = u & 0xFFFF0000u;
    x += lo.f;
    y += hi.f;
}

// ---------------- input dtype detection ----------------
__global__ void k_detect(const unsigned short* __restrict__ xp, int* __restrict__ flags) {
    int t = threadIdx.x;
    int cnt = 0;
    for (int i = t; i < 4096; i += 256) {
        unsigned short w = xp[2 * i];
        int e = (w >> 7) & 0xFF;
        if (w == 0 || (e >= 114 && e <= 141)) cnt++;
    }
    __shared__ int sh[256];
    sh[t] = cnt;
    __syncthreads();
    for (int s = 128; s > 0; s >>= 1) {
        if (t < s) sh[t] += sh[t + s];
        __syncthreads();
    }
    if (t == 0) flags[0] = (sh[0] < 2048) ? 1 : 0;
}

// ---- k_hist: all histograms via LDS (no global atomics), 1024 threads -----------------
#define HB0 NCH1
#define HB1 (HB0 + NCH2)
#define HB2 (HB1 + LABHB)
#define HB3 (HB2 + DISHB)
__global__ void k_hist(const int* __restrict__ e1s, const int* __restrict__ e1d,
                       const int* __restrict__ e2s, const int* __restrict__ e2d,
                       unsigned int* __restrict__ labHistP, unsigned int* __restrict__ disHistP,
                       unsigned char* __restrict__ r1s, unsigned char* __restrict__ r2s,
                       unsigned int* __restrict__ labHist, unsigned int* __restrict__ disHist) {
    __shared__ unsigned int sh[NPW];  // 100 KB: byte-packed patient counters / reused by dest hists
    int b = blockIdx.x, t = threadIdx.x;
    if (b < HB1) {
        for (int i = t; i < NPW; i += 1024) sh[i] = 0;
        __syncthreads();
        if (b < HB0) {
            int e0 = b * CHP;
            for (int j = t; j < CHP; j += 1024) {
                int e = e0 + j;
                int ss = __builtin_nontemporal_load(&e1s[e]);
                unsigned int old = atomicAdd(&sh[ss >> 2], 1u << (8 * (ss & 3)));
                r1s[e] = (unsigned char)(old >> (8 * (ss & 3)));
            }
            __syncthreads();
            unsigned int* out = labHistP + (size_t)b * NPW;
            for (int i = t; i < NPW; i += 1024) out[i] = sh[i];
        } else {
            int c = b - HB0;
            int e0 = c * CHP;
            for (int j = t; j < CHP; j += 1024) {
                int e = e0 + j;
                int ss = __builtin_nontemporal_load(&e2s[e]);
                unsigned int old = atomicAdd(&sh[ss >> 2], 1u << (8 * (ss & 3)));
                r2s[e] = (unsigned char)(old >> (8 * (ss & 3)));
            }
            __syncthreads();
            unsigned int* out = disHistP + (size_t)c * NPW;
            for (int i = t; i < NPW; i += 1024) out[i] = sh[i];
        }
    } else if (b < HB2) {
        int c = b - HB1;
        for (int i = t; i < NL / 2; i += 1024) sh[i] = 0;
        __syncthreads();
        int e0 = c * CHUNK, ee = min(E1, e0 + CHUNK);
        for (int e = e0 + t; e < ee; e += 1024) {
            int dd = __builtin_nontemporal_load(&e1d[e]);
            atomicAdd(&sh[dd >> 1], 1u << (16 * (dd & 1)));
        }
        __syncthreads();
        for (int i = t; i < NL; i += 1024)
            labHist[(size_t)c * NL + i] = (sh[i >> 1] >> (16 * (i & 1))) & 0xFFFFu;
    } else {
        int c = b - HB2;
        for (int i = t; i < ND / 2; i += 1024) sh[i] = 0;
        __syncthreads();
        int e0 = c * CHUNK, ee = min(E2, e0 + CHUNK);
        for (int e = e0 + t; e < ee; e += 1024) {
            int dd = __builtin_nontemporal_load(&e2d[e]);
            atomicAdd(&sh[dd >> 1], 1u << (16 * (dd & 1)));
        }
        __syncthreads();
        for (int i = t; i < ND; i += 1024)
            disHist[(size_t)c * ND + i] = (sh[i >> 1] >> (16 * (i & 1))) & 0xFFFFu;
    }
}

// ---- reduce: chunk exclusive bases (packed-byte scan for patients); totals -> cnt ------
#define RB0 RED_LAB
#define RB1 (RB0 + RED_DIS)
#define RB2 (RB1 + RPW)
#define RB3 (RB2 + RPW)
#define RB4 (RB3 + EMBP)
#define RB5 (RB4 + 16)
#define RB6 (RB5 + 7)
#define RB7 (RB6 + 64)
__global__ void k_reduce(unsigned int* __restrict__ labHist, unsigned int* __restrict__ disHist,
                         unsigned int* __restrict__ labHistP, unsigned int* __restrict__ disHistP,
                         int* __restrict__ cnt, const void* __restrict__ xp,
                         const void* __restrict__ Wp, const void* __restrict__ bp,
                         const void* __restrict__ Wlab, const void* __restrict__ blab,
                         const void* __restrict__ Wdis, const void* __restrict__ bdis,
                         const void* __restrict__ Wl1, const void* __restrict__ bl1,
                         const void* __restrict__ Wr1, bf16* __restrict__ hp,
                         float* __restrict__ WpWl0, float* __restrict__ WpWl1,
                         float* __restrict__ vecs, bf16* __restrict__ w23bT1,
                         const int* __restrict__ flags) {
    int b = blockIdx.x, t = threadIdx.x;
    if (b < RB0) {
        int bin = b * 256 + t;
        if (bin < NL) {
            unsigned int run = 0;
            for (int k = 0; k < LABHB; ++k) {
                unsigned int x = labHist[(size_t)k * NL + bin];
                labHist[(size_t)k * NL + bin] = run;
                run += x;
            }
            cnt[bin] = (int)run;
        }
    } else if (b < RB1) {
        int bin = (b - RB0) * 256 + t;
        if (bin < ND) {
            unsigned int run = 0;
            for (int k = 0; k < DISHB; ++k) {
                unsigned int x = disHist[(size_t)k * ND + bin];
                disHist[(size_t)k * ND + bin] = run;
                run += x;
            }
            cnt[NL + bin] = (int)run;
        }
    } else if (b < RB2) {
        int w = (b - RB1) * 256 + t;
        if (w < NPW) {
            unsigned int run = 0;  // 4 byte-lanes scanned in parallel; degree < 256 so no carry
            for (int c = 0; c < NCH1; ++c) {
                unsigned int x = labHistP[(size_t)c * NPW + w];
                labHistP[(size_t)c * NPW + w] = run;
                run += x;
            }
            int base = NL + ND + 4 * w;
            cnt[base] = (int)(run & 0xFFu);
            cnt[base + 1] = (int)((run >> 8) & 0xFFu);
            cnt[base + 2] = (int)((run >> 16) & 0xFFu);
            cnt[base + 3] = (int)(run >> 24);
        }
    } else if (b < RB3) {
        int w = (b - RB2) * 256 + t;
        if (w < NPW) {
            unsigned int run = 0;
            for (int c = 0; c < NCH2; ++c) {
                unsigned int x = disHistP[(size_t)c * NPW + w];
                disHistP[(size_t)c * NPW + w] = run;
                run += x;
            }
            int base = NL + ND + NP + 4 * w;
            cnt[base] = (int)(run & 0xFFu);
            cnt[base + 1] = (int)((run >> 8) & 0xFFu);
            cnt[base + 2] = (int)((run >> 16) & 0xFFu);
            cnt[base + 3] = (int)(run >> 24);
        }
    } else if (b < RB4) {
        int f32m = flags[0];
        int idx = (b - RB3) * 256 + t;
        int h = idx & 127;
        int i = idx >> 7;
        float acc = ldin(bp, h, f32m);
#pragma unroll
        for (int k = 0; k < 16; ++k)
            acc = fmaf(ldin(xp, (size_t)i * 16 + k, f32m), ldin(Wp, (size_t)k * H + h, f32m), acc);
        hp[idx] = __float2bfloat16(acc);
    } else if (b < RB5) {
        int f32m = flags[0];
        int pb = b - RB4;
        bool first = pb < 8;
        size_t woff = first ? 0 : (size_t)HH;
        float* outp = first ? WpWl0 : WpWl1;
        int k = (first ? pb : pb - 8) * 2 + (t >> 7);
        int h = t & 127;
        float s = 0.f;
        for (int m = 0; m < H; ++m)
            s = fmaf(ldin(Wp, (size_t)k * H + m, f32m), ldin(Wl1, woff + (size_t)m * H + h, f32m), s);
        outp[k * H + h] = s;
    } else if (b < RB6) {
        int f32m = flags[0];
        int idx = (b - RB5) * 256 + t;
        if (idx < 13 * 128) {
            int v = idx >> 7, h = idx & 127;
            float s = 0.f;
            if (v == 12) {
                s = ldin(bl1, 2 * H + h, f32m) + ldin(bl1, 3 * H + h, f32m);
            } else {
                const void* A;
                size_t aoff = 0;
                const void* W;
                size_t woff;
                float add = 0.f;
                switch (v) {
                    case 0: A = Wlab; W = Wl1; woff = 2 * (size_t)HH; break;
                    case 1: A = blab; W = Wl1; woff = 2 * (size_t)HH; break;
                    case 2: A = Wdis; W = Wl1; woff = 3 * (size_t)HH; break;
                    case 3: A = Wdis; aoff = H; W = Wl1; woff = 3 * (size_t)HH; break;
                    case 4: A = bdis; W = Wl1; woff = 3 * (size_t)HH; break;
                    case 5: A = Wlab; W = Wr1; woff = 0; break;
                    case 6: A = blab; W = Wr1; woff = 0; add = ldin(bl1, h, f32m); break;
                    case 7: A = Wdis; W = Wr1; woff = (size_t)HH; break;
                    case 8: A = Wdis; aoff = H; W = Wr1; woff = (size_t)HH; break;
                    case 9: A = bdis; W = Wr1; woff = (size_t)HH; add = ldin(bl1, H + h, f32m); break;
                    case 10: A = bp; W = Wl1; woff = 0; break;
                    default: A = bp; W = Wl1; woff = (size_t)HH; break;
                }
                for (int m = 0; m < H; ++m)
                    s = fmaf(ldin(A, aoff + m, f32m), ldin(W, woff + (size_t)m * H + h, f32m), s);
                s += add;
            }
            vecs[v * 128 + h] = s;
        }
    } else {
        int f32m = flags[0];
        int idx = (b - RB6) * 256 + t;
        if (idx < HH) {
            int k = idx >> 7, n = idx & 127;
            float v = ldin(Wr1, (size_t)2 * HH + idx, f32m) + ldin(Wr1, (size_t)3 * HH + idx, f32m);
            w23bT1[(size_t)n * H + k] = __float2bfloat16(v);
        }
    }
}

#define SCAN_ELEMS 2048
__global__ void k_scan1(const int* __restrict__ in, int* __restrict__ out,
                        int* __restrict__ bsums, int n) {
    int t = threadIdx.x;
    int base = blockIdx.x * SCAN_ELEMS + t * 8;
    int v[8], tsum = 0;
#pragma unroll
    for (int j = 0; j < 8; ++j) {
        v[j] = (base + j < n) ? in[base + j] : 0;
        tsum += v[j];
    }
    __shared__ int sh[256];
    sh[t] = tsum;
    __syncthreads();
    for (int d = 1; d < 256; d <<= 1) {
        int x = (t >= d) ? sh[t - d] : 0;
        __syncthreads();
        sh[t] += x;
        __syncthreads();
    }
    int run = sh[t] - tsum;
    if (t == 255) bsums[blockIdx.x] = sh[255];
#pragma unroll
    for (int j = 0; j < 8; ++j) {
        if (base + j < n) out[base + j] = run;
        run += v[j];
    }
}

__global__ void k_scan2(int* __restrict__ bsums, int nb) {
    int t = threadIdx.x;
    int v = (t < nb) ? bsums[t] : 0;
    __shared__ int sh[256];
    sh[t] = v;
    __syncthreads();
    for (int d = 1; d < 256; d <<= 1) {
        int x = (t >= d) ? sh[t - d] : 0;
        __syncthreads();
        sh[t] += x;
        __syncthreads();
    }
    if (t < nb) bsums[t] = sh[t] - v;
}

__global__ void k_scan3(int* __restrict__ out, const int* __restrict__ bsums, int n) {
    int i = blockIdx.x * 256 + threadIdx.x;
    if (i < n) out[i] += bsums[i / SCAN_ELEMS];
}

// ---- fill (+ last block zeros bns: 8 segments) ----------------------------------------
// Scattered nbr writes are non-temporal: avoids L2 RFO ping-pong (each 64B line is
// written ~20x from different blocks); edge streams are NT loads (read-once).
__global__ void k_fill(const int* __restrict__ e1s, const int* __restrict__ e1d,
                       const int* __restrict__ e2s, const int* __restrict__ e2d,
                       const int* __restrict__ off, const unsigned char* __restrict__ r1s,
                       const unsigned char* __restrict__ r2s,
                       const unsigned char* __restrict__ labBase,
                       const unsigned char* __restrict__ disBase,
                       const unsigned int* __restrict__ labHist,
                       const unsigned int* __restrict__ disHist, int* __restrict__ nbr,
                       float* __restrict__ bns) {
    __shared__ unsigned int slot[NL];
    int b = blockIdx.x, t = threadIdx.x;
    if (b < CNT_BLOCKS) {
        int e = b * 256 + t;
        if (e < E1) {
            int ss = __builtin_nontemporal_load(&e1s[e]);
            int dd = __builtin_nontemporal_load(&e1d[e]);
            int c = e / CHP;
            int pos = off[NL + ND + ss] + (int)labBase[(size_t)c * NP + ss] + (int)r1s[e];
            __builtin_nontemporal_store(dd, &nbr[pos]);
        } else if (e < E1 + E2) {
            int i = e - E1;
            int ss = __builtin_nontemporal_load(&e2s[i]);
            int dd = __builtin_nontemporal_load(&e2d[i]);
            int c = i / CHP;
            int pos = off[NL + ND + NP + ss] + (int)disBase[(size_t)c * NP + ss] + (int)r2s[i];
            __builtin_nontemporal_store(dd, &nbr[pos]);
        }
    } else if (b < CNT_BLOCKS + LABHB) {
        int c = b - CNT_BLOCKS;
        for (int i = t; i < NL; i += 256)
            slot[i] = (unsigned int)off[i] + labHist[(size_t)c * NL + i];
        __syncthreads();
        int e0 = c * CHUNK, ee = min(E1, e0 + CHUNK);
        for (int e = e0 + t; e < ee; e += 256) {
            int dd = __builtin_nontemporal_load(&e1d[e]);
            int ss = __builtin_nontemporal_load(&e1s[e]);
            unsigned int pos = atomicAdd(&slot[dd], 1u);
            __builtin_nontemporal_store(ss, &nbr[pos]);
        }
    } else if (b < CNT_BLOCKS + LABHB + DISHB) {
        int c = b - CNT_BLOCKS - LABHB;
        for (int i = t; i < ND; i += 256)
            slot[i] = (unsigned int)off[NL + i] + disHist[(size_t)c * ND + i];
        __syncthreads();
        int e0 = c * CHUNK, ee = min(E2, e0 + CHUNK);
        for (int e = e0 + t; e < ee; e += 256) {
            int dd = __builtin_nontemporal_load(&e2d[e]);
            int ss = __builtin_nontemporal_load(&e2s[e]);
            unsigned int pos = atomicAdd(&slot[dd], 1u);
            __builtin_nontemporal_store(ss, &nbr[pos]);
        }
    } else {
        for (int i = t; i < 8 * H; i += 256) bns[i] = 0.f;
    }
}

// ---------------- L1 stage1: gather 16-dim mean of x_p per lab/dis row ------------------
// Lane-per-neighbor: each lane loads a full 16-dim patient row (32 B bf16 / 64 B f32),
// giving 64-128 gathers in flight per wave instead of 4. Block LDS reduce at the end.
__global__ void k_stage1_L1(const void* __restrict__ xp, const int* __restrict__ off,
                            const int* __restrict__ cnt, const int* __restrict__ nbr,
                            float* __restrict__ mxp, const int* __restrict__ flags) {
    __shared__ float red[4][64][16];  // 16 KB
    int f32m = flags[0];
    int t = threadIdx.x;
    int w = t >> 6, lane = t & 63;
    int row = blockIdx.x * 4 + w;
    float acc[16];
#pragma unroll
    for (int d = 0; d < 16; ++d) acc[d] = 0.f;
    if (row < NROW) {
        int s0 = off[row], c = cnt[row];
        const int* nb = nbr + s0;
        if (f32m) {
            const float* xpf = (const float*)xp;
            int j = lane;
            for (; j + 64 < c; j += 128) {
                int p0 = nb[j], p1 = nb[j + 64];
                const float4* r0 = (const float4*)(xpf + (size_t)p0 * 16);
                const float4* r1 = (const float4*)(xpf + (size_t)p1 * 16);
                float4 a = r0[0], b2 = r0[1], cc = r0[2], dd = r0[3];
                float4 e = r1[0], f = r1[1], g = r1[2], h2 = r1[3];
                acc[0] += a.x + e.x;  acc[1] += a.y + e.y;  acc[2] += a.z + e.z;  acc[3] += a.w + e.w;
                acc[4] += b2.x + f.x; acc[5] += b2.y + f.y; acc[6] += b2.z + f.z; acc[7] += b2.w + f.w;
                acc[8] += cc.x + g.x; acc[9] += cc.y + g.y; acc[10] += cc.z + g.z; acc[11] += cc.w + g.w;
                acc[12] += dd.x + h2.x; acc[13] += dd.y + h2.y; acc[14] += dd.z + h2.z; acc[15] += dd.w + h2.w;
            }
            if (j < c) {
                const float4* r0 = (const float4*)(xpf + (size_t)nb[j] * 16);
                float4 a = r0[0], b2 = r0[1], cc = r0[2], dd = r0[3];
                acc[0] += a.x;  acc[1] += a.y;  acc[2] += a.z;  acc[3] += a.w;
                acc[4] += b2.x; acc[5] += b2.y; acc[6] += b2.z; acc[7] += b2.w;
                acc[8] += cc.x; acc[9] += cc.y; acc[10] += cc.z; acc[11] += cc.w;
                acc[12] += dd.x; acc[13] += dd.y; acc[14] += dd.z; acc[15] += dd.w;
            }
        } else {
            const bf16* xpb = (const bf16*)xp;
            int j = lane;
            for (; j + 64 < c; j += 128) {
                int p0 = nb[j], p1 = nb[j + 64];
                const uint4* r0 = (const uint4*)(xpb + (size_t)p0 * 16);
                const uint4* r1 = (const uint4*)(xpb + (size_t)p1 * 16);
                uint4 u0 = r0[0], u1 = r0[1];
                uint4 v0 = r1[0], v1 = r1[1];
                bfacc2(acc[0], acc[1], u0.x);   bfacc2(acc[2], acc[3], u0.y);
                bfacc2(acc[4], acc[5], u0.z);   bfacc2(acc[6], acc[7], u0.w);
                bfacc2(acc[8], acc[9], u1.x);   bfacc2(acc[10], acc[11], u1.y);
                bfacc2(acc[12], acc[13], u1.z); bfacc2(acc[14], acc[15], u1.w);
                bfacc2(acc[0], acc[1], v0.x);   bfacc2(acc[2], acc[3], v0.y);
                bfacc2(acc[4], acc[5], v0.z);   bfacc2(acc[6], acc[7], v0.w);
                bfacc2(acc[8], acc[9], v1.x);   bfacc2(acc[10], acc[11], v1.y);
                bfacc2(acc[12], acc[13], v1.z); bfacc2(acc[14], acc[15], v1.w);
            }
            if (j < c) {
                const uint4* r0 = (const uint4*)(xpb + (size_t)nb[j] * 16);
                uint4 u0 = r0[0], u1 = r0[1];
                bfacc2(acc[0], acc[1], u0.x);   bfacc2(acc[2], acc[3], u0.y);
                bfacc2(acc[4], acc[5], u0.z);   bfacc2(acc[6], acc[7], u0.w);
                bfacc2(acc[8], acc[9], u1.x);   bfacc2(acc[10], acc[11], u1.y);
                bfacc2(acc[12], acc[13], u1.z); bfacc2(acc[14], acc[15], u1.w);
            }
        }
    }
#pragma unroll
    for (int d = 0; d < 16; ++d) red[w][lane][d] = acc[d];
    __syncthreads();
    if (t < 64) {
        int w2 = t >> 4, d = t & 15;
        int row2 = blockIdx.x * 4 + w2;
        if (row2 < NROW) {
            float s = 0.f;
#pragma unroll 8
            for (int l = 0; l < 64; ++l) s += red[w2][l][d];
            mxp[(size_t)row2 * 16 + d] = s / fmaxf((float)cnt[row2], 1.f);
        }
    }
}

// -------- L1 patmm: scalar gathers + MFMA | lab/dis affine | per-block stats ------------
#define LD1_BLOCKS ((NROW + 1) / 2)
#define HPAD 136
#define APAD 132
__global__ void k_patmm_L1(const bf16* __restrict__ hp, const void* __restrict__ xl,
                           const void* __restrict__ xd, const int* __restrict__ off,
                           const int* __restrict__ cnt, const int* __restrict__ nbr,
                           const bf16* __restrict__ w23bT1, const float* __restrict__ vecs,
                           const float* __restrict__ WpWl0, const float* __restrict__ WpWl1,
                           const float* __restrict__ mxp, bf16* __restrict__ aggp,
                           float* __restrict__ bufL, float* __restrict__ bufD,
                           float* __restrict__ blocksums, const int* __restrict__ flags) {
    int t = threadIdx.x;
    int f32m = flags[0];
    if (blockIdx.x < PAT_BLOCKS) {
        __shared__ bf16 hpA[16][HPAD];
        __shared__ float accf[16][APAD];
        __shared__ float svec[6][128];
        __shared__ float s_mxl[16], s_onL[16], s_d0[16], s_d1[16], s_onD[16];
        int w = t >> 6, lane = t & 63;
        int p0 = blockIdx.x * 16;
        {
            const unsigned int* hpu = (const unsigned int*)(hp + (size_t)p0 * H);
            for (int i = t; i < 16 * 64; i += 256) {
                int r = i >> 6, c = i & 63;
                *(unsigned int*)&hpA[r][2 * c] = hpu[(size_t)r * 64 + c];
            }
        }
        {
            const int map[6] = {0, 1, 2, 3, 4, 12};
            for (int i = t; i < 6 * 128; i += 256)
                svec[i >> 7][i & 127] = vecs[map[i >> 7] * 128 + (i & 127)];
        }
        {
            int g = t >> 4, sl = t & 15;
            int p = p0 + g;
            int s1 = off[NL + ND + p], c1 = cnt[NL + ND + p];
            float a = 0.f;
            for (int j = sl; j < c1; j += 16) a += ldin(xl, nbr[s1 + j], f32m);
            a += __shfl_xor(a, 1);
            a += __shfl_xor(a, 2);
            a += __shfl_xor(a, 4);
            a += __shfl_xor(a, 8);
            int s2 = off[NL + ND + NP + p], c2 = cnt[NL + ND + NP + p];
            float d0 = 0.f, d1 = 0.f;
            for (int j = sl; j < c2; j += 16) {
                int q = nbr[s2 + j];
                d0 += ldin(xd, (size_t)2 * q, f32m);
                d1 += ldin(xd, (size_t)2 * q + 1, f32m);
            }
            d0 += __shfl_xor(d0, 1); d0 += __shfl_xor(d0, 2);
            d0 += __shfl_xor(d0, 4); d0 += __shfl_xor(d0, 8);
            d1 += __shfl_xor(d1, 1); d1 += __shfl_xor(d1, 2);
            d1 += __shfl_xor(d1, 4); d1 += __shfl_xor(d1, 8);
            if (sl == 0) {
                s_mxl[g] = a / fmaxf((float)c1, 1.f);
                s_onL[g] = (c1 > 0) ? 1.f : 0.f;
                s_d0[g] = d0 / fmaxf((float)c2, 1.f);
                s_d1[g] = d1 / fmaxf((float)c2, 1.f);
                s_onD[g] = (c2 > 0) ? 1.f : 0.f;
            }
        }
        __syncthreads();
        {
            int m = lane & 15, kg = lane >> 4;
            bf16x8 afr[4];
#pragma unroll
            for (int ks = 0; ks < 4; ++ks)
                afr[ks] = *(const bf16x8*)&hpA[m][ks * 32 + kg * 8];
            int n0 = w * 32;
#pragma unroll
            for (int tt = 0; tt < 2; ++tt) {
                int nc = n0 + tt * 16 + m;
                f32x4 acc = {0.f, 0.f, 0.f, 0.f};
#pragma unroll
                for (int ks = 0; ks < 4; ++ks) {
                    bf16x8 bfr = *(const bf16x8*)&w23bT1[(size_t)nc * H + ks * 32 + kg * 8];
                    acc = __builtin_amdgcn_mfma_f32_16x16x32_bf16(afr[ks], bfr, acc, 0, 0, 0);
                }
#pragma unroll
                for (int rg = 0; rg < 4; ++rg)
                    accf[kg * 4 + rg][nc] = acc[rg];
            }
        }
        __syncthreads();
        for (int i = t; i < 16 * 64; i += 256) {
            int r = i >> 6, cc = (i & 63) * 2;
            float l0 = s_onL[r] * fmaf(s_mxl[r], svec[0][cc], svec[1][cc]);
            float l1 = s_onL[r] * fmaf(s_mxl[r], svec[0][cc + 1], svec[1][cc + 1]);
            float q0 = s_onD[r] * (s_d0[r] * svec[2][cc] + s_d1[r] * svec[3][cc] + svec[4][cc]);
            float q1 = s_onD[r] * (s_d0[r] * svec[2][cc + 1] + s_d1[r] * svec[3][cc + 1] + svec[4][cc + 1]);
            float v0 = accf[r][cc] + l0 + q0 + svec[5][cc];
            float v1 = accf[r][cc + 1] + l1 + q1 + svec[5][cc + 1];
            accf[r][cc] = v0;
            accf[r][cc + 1] = v1;
            st_bf2(aggp + (size_t)(p0 + r) * H + cc, make_float2(v0, v1));
        }
        __syncthreads();
        if (t < 128) {
            float s = 0.f, q = 0.f;
#pragma unroll
            for (int r = 0; r < 16; ++r) {
                float v = accf[r][t];
                s += v;
                q = fmaf(v, v, q);
            }
            blocksums[(size_t)blockIdx.x * 256 + t] = s;
            blocksums[(size_t)blockIdx.x * 256 + 128 + t] = q;
        }
    } else {
        int bb = blockIdx.x - PAT_BLOCKS;
        int rr = bb * 2 + (t >> 7);
        int h = t & 127;
        if (rr >= NROW) return;
        if (rr < NL) {
            float acc = vecs[6 * 128 + h] + ldin(xl, rr, f32m) * vecs[5 * 128 + h];
            if (cnt[rr] > 0) {
                float s = vecs[10 * 128 + h];
                const float* mx = mxp + (size_t)rr * 16;
#pragma unroll
                for (int k = 0; k < 16; ++k) s = fmaf(mx[k], WpWl0[k * H + h], s);
                acc += s;
            }
            bufL[(size_t)rr * H + h] = acc;
        } else {
            int rd = rr - NL;
            float acc = vecs[9 * 128 + h] + ldin(xd, (size_t)2 * rd, f32m) * vecs[7 * 128 + h] +
                        ldin(xd, (size_t)2 * rd + 1, f32m) * vecs[8 * 128 + h];
            if (cnt[rr] > 0) {
                float s = vecs[11 * 128 + h];
                const float* mx = mxp + (size_t)rr * 16;
#pragma unroll
                for (int k = 0; k < 16; ++k) s = fmaf(mx[k], WpWl1[k * H + h], s);
                acc += s;
            }
            bufD[(size_t)rd * H + h] = acc;
        }
    }
}

// -------- bnred: patient stats from blocksums (+ lab/dis stats when grid>64) -----------
__global__ void k_bnred(const float* __restrict__ blocksums, const float* __restrict__ bufL,
                        const float* __restrict__ bufD, float* __restrict__ sums) {
    int b = blockIdx.x, t = threadIdx.x;
    if (b < 64) {
        float acc = 0.f;
        for (int r = b; r < PAT_BLOCKS; r += 64) acc += blocksums[(size_t)r * 256 + t];
        atomicAdd(&sums[t], acc);
        return;
    }
    int h = t & 127;
    int sub = t >> 7;
    float s = 0.f, s2 = 0.f;
    float* sm;
    if (b < 320) {
        int bid = b - 64;
        for (int i = bid * 2 + sub; i < NL; i += 512) {
            float v = bufL[(size_t)i * H + h];
            s += v;
            s2 = fmaf(v, v, s2);
        }
        sm = sums + 2 * H;
    } else {
        int bid = b - 320;
        for (int i = bid * 2 + sub; i < ND; i += 128) {
            float v = bufD[(size_t)i * H + h];
            s += v;
            s2 = fmaf(v, v, s2);
        }
        sm = sums + 4 * H;
    }
    __shared__ float ls[256], ls2[256];
    ls[t] = s;
    ls2[t] = s2;
    __syncthreads();
    if (sub == 0) {
        atomicAdd(&sm[h], s + ls[128 + h]);
        atomicAdd(&sm[H + h], s2 + ls2[128 + h]);
    }
}

// ---- L2 stage1: mm_small (L1 lab/dis BN inline) + prep23 + head-W1 precompute ----------
#define S2_MM 1313
#define S2_PREP 64
#define S2_TOTAL (S2_MM + S2_PREP)
__global__ void k_stage1_L2(const float* __restrict__ bufL, const float* __restrict__ bufD,
                            const float* __restrict__ bns, const void* __restrict__ bng1,
                            const void* __restrict__ bnb1, const void* __restrict__ Wl,
                            bf16* __restrict__ tlp, bf16* __restrict__ tdp,
                            const void* __restrict__ Wr, const void* __restrict__ bl,
                            bf16* __restrict__ w23bT, float* __restrict__ b23,
                            const void* __restrict__ W1in, bf16* __restrict__ w1T,
                            const int* __restrict__ flags) {
    __shared__ float smm[8][H];
    int b = blockIdx.x, t = threadIdx.x;
    int f32m = flags[0];
    if (b < S2_MM) {
        int bb = b;
        bool lab = bb < 1250;
        const float* buf = lab ? bufL : bufD;
        int N = lab ? NL : ND;
        float invN = lab ? 1.f / NL : 1.f / ND;
        int so = lab ? 2 * H : 4 * H;
        int go = lab ? H : 2 * H;
        bf16* outp = lab ? tlp : tdp;
        size_t woff = lab ? (size_t)2 * HH : (size_t)3 * HH;
        int r0 = (lab ? bb : bb - 1250) * 8;
        int h = t & 127, half = t >> 7;
        float m = bns[so + h] * invN;
        float v = fmaf(-m, m, bns[so + H + h] * invN);
        float sc = rsqrtf(v + 1e-5f) * ldin(bng1, go + h, f32m);
        float be = ldin(bnb1, go + h, f32m);
        for (int r = half; r < 8; r += 2) {
            int ri = r0 + r;
            float x = (ri < N) ? buf[(size_t)ri * H + h] : 0.f;
            smm[r][h] = (ri < N) ? fmaxf(fmaf(x - m, sc, be), 0.f) : 0.f;
        }
        __syncthreads();
        int rb = half * 4;
        float a0 = 0.f, a1 = 0.f, a2 = 0.f, a3 = 0.f;
        for (int k = 0; k < H; ++k) {
            float wv = ldin(Wl, woff + (size_t)k * H + h, f32m);
            a0 = fmaf(smm[rb + 0][k], wv, a0);
            a1 = fmaf(smm[rb + 1][k], wv, a1);
            a2 = fmaf(smm[rb + 2][k], wv, a2);
            a3 = fmaf(smm[rb + 3][k], wv, a3);
        }
        float acc[4] = {a0, a1, a2, a3};
#pragma unroll
        for (int r = 0; r < 4; ++r)
            if (r0 + rb + r < N)
                outp[(size_t)(r0 + rb + r) * H + h] = __float2bfloat16(acc[r]);
    } else {
        int pb = b - S2_MM;
        int idx = pb * 256 + t;
        if (idx < HH) {
            int k = idx >> 7, n = idx & 127;
            float v = ldin(Wr, (size_t)2 * HH + idx, f32m) + ldin(Wr, (size_t)3 * HH + idx, f32m);
            w23bT[(size_t)n * H + k] = __float2bfloat16(v);
        }
        if (idx < H)
            b23[idx] = ldin(bl, (size_t)2 * H + idx, f32m) + ldin(bl, (size_t)3 * H + idx, f32m);
        if (idx < 64 * H) {  // head FC1 weight, transposed to [n][k] bf16 for MFMA B-operand
            int n = idx >> 7, k = idx & 127;
            w1T[idx] = __float2bfloat16(ldin(W1in, (size_t)k * 64 + n, f32m));
        }
    }
}

// -------- L2 patmm: in-place aggp update (L1 pat BN inline) + per-block stats -----------
// Gather: half-wave (32 lanes) per patient row, 8 B (4 cols) per lane, unroll x4.
// aggp staging read is non-temporal (read-once; keeps tlp/tdp L2-resident).
__global__ void k_patmm_L2(bf16* __restrict__ aggp, const bf16* __restrict__ tlp,
                           const bf16* __restrict__ tdp, const int* __restrict__ off,
                           const int* __restrict__ cnt, const int* __restrict__ nbr,
                           const bf16* __restrict__ w23bT, const float* __restrict__ b23,
                           const float* __restrict__ bns, const void* __restrict__ bng1,
                           const void* __restrict__ bnb1, float* __restrict__ blocksums,
                           const int* __restrict__ flags) {
    __shared__ bf16 hpA[16][HPAD];
    __shared__ __align__(16) float accf[16][APAD];
    int t = threadIdx.x;
    int f32m = flags[0];
    int w = t >> 6, lane = t & 63;
    int p0 = blockIdx.x * 16;
    {
        int cc = (t & 63) * 2;
        const float invN = 1.f / NP;
        float m0 = bns[cc] * invN, m1 = bns[cc + 1] * invN;
        float v0 = fmaf(-m0, m0, bns[128 + cc] * invN);
        float v1 = fmaf(-m1, m1, bns[128 + cc + 1] * invN);
        float sc0 = rsqrtf(v0 + 1e-5f) * ldin(bng1, cc, f32m);
        float sc1 = rsqrtf(v1 + 1e-5f) * ldin(bng1, cc + 1, f32m);
        float be0 = ldin(bnb1, cc, f32m), be1 = ldin(bnb1, cc + 1, f32m);
        for (int i = t; i < 16 * 64; i += 256) {
            int r = i >> 6;
            float2 v = ld_bf2_nt(aggp + (size_t)(p0 + r) * H + cc);
            st_bf2(&hpA[r][cc], make_float2(fmaxf(fmaf(v.x - m0, sc0, be0), 0.f),
                                            fmaxf(fmaf(v.y - m1, sc1, be1), 0.f)));
        }
    }
    {
        const int* off1 = off + NL + ND;
        const int* cnt1 = cnt + NL + ND;
        const int* off2 = off + NL + ND + NP;
        const int* cnt2 = cnt + NL + ND + NP;
        int hw = t >> 5, hl = t & 31;  // 8 half-waves; each owns 2 patients
        int cb = hl * 4;               // this lane's 4 columns
        float4 bbv = *(const float4*)(b23 + cb);
#pragma unroll
        for (int rp = 0; rp < 2; ++rp) {
            int p = p0 + hw * 2 + rp;
            int s1 = off1[p], c1 = cnt1[p];
            const int* nb1 = nbr + s1;
            float a0 = 0.f, a1 = 0.f, a2 = 0.f, a3 = 0.f;
            float g0 = 0.f, g1 = 0.f, g2 = 0.f, g3 = 0.f;
            int j = 0;
            for (; j + 4 <= c1; j += 4) {
                int i0 = nb1[j], i1 = nb1[j + 1], i2 = nb1[j + 2], i3 = nb1[j + 3];
                uint2 v0 = *(const uint2*)(tlp + (size_t)i0 * H + cb);
                uint2 v1 = *(const uint2*)(tlp + (size_t)i1 * H + cb);
                uint2 v2 = *(const uint2*)(tlp + (size_t)i2 * H + cb);
                uint2 v3 = *(const uint2*)(tlp + (size_t)i3 * H + cb);
                bfacc2(a0, a1, v0.x); bfacc2(a2, a3, v0.y);
                bfacc2(g0, g1, v1.x); bfacc2(g2, g3, v1.y);
                bfacc2(a0, a1, v2.x); bfacc2(a2, a3, v2.y);
                bfacc2(g0, g1, v3.x); bfacc2(g2, g3, v3.y);
            }
            for (; j < c1; ++j) {
                uint2 v = *(const uint2*)(tlp + (size_t)nb1[j] * H + cb);
                bfacc2(a0, a1, v.x); bfacc2(a2, a3, v.y);
            }
            a0 += g0; a1 += g1; a2 += g2; a3 += g3;
            int s2 = off2[p], c2 = cnt2[p];
            const int* nb2 = nbr + s2;
            float d0 = 0.f, d1 = 0.f, d2 = 0.f, d3 = 0.f;
            float e0 = 0.f, e1 = 0.f, e2 = 0.f, e3 = 0.f;
            j = 0;
            for (; j + 2 <= c2; j += 2) {
                int i0 = nb2[j], i1 = nb2[j + 1];
                uint2 v0 = *(const uint2*)(tdp + (size_t)i0 * H + cb);
                uint2 v1 = *(const uint2*)(tdp + (size_t)i1 * H + cb);
                bfacc2(d0, d1, v0.x); bfacc2(d2, d3, v0.y);
                bfacc2(e0, e1, v1.x); bfacc2(e2, e3, v1.y);
            }
            if (j < c2) {
                uint2 v = *(const uint2*)(tdp + (size_t)nb2[j] * H + cb);
                bfacc2(d0, d1, v.x); bfacc2(d2, d3, v.y);
            }
            d0 += e0; d1 += e1; d2 += e2; d3 += e3;
            float i1f = 1.f / fmaxf((float)c1, 1.f), i2f = 1.f / fmaxf((float)c2, 1.f);
            float4 res;
            res.x = a0 * i1f + d0 * i2f + bbv.x;
            res.y = a1 * i1f + d1 * i2f + bbv.y;
            res.z = a2 * i1f + d2 * i2f + bbv.z;
            res.w = a3 * i1f + d3 * i2f + bbv.w;
            *(float4*)&accf[hw * 2 + rp][cb] = res;
        }
    }
    __syncthreads();
    {
        int m = lane & 15, kg = lane >> 4;
        bf16x8 afr[4];
#pragma unroll
        for (int ks = 0; ks < 4; ++ks)
            afr[ks] = *(const bf16x8*)&hpA[m][ks * 32 + kg * 8];
        int n0 = w * 32;
#pragma unroll
        for (int tt = 0; tt < 2; ++tt) {
            int nc = n0 + tt * 16 + m;
            f32x4 acc = {0.f, 0.f, 0.f, 0.f};
#pragma unroll
            for (int ks = 0; ks < 4; ++ks) {
                bf16x8 bfr = *(const bf16x8*)&w23bT[(size_t)nc * H + ks * 32 + kg * 8];
                acc = __builtin_amdgcn_mfma_f32_16x16x32_bf16(afr[ks], bfr, acc, 0, 0, 0);
            }
#pragma unroll
            for (int rg = 0; rg < 4; ++rg)
                accf[kg * 4 + rg][nc] += acc[rg];
        }
    }
    __syncthreads();
    for (int i = t; i < 16 * 64; i += 256) {
        int r = i >> 6, cc = (i & 63) * 2;
        st_bf2(aggp + (size_t)(p0 + r) * H + cc, make_float2(accf[r][cc], accf[r][cc + 1]));
    }
    if (t < 128) {
        float s = 0.f, q = 0.f;
#pragma unroll
        for (int r = 0; r < 16; ++r) {
            float v = accf[r][t];
            s += v;
            q = fmaf(v, v, q);
        }
        blocksums[(size_t)blockIdx.x * 256 + t] = s;
        blocksums[(size_t)blockIdx.x * 256 + 128 + t] = q;
    }
}

// ---------------- head: fused L2 patient BN+ReLU -> MFMA FC1 -> FC2 -> log_softmax ------
__global__ void k_head(const bf16* __restrict__ aggp, const float* __restrict__ sums,
                       const void* __restrict__ bng, const void* __restrict__ bnb,
                       const bf16* __restrict__ w1T, const void* __restrict__ b1,
                       const void* __restrict__ W2, const void* __restrict__ b2f,
                       void* __restrict__ out, const int* __restrict__ flags) {
    int f32m = flags[0];
    __shared__ bf16 hpA[16][HPAD];
    __shared__ float h1s[16][68];
    __shared__ float lgs[16][16];
    __shared__ float W2s[64 * NOUT];
    __shared__ float b1s[64], b2s[NOUT];
    int t = threadIdx.x;
    int w = t >> 6, lane = t & 63;
    for (int i = t; i < 64 * NOUT; i += 256) W2s[i] = ldin(W2, i, f32m);
    if (t < 64) b1s[t] = ldin(b1, t, f32m);
    else if (t >= 64 && t < 64 + NOUT) b2s[t - 64] = ldin(b2f, t - 64, f32m);
    int p0 = blockIdx.x * 16;
    {
        int cc = (t & 63) * 2;
        const float invN = 1.f / NP;
        float m0 = sums[cc] * invN, m1 = sums[cc + 1] * invN;
        float v0 = fmaf(-m0, m0, sums[128 + cc] * invN);
        float v1 = fmaf(-m1, m1, sums[128 + cc + 1] * invN);
        float sc0 = rsqrtf(v0 + 1e-5f) * ldin(bng, cc, f32m);
        float sc1 = rsqrtf(v1 + 1e-5f) * ldin(bng, cc + 1, f32m);
        float be0 = ldin(bnb, cc, f32m), be1 = ldin(bnb, cc + 1, f32m);
        for (int i = t; i < 16 * 64; i += 256) {
            int r = i >> 6;
            float2 v = ld_bf2(aggp + (size_t)(p0 + r) * H + cc);
            st_bf2(&hpA[r][cc], make_float2(fmaxf(fmaf(v.x - m0, sc0, be0), 0.f),
                                            fmaxf(fmaf(v.y - m1, sc1, be1), 0.f)));
        }
    }
    __syncthreads();
    {
        // MFMA FC1: wave w computes output cols [w*16, w*16+16); K=128 over 4 ksteps.
        int m = lane & 15, kg = lane >> 4;
        bf16x8 afr[4];
#pragma unroll
        for (int ks = 0; ks < 4; ++ks)
            afr[ks] = *(const bf16x8*)&hpA[m][ks * 32 + kg * 8];
        int nc = w * 16 + m;
        f32x4 acc = {0.f, 0.f, 0.f, 0.f};
#pragma unroll
        for (int ks = 0; ks < 4; ++ks) {
            bf16x8 bfr = *(const bf16x8*)&w1T[(size_t)nc * H + ks * 32 + kg * 8];
            acc = __builtin_amdgcn_mfma_f32_16x16x32_bf16(afr[ks], bfr, acc, 0, 0, 0);
        }
        float bv = b1s[nc];
#pragma unroll
        for (int rg = 0; rg < 4; ++rg)
            h1s[kg * 4 + rg][nc] = fmaxf(acc[rg] + bv, 0.f);
    }
    __syncthreads();
    int pat = lane >> 4, oidx = lane & 15;
    int prow = 4 * w + pat;
    float lg = 0.f;
    if (oidx < NOUT) {
        lg = b2s[oidx];
        const float* hh = h1s[prow];
#pragma unroll 8
        for (int k = 0; k < 64; ++k) lg = fmaf(hh[k], W2s[k * NOUT + oidx], lg);
        lgs[prow][oidx] = lg;
    }
    __syncthreads();
    if (oidx < NOUT) {
        float m = -1e30f;
#pragma unroll
        for (int k = 0; k < NOUT; ++k) m = fmaxf(m, lgs[prow][k]);
        float s = 0.f;
#pragma unroll
        for (int k = 0; k < NOUT; ++k) s += __expf(lgs[prow][k] - m);
        float r = lg - m - __logf(s);
        if (f32m)
            ((float*)out)[(size_t)(p0 + prow) * NOUT + oidx] = r;
        else
            ((bf16*)out)[(size_t)(p0 + prow) * NOUT + oidx] = __float2bfloat16(r);
    }
}

extern "C" void kernel_launch(void* const* d_in, const int* in_sizes, int n_in, void* d_out,
                              int out_size, void* d_ws, size_t ws_size, hipStream_t stream) {
    const int* e1s = (const int*)d_in[23];
    const int* e1d = (const int*)d_in[24];
    const int* e2s = (const int*)d_in[25];
    const int* e2d = (const int*)d_in[26];
    const int NPOOL = 2 * (E1 + E2);

    char* wsb = (char*)d_ws;
    size_t o = 0;
    auto af = [&](size_t nwords) { void* p = wsb + o * 4; o += nwords; return p; };
    int* flags = (int*)af(16);
    bf16* w23bT = (bf16*)af(HH / 2);
    bf16* w23bT1 = (bf16*)af(HH / 2);
    bf16* w1T = (bf16*)af(64 * H / 2);
    float* b23 = (float*)af(H);
    float* bns = (float*)af(8 * H);
    int* bsums = (int*)af(256);
    float* WpWl0 = (float*)af(16 * H);
    float* WpWl1 = (float*)af(16 * H);
    float* vecs = (float*)af(13 * 128);
    int* cnt = (int*)af(NCNT);
    int* off = (int*)af(NCNT);
    int* nbr = (int*)af(NPOOL);
    bf16* hp = (bf16*)af((size_t)NP * H / 2);
    size_t arena = o;
    unsigned char* r1s = (unsigned char*)af(E1 / 4);
    unsigned char* r2s = (unsigned char*)af(E2 / 4);
    unsigned int* labHistP = (unsigned int*)af((size_t)NCH1 * NPW);
    unsigned int* disHistP = (unsigned int*)af((size_t)NCH2 * NPW);
    unsigned int* labHist = (unsigned int*)af((size_t)LABHB * NL);
    unsigned int* disHist = (unsigned int*)af((size_t)DISHB * ND);
    size_t endA = o;
    o = arena;
    float* bufL = (float*)af((size_t)NL * H);
    float* bufD = (float*)af((size_t)ND * H);
    bf16* tlp = (bf16*)af((size_t)NL * H / 2);
    bf16* tdp = (bf16*)af((size_t)ND * H / 2);
    bf16* aggp = (bf16*)af((size_t)NP * H / 2);
    float* mxp = (float*)af((size_t)NROW * 16);
    float* blocksums = (float*)af((size_t)PAT_BLOCKS * 256);
    size_t endB = o;
    o = endA > endB ? endA : endB;
    (void)ws_size;

    k_detect<<<1, 256, 0, stream>>>((const unsigned short*)d_in[0], flags);

    k_hist<<<HB3, 1024, 0, stream>>>(e1s, e1d, e2s, e2d, labHistP, disHistP, r1s, r2s,
                                     labHist, disHist);
    k_reduce<<<RB7, 256, 0, stream>>>(labHist, disHist, labHistP, disHistP, cnt, d_in[0],
                                      d_in[3], d_in[4], d_in[5], d_in[6], d_in[7], d_in[8],
                                      d_in[9], d_in[10], d_in[11], hp, WpWl0, WpWl1, vecs,
                                      w23bT1, flags);
    int nb = (NCNT + SCAN_ELEMS - 1) / SCAN_ELEMS;
    k_scan1<<<nb, 256, 0, stream>>>(cnt, off, bsums, NCNT);
    k_scan2<<<1, 256, 0, stream>>>(bsums, nb);
    k_scan3<<<(NCNT + 255) / 256, 256, 0, stream>>>(off, bsums, NCNT);
    k_fill<<<CNT_BLOCKS + LABHB + DISHB + 1, 256, 0, stream>>>(
        e1s, e1d, e2s, e2d, off, r1s, r2s, (const unsigned char*)labHistP,
        (const unsigned char*)disHistP, labHist, disHist, nbr, bns);

    // ---- layer 1 (algebraically collapsed) ----
    k_stage1_L1<<<(NROW + 3) / 4, 256, 0, stream>>>(d_in[0], off, cnt, nbr, mxp, flags);
    k_patmm_L1<<<PAT_BLOCKS + LD1_BLOCKS, 256, 0, stream>>>(hp, d_in[1], d_in[2], off, cnt, nbr,
                                                            w23bT1, vecs, WpWl0, WpWl1, mxp,
                                                            aggp, bufL, bufD, blocksums, flags);
    k_bnred<<<384, 256, 0, stream>>>(blocksums, bufL, bufD, bns);

    // ---- layer 2: all BN applications fused into consumers ----
    k_stage1_L2<<<S2_TOTAL, 256, 0, stream>>>(bufL, bufD, bns, d_in[15], d_in[16], d_in[12],
                                              tlp, tdp, d_in[14], d_in[13], w23bT, b23,
                                              d_in[19], w1T, flags);
    k_patmm_L2<<<PAT_BLOCKS, 256, 0, stream>>>(aggp, tlp, tdp, off, cnt, nbr, w23bT, b23, bns,
                                               d_in[15], d_in[16], blocksums, flags);
    k_bnred<<<64, 256, 0, stream>>>(blocksums, bufL, bufD, bns + 6 * H);
    k_head<<<NP / 16, 256, 0, stream>>>(aggp, bns + 6 * H, d_in[17], d_in[18], w1T,
                                        d_in[20], d_in[21], d_in[22], d_out, flags);
}

// Round 7
// 604.211 us; speedup vs baseline: 1.1926x; 1.1926x over previous
//
#include <hip/hip_runtime.h>
#include <hip/hip_bf16.h>

#define NP 100000
#define NL 10000
#define ND 500
#define H 128
#define HH (H * H)
#define E1 2000000
#define E2 500000
#define NOUT 10
#define NCNT (NL + ND + 2 * NP)
#define NROW (NL + ND)
#define CHUNK 8192
#define LABHB ((E1 + CHUNK - 1) / CHUNK)
#define DISHB ((E2 + CHUNK - 1) / CHUNK)
#define CNT_BLOCKS ((E1 + E2 + 255) / 256)
#define EMBP ((NP * H + 255) / 256)
#define RED_LAB ((NL + 255) / 256)
#define RED_DIS ((ND + 255) / 256)
#define PAT_BLOCKS (NP / 16)

// patient-side chunked LDS histogram sort (replaces global atomics)
#define CHP 15625
#define NCH1 (E1 / CHP) /* 128 */
#define NCH2 (E2 / CHP) /* 32 */
#define NPW (NP / 4)    /* 25000 packed-byte words = 100 KB LDS */
#define RPW ((NPW + 255) / 256)

typedef __hip_bfloat16 bf16;
typedef __attribute__((ext_vector_type(8))) short bf16x8;
typedef __attribute__((ext_vector_type(4))) float f32x4;

__device__ __forceinline__ float bfbits2f(unsigned short s) {
    union { unsigned int u; float f; } v;
    v.u = (unsigned int)s << 16;
    return v.f;
}
__device__ __forceinline__ float2 ld_bf2(const bf16* p) {
    unsigned int u = *(const unsigned int*)p;
    return make_float2(bfbits2f((unsigned short)(u & 0xFFFFu)), bfbits2f((unsigned short)(u >> 16)));
}
__device__ __forceinline__ float2 ld_bf2_nt(const bf16* p) {
    unsigned int u = __builtin_nontemporal_load((const unsigned int*)p);
    return make_float2(bfbits2f((unsigned short)(u & 0xFFFFu)), bfbits2f((unsigned short)(u >> 16)));
}
__device__ __forceinline__ void st_bf2(bf16* p, float2 v) {
    union { unsigned int u; bf16 b[2]; } t;
    t.b[0] = __float2bfloat16(v.x);
    t.b[1] = __float2bfloat16(v.y);
    *(unsigned int*)p = t.u;
}
__device__ __forceinline__ float ldin(const void* p, size_t i, int f32m) {
    return f32m ? ((const float*)p)[i] : __bfloat162float(((const bf16*)p)[i]);
}
// accumulate 2 packed bf16 (one u32) into two f32 accumulators: 2 unpack + 2 add VALU
__device__ __forceinline__ void bfacc2(float& x, float& y, unsigned int u) {
    union { unsigned int q; float f; } lo, hi;
    lo.q = u << 16;
    hi.q = u & 0xFFFF0000u;
    x += lo.f;
    y += hi.f;
}

// ---------------- input dtype detection ----------------
__global__ void k_detect(const unsigned short* __restrict__ xp, int* __restrict__ flags) {
    int t = threadIdx.x;
    int cnt = 0;
    for (int i = t; i < 4096; i += 256) {
        unsigned short w = xp[2 * i];
        int e = (w >> 7) & 0xFF;
        if (w == 0 || (e >= 114 && e <= 141)) cnt++;
    }
    __shared__ int sh[256];
    sh[t] = cnt;
    __syncthreads();
    for (int s = 128; s > 0; s >>= 1) {
        if (t < s) sh[t] += sh[t + s];
        __syncthreads();
    }
    if (t == 0) flags[0] = (sh[0] < 2048) ? 1 : 0;
}

// ---- k_hist: all histograms via LDS (no global atomics), 1024 threads -----------------
#define HB0 NCH1
#define HB1 (HB0 + NCH2)
#define HB2 (HB1 + LABHB)
#define HB3 (HB2 + DISHB)
__global__ void k_hist(const int* __restrict__ e1s, const int* __restrict__ e1d,
                       const int* __restrict__ e2s, const int* __restrict__ e2d,
                       unsigned int* __restrict__ labHistP, unsigned int* __restrict__ disHistP,
                       unsigned char* __restrict__ r1s, unsigned char* __restrict__ r2s,
                       unsigned int* __restrict__ labHist, unsigned int* __restrict__ disHist) {
    __shared__ unsigned int sh[NPW];  // 100 KB: byte-packed patient counters / reused by dest hists
    int b = blockIdx.x, t = threadIdx.x;
    if (b < HB1) {
        for (int i = t; i < NPW; i += 1024) sh[i] = 0;
        __syncthreads();
        if (b < HB0) {
            int e0 = b * CHP;
            for (int j = t; j < CHP; j += 1024) {
                int e = e0 + j;
                int ss = e1s[e];
                unsigned int old = atomicAdd(&sh[ss >> 2], 1u << (8 * (ss & 3)));
                r1s[e] = (unsigned char)(old >> (8 * (ss & 3)));
            }
            __syncthreads();
            unsigned int* out = labHistP + (size_t)b * NPW;
            for (int i = t; i < NPW; i += 1024) out[i] = sh[i];
        } else {
            int c = b - HB0;
            int e0 = c * CHP;
            for (int j = t; j < CHP; j += 1024) {
                int e = e0 + j;
                int ss = e2s[e];
                unsigned int old = atomicAdd(&sh[ss >> 2], 1u << (8 * (ss & 3)));
                r2s[e] = (unsigned char)(old >> (8 * (ss & 3)));
            }
            __syncthreads();
            unsigned int* out = disHistP + (size_t)c * NPW;
            for (int i = t; i < NPW; i += 1024) out[i] = sh[i];
        }
    } else if (b < HB2) {
        int c = b - HB1;
        for (int i = t; i < NL / 2; i += 1024) sh[i] = 0;
        __syncthreads();
        int e0 = c * CHUNK, ee = min(E1, e0 + CHUNK);
        for (int e = e0 + t; e < ee; e += 1024) {
            int dd = e1d[e];
            atomicAdd(&sh[dd >> 1], 1u << (16 * (dd & 1)));
        }
        __syncthreads();
        for (int i = t; i < NL; i += 1024)
            labHist[(size_t)c * NL + i] = (sh[i >> 1] >> (16 * (i & 1))) & 0xFFFFu;
    } else {
        int c = b - HB2;
        for (int i = t; i < ND / 2; i += 1024) sh[i] = 0;
        __syncthreads();
        int e0 = c * CHUNK, ee = min(E2, e0 + CHUNK);
        for (int e = e0 + t; e < ee; e += 1024) {
            int dd = e2d[e];
            atomicAdd(&sh[dd >> 1], 1u << (16 * (dd & 1)));
        }
        __syncthreads();
        for (int i = t; i < ND; i += 1024)
            disHist[(size_t)c * ND + i] = (sh[i >> 1] >> (16 * (i & 1))) & 0xFFFFu;
    }
}

// ---- reduce: chunk exclusive bases (packed-byte scan for patients); totals -> cnt ------
#define RB0 RED_LAB
#define RB1 (RB0 + RED_DIS)
#define RB2 (RB1 + RPW)
#define RB3 (RB2 + RPW)
#define RB4 (RB3 + EMBP)
#define RB5 (RB4 + 16)
#define RB6 (RB5 + 7)
#define RB7 (RB6 + 64)
__global__ void k_reduce(unsigned int* __restrict__ labHist, unsigned int* __restrict__ disHist,
                         unsigned int* __restrict__ labHistP, unsigned int* __restrict__ disHistP,
                         int* __restrict__ cnt, const void* __restrict__ xp,
                         const void* __restrict__ Wp, const void* __restrict__ bp,
                         const void* __restrict__ Wlab, const void* __restrict__ blab,
                         const void* __restrict__ Wdis, const void* __restrict__ bdis,
                         const void* __restrict__ Wl1, const void* __restrict__ bl1,
                         const void* __restrict__ Wr1, bf16* __restrict__ hp,
                         float* __restrict__ WpWl0, float* __restrict__ WpWl1,
                         float* __restrict__ vecs, bf16* __restrict__ w23bT1,
                         const int* __restrict__ flags) {
    int b = blockIdx.x, t = threadIdx.x;
    if (b < RB0) {
        int bin = b * 256 + t;
        if (bin < NL) {
            unsigned int run = 0;
            for (int k = 0; k < LABHB; ++k) {
                unsigned int x = labHist[(size_t)k * NL + bin];
                labHist[(size_t)k * NL + bin] = run;
                run += x;
            }
            cnt[bin] = (int)run;
        }
    } else if (b < RB1) {
        int bin = (b - RB0) * 256 + t;
        if (bin < ND) {
            unsigned int run = 0;
            for (int k = 0; k < DISHB; ++k) {
                unsigned int x = disHist[(size_t)k * ND + bin];
                disHist[(size_t)k * ND + bin] = run;
                run += x;
            }
            cnt[NL + bin] = (int)run;
        }
    } else if (b < RB2) {
        int w = (b - RB1) * 256 + t;
        if (w < NPW) {
            unsigned int run = 0;  // 4 byte-lanes scanned in parallel; degree < 256 so no carry
            for (int c = 0; c < NCH1; ++c) {
                unsigned int x = labHistP[(size_t)c * NPW + w];
                labHistP[(size_t)c * NPW + w] = run;
                run += x;
            }
            int base = NL + ND + 4 * w;
            cnt[base] = (int)(run & 0xFFu);
            cnt[base + 1] = (int)((run >> 8) & 0xFFu);
            cnt[base + 2] = (int)((run >> 16) & 0xFFu);
            cnt[base + 3] = (int)(run >> 24);
        }
    } else if (b < RB3) {
        int w = (b - RB2) * 256 + t;
        if (w < NPW) {
            unsigned int run = 0;
            for (int c = 0; c < NCH2; ++c) {
                unsigned int x = disHistP[(size_t)c * NPW + w];
                disHistP[(size_t)c * NPW + w] = run;
                run += x;
            }
            int base = NL + ND + NP + 4 * w;
            cnt[base] = (int)(run & 0xFFu);
            cnt[base + 1] = (int)((run >> 8) & 0xFFu);
            cnt[base + 2] = (int)((run >> 16) & 0xFFu);
            cnt[base + 3] = (int)(run >> 24);
        }
    } else if (b < RB4) {
        int f32m = flags[0];
        int idx = (b - RB3) * 256 + t;
        int h = idx & 127;
        int i = idx >> 7;
        float acc = ldin(bp, h, f32m);
#pragma unroll
        for (int k = 0; k < 16; ++k)
            acc = fmaf(ldin(xp, (size_t)i * 16 + k, f32m), ldin(Wp, (size_t)k * H + h, f32m), acc);
        hp[idx] = __float2bfloat16(acc);
    } else if (b < RB5) {
        int f32m = flags[0];
        int pb = b - RB4;
        bool first = pb < 8;
        size_t woff = first ? 0 : (size_t)HH;
        float* outp = first ? WpWl0 : WpWl1;
        int k = (first ? pb : pb - 8) * 2 + (t >> 7);
        int h = t & 127;
        float s = 0.f;
        for (int m = 0; m < H; ++m)
            s = fmaf(ldin(Wp, (size_t)k * H + m, f32m), ldin(Wl1, woff + (size_t)m * H + h, f32m), s);
        outp[k * H + h] = s;
    } else if (b < RB6) {
        int f32m = flags[0];
        int idx = (b - RB5) * 256 + t;
        if (idx < 13 * 128) {
            int v = idx >> 7, h = idx & 127;
            float s = 0.f;
            if (v == 12) {
                s = ldin(bl1, 2 * H + h, f32m) + ldin(bl1, 3 * H + h, f32m);
            } else {
                const void* A;
                size_t aoff = 0;
                const void* W;
                size_t woff;
                float add = 0.f;
                switch (v) {
                    case 0: A = Wlab; W = Wl1; woff = 2 * (size_t)HH; break;
                    case 1: A = blab; W = Wl1; woff = 2 * (size_t)HH; break;
                    case 2: A = Wdis; W = Wl1; woff = 3 * (size_t)HH; break;
                    case 3: A = Wdis; aoff = H; W = Wl1; woff = 3 * (size_t)HH; break;
                    case 4: A = bdis; W = Wl1; woff = 3 * (size_t)HH; break;
                    case 5: A = Wlab; W = Wr1; woff = 0; break;
                    case 6: A = blab; W = Wr1; woff = 0; add = ldin(bl1, h, f32m); break;
                    case 7: A = Wdis; W = Wr1; woff = (size_t)HH; break;
                    case 8: A = Wdis; aoff = H; W = Wr1; woff = (size_t)HH; break;
                    case 9: A = bdis; W = Wr1; woff = (size_t)HH; add = ldin(bl1, H + h, f32m); break;
                    case 10: A = bp; W = Wl1; woff = 0; break;
                    default: A = bp; W = Wl1; woff = (size_t)HH; break;
                }
                for (int m = 0; m < H; ++m)
                    s = fmaf(ldin(A, aoff + m, f32m), ldin(W, woff + (size_t)m * H + h, f32m), s);
                s += add;
            }
            vecs[v * 128 + h] = s;
        }
    } else {
        int f32m = flags[0];
        int idx = (b - RB6) * 256 + t;
        if (idx < HH) {
            int k = idx >> 7, n = idx & 127;
            float v = ldin(Wr1, (size_t)2 * HH + idx, f32m) + ldin(Wr1, (size_t)3 * HH + idx, f32m);
            w23bT1[(size_t)n * H + k] = __float2bfloat16(v);
        }
    }
}

#define SCAN_ELEMS 2048
__global__ void k_scan1(const int* __restrict__ in, int* __restrict__ out,
                        int* __restrict__ bsums, int n) {
    int t = threadIdx.x;
    int base = blockIdx.x * SCAN_ELEMS + t * 8;
    int v[8], tsum = 0;
#pragma unroll
    for (int j = 0; j < 8; ++j) {
        v[j] = (base + j < n) ? in[base + j] : 0;
        tsum += v[j];
    }
    __shared__ int sh[256];
    sh[t] = tsum;
    __syncthreads();
    for (int d = 1; d < 256; d <<= 1) {
        int x = (t >= d) ? sh[t - d] : 0;
        __syncthreads();
        sh[t] += x;
        __syncthreads();
    }
    int run = sh[t] - tsum;
    if (t == 255) bsums[blockIdx.x] = sh[255];
#pragma unroll
    for (int j = 0; j < 8; ++j) {
        if (base + j < n) out[base + j] = run;
        run += v[j];
    }
}

__global__ void k_scan2(int* __restrict__ bsums, int nb) {
    int t = threadIdx.x;
    int v = (t < nb) ? bsums[t] : 0;
    __shared__ int sh[256];
    sh[t] = v;
    __syncthreads();
    for (int d = 1; d < 256; d <<= 1) {
        int x = (t >= d) ? sh[t - d] : 0;
        __syncthreads();
        sh[t] += x;
        __syncthreads();
    }
    if (t < nb) bsums[t] = sh[t] - v;
}

__global__ void k_scan3(int* __restrict__ out, const int* __restrict__ bsums, int n) {
    int i = blockIdx.x * 256 + threadIdx.x;
    if (i < n) out[i] += bsums[i / SCAN_ELEMS];
}

// ---- fill (+ last block zeros bns: 8 segments) ----------------------------------------
__global__ void k_fill(const int* __restrict__ e1s, const int* __restrict__ e1d,
                       const int* __restrict__ e2s, const int* __restrict__ e2d,
                       const int* __restrict__ off, const unsigned char* __restrict__ r1s,
                       const unsigned char* __restrict__ r2s,
                       const unsigned char* __restrict__ labBase,
                       const unsigned char* __restrict__ disBase,
                       const unsigned int* __restrict__ labHist,
                       const unsigned int* __restrict__ disHist, int* __restrict__ nbr,
                       float* __restrict__ bns) {
    __shared__ unsigned int slot[NL];
    int b = blockIdx.x, t = threadIdx.x;
    if (b < CNT_BLOCKS) {
        int e = b * 256 + t;
        if (e < E1) {
            int ss = e1s[e];
            int c = e / CHP;
            int pos = off[NL + ND + ss] + (int)labBase[(size_t)c * NP + ss] + (int)r1s[e];
            nbr[pos] = e1d[e];
        } else if (e < E1 + E2) {
            int i = e - E1;
            int ss = e2s[i];
            int c = i / CHP;
            int pos = off[NL + ND + NP + ss] + (int)disBase[(size_t)c * NP + ss] + (int)r2s[i];
            nbr[pos] = e2d[i];
        }
    } else if (b < CNT_BLOCKS + LABHB) {
        int c = b - CNT_BLOCKS;
        for (int i = t; i < NL; i += 256)
            slot[i] = (unsigned int)off[i] + labHist[(size_t)c * NL + i];
        __syncthreads();
        int e0 = c * CHUNK, ee = min(E1, e0 + CHUNK);
        for (int e = e0 + t; e < ee; e += 256) {
            unsigned int pos = atomicAdd(&slot[e1d[e]], 1u);
            nbr[pos] = e1s[e];
        }
    } else if (b < CNT_BLOCKS + LABHB + DISHB) {
        int c = b - CNT_BLOCKS - LABHB;
        for (int i = t; i < ND; i += 256)
            slot[i] = (unsigned int)off[NL + i] + disHist[(size_t)c * ND + i];
        __syncthreads();
        int e0 = c * CHUNK, ee = min(E2, e0 + CHUNK);
        for (int e = e0 + t; e < ee; e += 256) {
            unsigned int pos = atomicAdd(&slot[e2d[e]], 1u);
            nbr[pos] = e2s[e];
        }
    } else {
        for (int i = t; i < 8 * H; i += 256) bns[i] = 0.f;
    }
}

// ---------------- L1 stage1: gather 16-dim mean of x_p per lab/dis row ------------------
// Lane-per-neighbor: each lane loads a full 16-dim patient row (32 B bf16 / 64 B f32),
// giving 64-128 gathers in flight per wave instead of 4. Block LDS reduce at the end.
__global__ void k_stage1_L1(const void* __restrict__ xp, const int* __restrict__ off,
                            const int* __restrict__ cnt, const int* __restrict__ nbr,
                            float* __restrict__ mxp, const int* __restrict__ flags) {
    __shared__ float red[4][64][16];  // 16 KB
    int f32m = flags[0];
    int t = threadIdx.x;
    int w = t >> 6, lane = t & 63;
    int row = blockIdx.x * 4 + w;
    float acc[16];
#pragma unroll
    for (int d = 0; d < 16; ++d) acc[d] = 0.f;
    if (row < NROW) {
        int s0 = off[row], c = cnt[row];
        const int* nb = nbr + s0;
        if (f32m) {
            const float* xpf = (const float*)xp;
            int j = lane;
            for (; j + 64 < c; j += 128) {
                int p0 = nb[j], p1 = nb[j + 64];
                const float4* r0 = (const float4*)(xpf + (size_t)p0 * 16);
                const float4* r1 = (const float4*)(xpf + (size_t)p1 * 16);
                float4 a = r0[0], b2 = r0[1], cc = r0[2], dd = r0[3];
                float4 e = r1[0], f = r1[1], g = r1[2], h2 = r1[3];
                acc[0] += a.x + e.x;  acc[1] += a.y + e.y;  acc[2] += a.z + e.z;  acc[3] += a.w + e.w;
                acc[4] += b2.x + f.x; acc[5] += b2.y + f.y; acc[6] += b2.z + f.z; acc[7] += b2.w + f.w;
                acc[8] += cc.x + g.x; acc[9] += cc.y + g.y; acc[10] += cc.z + g.z; acc[11] += cc.w + g.w;
                acc[12] += dd.x + h2.x; acc[13] += dd.y + h2.y; acc[14] += dd.z + h2.z; acc[15] += dd.w + h2.w;
            }
            if (j < c) {
                const float4* r0 = (const float4*)(xpf + (size_t)nb[j] * 16);
                float4 a = r0[0], b2 = r0[1], cc = r0[2], dd = r0[3];
                acc[0] += a.x;  acc[1] += a.y;  acc[2] += a.z;  acc[3] += a.w;
                acc[4] += b2.x; acc[5] += b2.y; acc[6] += b2.z; acc[7] += b2.w;
                acc[8] += cc.x; acc[9] += cc.y; acc[10] += cc.z; acc[11] += cc.w;
                acc[12] += dd.x; acc[13] += dd.y; acc[14] += dd.z; acc[15] += dd.w;
            }
        } else {
            const bf16* xpb = (const bf16*)xp;
            int j = lane;
            for (; j + 64 < c; j += 128) {
                int p0 = nb[j], p1 = nb[j + 64];
                const uint4* r0 = (const uint4*)(xpb + (size_t)p0 * 16);
                const uint4* r1 = (const uint4*)(xpb + (size_t)p1 * 16);
                uint4 u0 = r0[0], u1 = r0[1];
                uint4 v0 = r1[0], v1 = r1[1];
                bfacc2(acc[0], acc[1], u0.x);   bfacc2(acc[2], acc[3], u0.y);
                bfacc2(acc[4], acc[5], u0.z);   bfacc2(acc[6], acc[7], u0.w);
                bfacc2(acc[8], acc[9], u1.x);   bfacc2(acc[10], acc[11], u1.y);
                bfacc2(acc[12], acc[13], u1.z); bfacc2(acc[14], acc[15], u1.w);
                bfacc2(acc[0], acc[1], v0.x);   bfacc2(acc[2], acc[3], v0.y);
                bfacc2(acc[4], acc[5], v0.z);   bfacc2(acc[6], acc[7], v0.w);
                bfacc2(acc[8], acc[9], v1.x);   bfacc2(acc[10], acc[11], v1.y);
                bfacc2(acc[12], acc[13], v1.z); bfacc2(acc[14], acc[15], v1.w);
            }
            if (j < c) {
                const uint4* r0 = (const uint4*)(xpb + (size_t)nb[j] * 16);
                uint4 u0 = r0[0], u1 = r0[1];
                bfacc2(acc[0], acc[1], u0.x);   bfacc2(acc[2], acc[3], u0.y);
                bfacc2(acc[4], acc[5], u0.z);   bfacc2(acc[6], acc[7], u0.w);
                bfacc2(acc[8], acc[9], u1.x);   bfacc2(acc[10], acc[11], u1.y);
                bfacc2(acc[12], acc[13], u1.z); bfacc2(acc[14], acc[15], u1.w);
            }
        }
    }
#pragma unroll
    for (int d = 0; d < 16; ++d) red[w][lane][d] = acc[d];
    __syncthreads();
    if (t < 64) {
        int w2 = t >> 4, d = t & 15;
        int row2 = blockIdx.x * 4 + w2;
        if (row2 < NROW) {
            float s = 0.f;
#pragma unroll 8
            for (int l = 0; l < 64; ++l) s += red[w2][l][d];
            mxp[(size_t)row2 * 16 + d] = s / fmaxf((float)cnt[row2], 1.f);
        }
    }
}

// -------- L1 patmm: scalar gathers + MFMA | lab/dis affine | per-block stats ------------
#define LD1_BLOCKS ((NROW + 1) / 2)
#define HPAD 136
#define APAD 132
__global__ void k_patmm_L1(const bf16* __restrict__ hp, const void* __restrict__ xl,
                           const void* __restrict__ xd, const int* __restrict__ off,
                           const int* __restrict__ cnt, const int* __restrict__ nbr,
                           const bf16* __restrict__ w23bT1, const float* __restrict__ vecs,
                           const float* __restrict__ WpWl0, const float* __restrict__ WpWl1,
                           const float* __restrict__ mxp, bf16* __restrict__ aggp,
                           float* __restrict__ bufL, float* __restrict__ bufD,
                           float* __restrict__ blocksums, const int* __restrict__ flags) {
    int t = threadIdx.x;
    int f32m = flags[0];
    if (blockIdx.x < PAT_BLOCKS) {
        __shared__ bf16 hpA[16][HPAD];
        __shared__ float accf[16][APAD];
        __shared__ float svec[6][128];
        __shared__ float s_mxl[16], s_onL[16], s_d0[16], s_d1[16], s_onD[16];
        int w = t >> 6, lane = t & 63;
        int p0 = blockIdx.x * 16;
        {
            const unsigned int* hpu = (const unsigned int*)(hp + (size_t)p0 * H);
            for (int i = t; i < 16 * 64; i += 256) {
                int r = i >> 6, c = i & 63;
                *(unsigned int*)&hpA[r][2 * c] = hpu[(size_t)r * 64 + c];
            }
        }
        {
            const int map[6] = {0, 1, 2, 3, 4, 12};
            for (int i = t; i < 6 * 128; i += 256)
                svec[i >> 7][i & 127] = vecs[map[i >> 7] * 128 + (i & 127)];
        }
        {
            int g = t >> 4, sl = t & 15;
            int p = p0 + g;
            int s1 = off[NL + ND + p], c1 = cnt[NL + ND + p];
            float a = 0.f;
            for (int j = sl; j < c1; j += 16) a += ldin(xl, nbr[s1 + j], f32m);
            a += __shfl_xor(a, 1);
            a += __shfl_xor(a, 2);
            a += __shfl_xor(a, 4);
            a += __shfl_xor(a, 8);
            int s2 = off[NL + ND + NP + p], c2 = cnt[NL + ND + NP + p];
            float d0 = 0.f, d1 = 0.f;
            for (int j = sl; j < c2; j += 16) {
                int q = nbr[s2 + j];
                d0 += ldin(xd, (size_t)2 * q, f32m);
                d1 += ldin(xd, (size_t)2 * q + 1, f32m);
            }
            d0 += __shfl_xor(d0, 1); d0 += __shfl_xor(d0, 2);
            d0 += __shfl_xor(d0, 4); d0 += __shfl_xor(d0, 8);
            d1 += __shfl_xor(d1, 1); d1 += __shfl_xor(d1, 2);
            d1 += __shfl_xor(d1, 4); d1 += __shfl_xor(d1, 8);
            if (sl == 0) {
                s_mxl[g] = a / fmaxf((float)c1, 1.f);
                s_onL[g] = (c1 > 0) ? 1.f : 0.f;
                s_d0[g] = d0 / fmaxf((float)c2, 1.f);
                s_d1[g] = d1 / fmaxf((float)c2, 1.f);
                s_onD[g] = (c2 > 0) ? 1.f : 0.f;
            }
        }
        __syncthreads();
        {
            int m = lane & 15, kg = lane >> 4;
            bf16x8 afr[4];
#pragma unroll
            for (int ks = 0; ks < 4; ++ks)
                afr[ks] = *(const bf16x8*)&hpA[m][ks * 32 + kg * 8];
            int n0 = w * 32;
#pragma unroll
            for (int tt = 0; tt < 2; ++tt) {
                int nc = n0 + tt * 16 + m;
                f32x4 acc = {0.f, 0.f, 0.f, 0.f};
#pragma unroll
                for (int ks = 0; ks < 4; ++ks) {
                    bf16x8 bfr = *(const bf16x8*)&w23bT1[(size_t)nc * H + ks * 32 + kg * 8];
                    acc = __builtin_amdgcn_mfma_f32_16x16x32_bf16(afr[ks], bfr, acc, 0, 0, 0);
                }
#pragma unroll
                for (int rg = 0; rg < 4; ++rg)
                    accf[kg * 4 + rg][nc] = acc[rg];
            }
        }
        __syncthreads();
        for (int i = t; i < 16 * 64; i += 256) {
            int r = i >> 6, cc = (i & 63) * 2;
            float l0 = s_onL[r] * fmaf(s_mxl[r], svec[0][cc], svec[1][cc]);
            float l1 = s_onL[r] * fmaf(s_mxl[r], svec[0][cc + 1], svec[1][cc + 1]);
            float q0 = s_onD[r] * (s_d0[r] * svec[2][cc] + s_d1[r] * svec[3][cc] + svec[4][cc]);
            float q1 = s_onD[r] * (s_d0[r] * svec[2][cc + 1] + s_d1[r] * svec[3][cc + 1] + svec[4][cc + 1]);
            float v0 = accf[r][cc] + l0 + q0 + svec[5][cc];
            float v1 = accf[r][cc + 1] + l1 + q1 + svec[5][cc + 1];
            accf[r][cc] = v0;
            accf[r][cc + 1] = v1;
            st_bf2(aggp + (size_t)(p0 + r) * H + cc, make_float2(v0, v1));
        }
        __syncthreads();
        if (t < 128) {
            float s = 0.f, q = 0.f;
#pragma unroll
            for (int r = 0; r < 16; ++r) {
                float v = accf[r][t];
                s += v;
                q = fmaf(v, v, q);
            }
            blocksums[(size_t)blockIdx.x * 256 + t] = s;
            blocksums[(size_t)blockIdx.x * 256 + 128 + t] = q;
        }
    } else {
        int bb = blockIdx.x - PAT_BLOCKS;
        int rr = bb * 2 + (t >> 7);
        int h = t & 127;
        if (rr >= NROW) return;
        if (rr < NL) {
            float acc = vecs[6 * 128 + h] + ldin(xl, rr, f32m) * vecs[5 * 128 + h];
            if (cnt[rr] > 0) {
                float s = vecs[10 * 128 + h];
                const float* mx = mxp + (size_t)rr * 16;
#pragma unroll
                for (int k = 0; k < 16; ++k) s = fmaf(mx[k], WpWl0[k * H + h], s);
                acc += s;
            }
            bufL[(size_t)rr * H + h] = acc;
        } else {
            int rd = rr - NL;
            float acc = vecs[9 * 128 + h] + ldin(xd, (size_t)2 * rd, f32m) * vecs[7 * 128 + h] +
                        ldin(xd, (size_t)2 * rd + 1, f32m) * vecs[8 * 128 + h];
            if (cnt[rr] > 0) {
                float s = vecs[11 * 128 + h];
                const float* mx = mxp + (size_t)rr * 16;
#pragma unroll
                for (int k = 0; k < 16; ++k) s = fmaf(mx[k], WpWl1[k * H + h], s);
                acc += s;
            }
            bufD[(size_t)rd * H + h] = acc;
        }
    }
}

// -------- bnred: patient stats from blocksums (+ lab/dis stats when grid>64) -----------
__global__ void k_bnred(const float* __restrict__ blocksums, const float* __restrict__ bufL,
                        const float* __restrict__ bufD, float* __restrict__ sums) {
    int b = blockIdx.x, t = threadIdx.x;
    if (b < 64) {
        float acc = 0.f;
        for (int r = b; r < PAT_BLOCKS; r += 64) acc += blocksums[(size_t)r * 256 + t];
        atomicAdd(&sums[t], acc);
        return;
    }
    int h = t & 127;
    int sub = t >> 7;
    float s = 0.f, s2 = 0.f;
    float* sm;
    if (b < 320) {
        int bid = b - 64;
        for (int i = bid * 2 + sub; i < NL; i += 512) {
            float v = bufL[(size_t)i * H + h];
            s += v;
            s2 = fmaf(v, v, s2);
        }
        sm = sums + 2 * H;
    } else {
        int bid = b - 320;
        for (int i = bid * 2 + sub; i < ND; i += 128) {
            float v = bufD[(size_t)i * H + h];
            s += v;
            s2 = fmaf(v, v, s2);
        }
        sm = sums + 4 * H;
    }
    __shared__ float ls[256], ls2[256];
    ls[t] = s;
    ls2[t] = s2;
    __syncthreads();
    if (sub == 0) {
        atomicAdd(&sm[h], s + ls[128 + h]);
        atomicAdd(&sm[H + h], s2 + ls2[128 + h]);
    }
}

// ---- L2 stage1: mm_small (L1 lab/dis BN inline) + prep23 + head-W1 precompute ----------
#define S2_MM 1313
#define S2_PREP 64
#define S2_TOTAL (S2_MM + S2_PREP)
__global__ void k_stage1_L2(const float* __restrict__ bufL, const float* __restrict__ bufD,
                            const float* __restrict__ bns, const void* __restrict__ bng1,
                            const void* __restrict__ bnb1, const void* __restrict__ Wl,
                            bf16* __restrict__ tlp, bf16* __restrict__ tdp,
                            const void* __restrict__ Wr, const void* __restrict__ bl,
                            bf16* __restrict__ w23bT, float* __restrict__ b23,
                            const void* __restrict__ W1in, bf16* __restrict__ w1T,
                            const int* __restrict__ flags) {
    __shared__ float smm[8][H];
    int b = blockIdx.x, t = threadIdx.x;
    int f32m = flags[0];
    if (b < S2_MM) {
        int bb = b;
        bool lab = bb < 1250;
        const float* buf = lab ? bufL : bufD;
        int N = lab ? NL : ND;
        float invN = lab ? 1.f / NL : 1.f / ND;
        int so = lab ? 2 * H : 4 * H;
        int go = lab ? H : 2 * H;
        bf16* outp = lab ? tlp : tdp;
        size_t woff = lab ? (size_t)2 * HH : (size_t)3 * HH;
        int r0 = (lab ? bb : bb - 1250) * 8;
        int h = t & 127, half = t >> 7;
        float m = bns[so + h] * invN;
        float v = fmaf(-m, m, bns[so + H + h] * invN);
        float sc = rsqrtf(v + 1e-5f) * ldin(bng1, go + h, f32m);
        float be = ldin(bnb1, go + h, f32m);
        for (int r = half; r < 8; r += 2) {
            int ri = r0 + r;
            float x = (ri < N) ? buf[(size_t)ri * H + h] : 0.f;
            smm[r][h] = (ri < N) ? fmaxf(fmaf(x - m, sc, be), 0.f) : 0.f;
        }
        __syncthreads();
        int rb = half * 4;
        float a0 = 0.f, a1 = 0.f, a2 = 0.f, a3 = 0.f;
        for (int k = 0; k < H; ++k) {
            float wv = ldin(Wl, woff + (size_t)k * H + h, f32m);
            a0 = fmaf(smm[rb + 0][k], wv, a0);
            a1 = fmaf(smm[rb + 1][k], wv, a1);
            a2 = fmaf(smm[rb + 2][k], wv, a2);
            a3 = fmaf(smm[rb + 3][k], wv, a3);
        }
        float acc[4] = {a0, a1, a2, a3};
#pragma unroll
        for (int r = 0; r < 4; ++r)
            if (r0 + rb + r < N)
                outp[(size_t)(r0 + rb + r) * H + h] = __float2bfloat16(acc[r]);
    } else {
        int pb = b - S2_MM;
        int idx = pb * 256 + t;
        if (idx < HH) {
            int k = idx >> 7, n = idx & 127;
            float v = ldin(Wr, (size_t)2 * HH + idx, f32m) + ldin(Wr, (size_t)3 * HH + idx, f32m);
            w23bT[(size_t)n * H + k] = __float2bfloat16(v);
        }
        if (idx < H)
            b23[idx] = ldin(bl, (size_t)2 * H + idx, f32m) + ldin(bl, (size_t)3 * H + idx, f32m);
        if (idx < 64 * H) {  // head FC1 weight, transposed to [n][k] bf16 for MFMA B-operand
            int n = idx >> 7, k = idx & 127;
            w1T[idx] = __float2bfloat16(ldin(W1in, (size_t)k * 64 + n, f32m));
        }
    }
}

// -------- L2 patmm: in-place aggp update (L1 pat BN inline) + per-block stats -----------
// Gather: half-wave (32 lanes) per patient row, 8 B (4 cols) per lane, software-pipelined:
// next iteration's indices are prefetched into registers before consuming the current
// gathers, removing idx-load latency from the dependent chain. aggp staging read is
// non-temporal (read-once; keeps tlp/tdp L2-resident). Stores stay temporal.
__global__ void k_patmm_L2(bf16* __restrict__ aggp, const bf16* __restrict__ tlp,
                           const bf16* __restrict__ tdp, const int* __restrict__ off,
                           const int* __restrict__ cnt, const int* __restrict__ nbr,
                           const bf16* __restrict__ w23bT, const float* __restrict__ b23,
                           const float* __restrict__ bns, const void* __restrict__ bng1,
                           const void* __restrict__ bnb1, float* __restrict__ blocksums,
                           const int* __restrict__ flags) {
    __shared__ bf16 hpA[16][HPAD];
    __shared__ __align__(16) float accf[16][APAD];
    int t = threadIdx.x;
    int f32m = flags[0];
    int w = t >> 6, lane = t & 63;
    int p0 = blockIdx.x * 16;
    {
        int cc = (t & 63) * 2;
        const float invN = 1.f / NP;
        float m0 = bns[cc] * invN, m1 = bns[cc + 1] * invN;
        float v0 = fmaf(-m0, m0, bns[128 + cc] * invN);
        float v1 = fmaf(-m1, m1, bns[128 + cc + 1] * invN);
        float sc0 = rsqrtf(v0 + 1e-5f) * ldin(bng1, cc, f32m);
        float sc1 = rsqrtf(v1 + 1e-5f) * ldin(bng1, cc + 1, f32m);
        float be0 = ldin(bnb1, cc, f32m), be1 = ldin(bnb1, cc + 1, f32m);
        for (int i = t; i < 16 * 64; i += 256) {
            int r = i >> 6;
            float2 v = ld_bf2_nt(aggp + (size_t)(p0 + r) * H + cc);
            st_bf2(&hpA[r][cc], make_float2(fmaxf(fmaf(v.x - m0, sc0, be0), 0.f),
                                            fmaxf(fmaf(v.y - m1, sc1, be1), 0.f)));
        }
    }
    {
        const int* off1 = off + NL + ND;
        const int* cnt1 = cnt + NL + ND;
        const int* off2 = off + NL + ND + NP;
        const int* cnt2 = cnt + NL + ND + NP;
        int hw = t >> 5, hl = t & 31;  // 8 half-waves; each owns 2 patients
        int cb = hl * 4;               // this lane's 4 columns
        float4 bbv = *(const float4*)(b23 + cb);
#pragma unroll
        for (int rp = 0; rp < 2; ++rp) {
            int p = p0 + hw * 2 + rp;
            int s1 = off1[p], c1 = cnt1[p];
            const int* nb1 = nbr + s1;
            float a0 = 0.f, a1 = 0.f, a2 = 0.f, a3 = 0.f;
            float g0 = 0.f, g1 = 0.f, g2 = 0.f, g3 = 0.f;
            int j = 0;
            int i0, i1, i2, i3;
            if (c1 >= 4) { i0 = nb1[0]; i1 = nb1[1]; i2 = nb1[2]; i3 = nb1[3]; }
            for (; j + 8 <= c1; j += 4) {
                uint2 v0 = *(const uint2*)(tlp + (size_t)i0 * H + cb);
                uint2 v1 = *(const uint2*)(tlp + (size_t)i1 * H + cb);
                uint2 v2 = *(const uint2*)(tlp + (size_t)i2 * H + cb);
                uint2 v3 = *(const uint2*)(tlp + (size_t)i3 * H + cb);
                int n0 = nb1[j + 4], n1 = nb1[j + 5], n2 = nb1[j + 6], n3 = nb1[j + 7];
                bfacc2(a0, a1, v0.x); bfacc2(a2, a3, v0.y);
                bfacc2(g0, g1, v1.x); bfacc2(g2, g3, v1.y);
                bfacc2(a0, a1, v2.x); bfacc2(a2, a3, v2.y);
                bfacc2(g0, g1, v3.x); bfacc2(g2, g3, v3.y);
                i0 = n0; i1 = n1; i2 = n2; i3 = n3;
            }
            if (j + 4 <= c1) {
                uint2 v0 = *(const uint2*)(tlp + (size_t)i0 * H + cb);
                uint2 v1 = *(const uint2*)(tlp + (size_t)i1 * H + cb);
                uint2 v2 = *(const uint2*)(tlp + (size_t)i2 * H + cb);
                uint2 v3 = *(const uint2*)(tlp + (size_t)i3 * H + cb);
                bfacc2(a0, a1, v0.x); bfacc2(a2, a3, v0.y);
                bfacc2(g0, g1, v1.x); bfacc2(g2, g3, v1.y);
                bfacc2(a0, a1, v2.x); bfacc2(a2, a3, v2.y);
                bfacc2(g0, g1, v3.x); bfacc2(g2, g3, v3.y);
                j += 4;
            }
            for (; j < c1; ++j) {
                uint2 v = *(const uint2*)(tlp + (size_t)nb1[j] * H + cb);
                bfacc2(a0, a1, v.x); bfacc2(a2, a3, v.y);
            }
            a0 += g0; a1 += g1; a2 += g2; a3 += g3;
            int s2 = off2[p], c2 = cnt2[p];
            const int* nb2 = nbr + s2;
            float d0 = 0.f, d1 = 0.f, d2 = 0.f, d3 = 0.f;
            float e0 = 0.f, e1 = 0.f, e2 = 0.f, e3 = 0.f;
            j = 0;
            int k0, k1;
            if (c2 >= 2) { k0 = nb2[0]; k1 = nb2[1]; }
            for (; j + 4 <= c2; j += 2) {
                uint2 v0 = *(const uint2*)(tdp + (size_t)k0 * H + cb);
                uint2 v1 = *(const uint2*)(tdp + (size_t)k1 * H + cb);
                int n0 = nb2[j + 2], n1 = nb2[j + 3];
                bfacc2(d0, d1, v0.x); bfacc2(d2, d3, v0.y);
                bfacc2(e0, e1, v1.x); bfacc2(e2, e3, v1.y);
                k0 = n0; k1 = n1;
            }
            if (j + 2 <= c2) {
                uint2 v0 = *(const uint2*)(tdp + (size_t)k0 * H + cb);
                uint2 v1 = *(const uint2*)(tdp + (size_t)k1 * H + cb);
                bfacc2(d0, d1, v0.x); bfacc2(d2, d3, v0.y);
                bfacc2(e0, e1, v1.x); bfacc2(e2, e3, v1.y);
                j += 2;
            }
            if (j < c2) {
                uint2 v = *(const uint2*)(tdp + (size_t)nb2[j] * H + cb);
                bfacc2(d0, d1, v.x); bfacc2(d2, d3, v.y);
            }
            d0 += e0; d1 += e1; d2 += e2; d3 += e3;
            float i1f = 1.f / fmaxf((float)c1, 1.f), i2f = 1.f / fmaxf((float)c2, 1.f);
            float4 res;
            res.x = a0 * i1f + d0 * i2f + bbv.x;
            res.y = a1 * i1f + d1 * i2f + bbv.y;
            res.z = a2 * i1f + d2 * i2f + bbv.z;
            res.w = a3 * i1f + d3 * i2f + bbv.w;
            *(float4*)&accf[hw * 2 + rp][cb] = res;
        }
    }
    __syncthreads();
    {
        int m = lane & 15, kg = lane >> 4;
        bf16x8 afr[4];
#pragma unroll
        for (int ks = 0; ks < 4; ++ks)
            afr[ks] = *(const bf16x8*)&hpA[m][ks * 32 + kg * 8];
        int n0 = w * 32;
#pragma unroll
        for (int tt = 0; tt < 2; ++tt) {
            int nc = n0 + tt * 16 + m;
            f32x4 acc = {0.f, 0.f, 0.f, 0.f};
#pragma unroll
            for (int ks = 0; ks < 4; ++ks) {
                bf16x8 bfr = *(const bf16x8*)&w23bT[(size_t)nc * H + ks * 32 + kg * 8];
                acc = __builtin_amdgcn_mfma_f32_16x16x32_bf16(afr[ks], bfr, acc, 0, 0, 0);
            }
#pragma unroll
            for (int rg = 0; rg < 4; ++rg)
                accf[kg * 4 + rg][nc] += acc[rg];
        }
    }
    __syncthreads();
    for (int i = t; i < 16 * 64; i += 256) {
        int r = i >> 6, cc = (i & 63) * 2;
        st_bf2(aggp + (size_t)(p0 + r) * H + cc, make_float2(accf[r][cc], accf[r][cc + 1]));
    }
    if (t < 128) {
        float s = 0.f, q = 0.f;
#pragma unroll
        for (int r = 0; r < 16; ++r) {
            float v = accf[r][t];
            s += v;
            q = fmaf(v, v, q);
        }
        blocksums[(size_t)blockIdx.x * 256 + t] = s;
        blocksums[(size_t)blockIdx.x * 256 + 128 + t] = q;
    }
}

// ---------------- head: fused L2 patient BN+ReLU -> MFMA FC1 -> FC2 -> log_softmax ------
__global__ void k_head(const bf16* __restrict__ aggp, const float* __restrict__ sums,
                       const void* __restrict__ bng, const void* __restrict__ bnb,
                       const bf16* __restrict__ w1T, const void* __restrict__ b1,
                       const void* __restrict__ W2, const void* __restrict__ b2f,
                       void* __restrict__ out, const int* __restrict__ flags) {
    int f32m = flags[0];
    __shared__ bf16 hpA[16][HPAD];
    __shared__ float h1s[16][68];
    __shared__ float lgs[16][16];
    __shared__ float W2s[64 * NOUT];
    __shared__ float b1s[64], b2s[NOUT];
    int t = threadIdx.x;
    int w = t >> 6, lane = t & 63;
    for (int i = t; i < 64 * NOUT; i += 256) W2s[i] = ldin(W2, i, f32m);
    if (t < 64) b1s[t] = ldin(b1, t, f32m);
    else if (t >= 64 && t < 64 + NOUT) b2s[t - 64] = ldin(b2f, t - 64, f32m);
    int p0 = blockIdx.x * 16;
    {
        int cc = (t & 63) * 2;
        const float invN = 1.f / NP;
        float m0 = sums[cc] * invN, m1 = sums[cc + 1] * invN;
        float v0 = fmaf(-m0, m0, sums[128 + cc] * invN);
        float v1 = fmaf(-m1, m1, sums[128 + cc + 1] * invN);
        float sc0 = rsqrtf(v0 + 1e-5f) * ldin(bng, cc, f32m);
        float sc1 = rsqrtf(v1 + 1e-5f) * ldin(bng, cc + 1, f32m);
        float be0 = ldin(bnb, cc, f32m), be1 = ldin(bnb, cc + 1, f32m);
        for (int i = t; i < 16 * 64; i += 256) {
            int r = i >> 6;
            float2 v = ld_bf2(aggp + (size_t)(p0 + r) * H + cc);
            st_bf2(&hpA[r][cc], make_float2(fmaxf(fmaf(v.x - m0, sc0, be0), 0.f),
                                            fmaxf(fmaf(v.y - m1, sc1, be1), 0.f)));
        }
    }
    __syncthreads();
    {
        // MFMA FC1: wave w computes output cols [w*16, w*16+16); K=128 over 4 ksteps.
        int m = lane & 15, kg = lane >> 4;
        bf16x8 afr[4];
#pragma unroll
        for (int ks = 0; ks < 4; ++ks)
            afr[ks] = *(const bf16x8*)&hpA[m][ks * 32 + kg * 8];
        int nc = w * 16 + m;
        f32x4 acc = {0.f, 0.f, 0.f, 0.f};
#pragma unroll
        for (int ks = 0; ks < 4; ++ks) {
            bf16x8 bfr = *(const bf16x8*)&w1T[(size_t)nc * H + ks * 32 + kg * 8];
            acc = __builtin_amdgcn_mfma_f32_16x16x32_bf16(afr[ks], bfr, acc, 0, 0, 0);
        }
        float bv = b1s[nc];
#pragma unroll
        for (int rg = 0; rg < 4; ++rg)
            h1s[kg * 4 + rg][nc] = fmaxf(acc[rg] + bv, 0.f);
    }
    __syncthreads();
    int pat = lane >> 4, oidx = lane & 15;
    int prow = 4 * w + pat;
    float lg = 0.f;
    if (oidx < NOUT) {
        lg = b2s[oidx];
        const float* hh = h1s[prow];
#pragma unroll 8
        for (int k = 0; k < 64; ++k) lg = fmaf(hh[k], W2s[k * NOUT + oidx], lg);
        lgs[prow][oidx] = lg;
    }
    __syncthreads();
    if (oidx < NOUT) {
        float m = -1e30f;
#pragma unroll
        for (int k = 0; k < NOUT; ++k) m = fmaxf(m, lgs[prow][k]);
        float s = 0.f;
#pragma unroll
        for (int k = 0; k < NOUT; ++k) s += __expf(lgs[prow][k] - m);
        float r = lg - m - __logf(s);
        if (f32m)
            ((float*)out)[(size_t)(p0 + prow) * NOUT + oidx] = r;
        else
            ((bf16*)out)[(size_t)(p0 + prow) * NOUT + oidx] = __float2bfloat16(r);
    }
}

extern "C" void kernel_launch(void* const* d_in, const int* in_sizes, int n_in, void* d_out,
                              int out_size, void* d_ws, size_t ws_size, hipStream_t stream) {
    const int* e1s = (const int*)d_in[23];
    const int* e1d = (const int*)d_in[24];
    const int* e2s = (const int*)d_in[25];
    const int* e2d = (const int*)d_in[26];
    const int NPOOL = 2 * (E1 + E2);

    char* wsb = (char*)d_ws;
    size_t o = 0;
    auto af = [&](size_t nwords) { void* p = wsb + o * 4; o += nwords; return p; };
    int* flags = (int*)af(16);
    bf16* w23bT = (bf16*)af(HH / 2);
    bf16* w23bT1 = (bf16*)af(HH / 2);
    bf16* w1T = (bf16*)af(64 * H / 2);
    float* b23 = (float*)af(H);
    float* bns = (float*)af(8 * H);
    int* bsums = (int*)af(256);
    float* WpWl0 = (float*)af(16 * H);
    float* WpWl1 = (float*)af(16 * H);
    float* vecs = (float*)af(13 * 128);
    int* cnt = (int*)af(NCNT);
    int* off = (int*)af(NCNT);
    int* nbr = (int*)af(NPOOL);
    bf16* hp = (bf16*)af((size_t)NP * H / 2);
    size_t arena = o;
    unsigned char* r1s = (unsigned char*)af(E1 / 4);
    unsigned char* r2s = (unsigned char*)af(E2 / 4);
    unsigned int* labHistP = (unsigned int*)af((size_t)NCH1 * NPW);
    unsigned int* disHistP = (unsigned int*)af((size_t)NCH2 * NPW);
    unsigned int* labHist = (unsigned int*)af((size_t)LABHB * NL);
    unsigned int* disHist = (unsigned int*)af((size_t)DISHB * ND);
    size_t endA = o;
    o = arena;
    float* bufL = (float*)af((size_t)NL * H);
    float* bufD = (float*)af((size_t)ND * H);
    bf16* tlp = (bf16*)af((size_t)NL * H / 2);
    bf16* tdp = (bf16*)af((size_t)ND * H / 2);
    bf16* aggp = (bf16*)af((size_t)NP * H / 2);
    float* mxp = (float*)af((size_t)NROW * 16);
    float* blocksums = (float*)af((size_t)PAT_BLOCKS * 256);
    size_t endB = o;
    o = endA > endB ? endA : endB;
    (void)ws_size;

    k_detect<<<1, 256, 0, stream>>>((const unsigned short*)d_in[0], flags);

    k_hist<<<HB3, 1024, 0, stream>>>(e1s, e1d, e2s, e2d, labHistP, disHistP, r1s, r2s,
                                     labHist, disHist);
    k_reduce<<<RB7, 256, 0, stream>>>(labHist, disHist, labHistP, disHistP, cnt, d_in[0],
                                      d_in[3], d_in[4], d_in[5], d_in[6], d_in[7], d_in[8],
                                      d_in[9], d_in[10], d_in[11], hp, WpWl0, WpWl1, vecs,
                                      w23bT1, flags);
    int nb = (NCNT + SCAN_ELEMS - 1) / SCAN_ELEMS;
    k_scan1<<<nb, 256, 0, stream>>>(cnt, off, bsums, NCNT);
    k_scan2<<<1, 256, 0, stream>>>(bsums, nb);
    k_scan3<<<(NCNT + 255) / 256, 256, 0, stream>>>(off, bsums, NCNT);
    k_fill<<<CNT_BLOCKS + LABHB + DISHB + 1, 256, 0, stream>>>(
        e1s, e1d, e2s, e2d, off, r1s, r2s, (const unsigned char*)labHistP,
        (const unsigned char*)disHistP, labHist, disHist, nbr, bns);

    // ---- layer 1 (algebraically collapsed) ----
    k_stage1_L1<<<(NROW + 3) / 4, 256, 0, stream>>>(d_in[0], off, cnt, nbr, mxp, flags);
    k_patmm_L1<<<PAT_BLOCKS + LD1_BLOCKS, 256, 0, stream>>>(hp, d_in[1], d_in[2], off, cnt, nbr,
                                                            w23bT1, vecs, WpWl0, WpWl1, mxp,
                                                            aggp, bufL, bufD, blocksums, flags);
    k_bnred<<<384, 256, 0, stream>>>(blocksums, bufL, bufD, bns);

    // ---- layer 2: all BN applications fused into consumers ----
    k_stage1_L2<<<S2_TOTAL, 256, 0, stream>>>(bufL, bufD, bns, d_in[15], d_in[16], d_in[12],
                                              tlp, tdp, d_in[14], d_in[13], w23bT, b23,
                                              d_in[19], w1T, flags);
    k_patmm_L2<<<PAT_BLOCKS, 256, 0, stream>>>(aggp, tlp, tdp, off, cnt, nbr, w23bT, b23, bns,
                                               d_in[15], d_in[16], blocksums, flags);
    k_bnred<<<64, 256, 0, stream>>>(blocksums, bufL, bufD, bns + 6 * H);
    k_head<<<NP / 16, 256, 0, stream>>>(aggp, bns + 6 * H, d_in[17], d_in[18], w1T,
                                        d_in[20], d_in[21], d_in[22], d_out, flags);
}

// Round 8
// 577.014 us; speedup vs baseline: 1.2488x; 1.0471x over previous
//
#include <hip/hip_runtime.h>
#include <hip/hip_bf16.h>

#define NP 100000
#define NL 10000
#define ND 500
#define H 128
#define HH (H * H)
#define E1 2000000
#define E2 500000
#define NOUT 10
#define NCNT (NL + ND + 2 * NP)
#define NROW (NL + ND)
#define CHUNK 8192
#define LABHB ((E1 + CHUNK - 1) / CHUNK)
#define DISHB ((E2 + CHUNK - 1) / CHUNK)
#define CNT_BLOCKS ((E1 + E2 + 255) / 256)
#define EMBP ((NP * H + 255) / 256)
#define RED_LAB ((NL + 255) / 256)
#define RED_DIS ((ND + 255) / 256)
#define PAT_BLOCKS (NP / 16)

// patient-side chunked LDS histogram sort (replaces global atomics)
#define CHP 15625
#define NCH1 (E1 / CHP) /* 128 */
#define NCH2 (E2 / CHP) /* 32 */
#define NPW (NP / 4)    /* 25000 packed-byte words = 100 KB LDS */
#define RPW ((NPW + 255) / 256)

typedef __hip_bfloat16 bf16;
typedef __attribute__((ext_vector_type(8))) short bf16x8;
typedef __attribute__((ext_vector_type(4))) float f32x4;

__device__ __forceinline__ float bfbits2f(unsigned short s) {
    union { unsigned int u; float f; } v;
    v.u = (unsigned int)s << 16;
    return v.f;
}
__device__ __forceinline__ float2 ld_bf2(const bf16* p) {
    unsigned int u = *(const unsigned int*)p;
    return make_float2(bfbits2f((unsigned short)(u & 0xFFFFu)), bfbits2f((unsigned short)(u >> 16)));
}
__device__ __forceinline__ float2 ld_bf2_nt(const bf16* p) {
    unsigned int u = __builtin_nontemporal_load((const unsigned int*)p);
    return make_float2(bfbits2f((unsigned short)(u & 0xFFFFu)), bfbits2f((unsigned short)(u >> 16)));
}
__device__ __forceinline__ void st_bf2(bf16* p, float2 v) {
    union { unsigned int u; bf16 b[2]; } t;
    t.b[0] = __float2bfloat16(v.x);
    t.b[1] = __float2bfloat16(v.y);
    *(unsigned int*)p = t.u;
}
__device__ __forceinline__ float ldin(const void* p, size_t i, int f32m) {
    return f32m ? ((const float*)p)[i] : __bfloat162float(((const bf16*)p)[i]);
}
// accumulate 2 packed bf16 (one u32) into two f32 accumulators: 2 unpack + 2 add VALU
__device__ __forceinline__ void bfacc2(float& x, float& y, unsigned int u) {
    union { unsigned int q; float f; } lo, hi;
    lo.q = u << 16;
    hi.q = u & 0xFFFF0000u;
    x += lo.f;
    y += hi.f;
}

// ---- k_hist: all histograms via LDS (no global atomics), 1024 threads -----------------
// Last block (b == HB3) performs input-dtype detection (folded k_detect).
#define HB0 NCH1
#define HB1 (HB0 + NCH2)
#define HB2 (HB1 + LABHB)
#define HB3 (HB2 + DISHB)
__global__ void k_hist(const int* __restrict__ e1s, const int* __restrict__ e1d,
                       const int* __restrict__ e2s, const int* __restrict__ e2d,
                       unsigned int* __restrict__ labHistP, unsigned int* __restrict__ disHistP,
                       unsigned char* __restrict__ r1s, unsigned char* __restrict__ r2s,
                       unsigned int* __restrict__ labHist, unsigned int* __restrict__ disHist,
                       const unsigned short* __restrict__ xpw, int* __restrict__ flags) {
    __shared__ unsigned int sh[NPW];  // 100 KB: byte-packed patient counters / reused by dest hists
    int b = blockIdx.x, t = threadIdx.x;
    if (b < HB1) {
        for (int i = t; i < NPW; i += 1024) sh[i] = 0;
        __syncthreads();
        if (b < HB0) {
            int e0 = b * CHP;
            for (int j = t; j < CHP; j += 1024) {
                int e = e0 + j;
                int ss = e1s[e];
                unsigned int old = atomicAdd(&sh[ss >> 2], 1u << (8 * (ss & 3)));
                r1s[e] = (unsigned char)(old >> (8 * (ss & 3)));
            }
            __syncthreads();
            unsigned int* out = labHistP + (size_t)b * NPW;
            for (int i = t; i < NPW; i += 1024) out[i] = sh[i];
        } else {
            int c = b - HB0;
            int e0 = c * CHP;
            for (int j = t; j < CHP; j += 1024) {
                int e = e0 + j;
                int ss = e2s[e];
                unsigned int old = atomicAdd(&sh[ss >> 2], 1u << (8 * (ss & 3)));
                r2s[e] = (unsigned char)(old >> (8 * (ss & 3)));
            }
            __syncthreads();
            unsigned int* out = disHistP + (size_t)c * NPW;
            for (int i = t; i < NPW; i += 1024) out[i] = sh[i];
        }
    } else if (b < HB2) {
        int c = b - HB1;
        for (int i = t; i < NL / 2; i += 1024) sh[i] = 0;
        __syncthreads();
        int e0 = c * CHUNK, ee = min(E1, e0 + CHUNK);
        for (int e = e0 + t; e < ee; e += 1024) {
            int dd = e1d[e];
            atomicAdd(&sh[dd >> 1], 1u << (16 * (dd & 1)));
        }
        __syncthreads();
        for (int i = t; i < NL; i += 1024)
            labHist[(size_t)c * NL + i] = (sh[i >> 1] >> (16 * (i & 1))) & 0xFFFFu;
    } else if (b < HB3) {
        int c = b - HB2;
        for (int i = t; i < ND / 2; i += 1024) sh[i] = 0;
        __syncthreads();
        int e0 = c * CHUNK, ee = min(E2, e0 + CHUNK);
        for (int e = e0 + t; e < ee; e += 1024) {
            int dd = e2d[e];
            atomicAdd(&sh[dd >> 1], 1u << (16 * (dd & 1)));
        }
        __syncthreads();
        for (int i = t; i < ND; i += 1024)
            disHist[(size_t)c * ND + i] = (sh[i >> 1] >> (16 * (i & 1))) & 0xFFFFu;
    } else {
        // dtype detection (flags consumed first by k_reduce, next in stream order)
        int cnt = 0;
        for (int i = t; i < 4096; i += 1024) {
            unsigned short w = xpw[2 * i];
            int e = (w >> 7) & 0xFF;
            if (w == 0 || (e >= 114 && e <= 141)) cnt++;
        }
        int* shi = (int*)sh;
        shi[t] = cnt;
        __syncthreads();
        for (int s = 512; s > 0; s >>= 1) {
            if (t < s) shi[t] += shi[t + s];
            __syncthreads();
        }
        if (t == 0) flags[0] = (shi[0] < 2048) ? 1 : 0;
    }
}

// ---- reduce: chunk exclusive bases (packed-byte scan for patients); totals -> cnt ------
#define RB0 RED_LAB
#define RB1 (RB0 + RED_DIS)
#define RB2 (RB1 + RPW)
#define RB3 (RB2 + RPW)
#define RB4 (RB3 + EMBP)
#define RB5 (RB4 + 16)
#define RB6 (RB5 + 7)
#define RB7 (RB6 + 64)
__global__ void k_reduce(unsigned int* __restrict__ labHist, unsigned int* __restrict__ disHist,
                         unsigned int* __restrict__ labHistP, unsigned int* __restrict__ disHistP,
                         int* __restrict__ cnt, const void* __restrict__ xp,
                         const void* __restrict__ Wp, const void* __restrict__ bp,
                         const void* __restrict__ Wlab, const void* __restrict__ blab,
                         const void* __restrict__ Wdis, const void* __restrict__ bdis,
                         const void* __restrict__ Wl1, const void* __restrict__ bl1,
                         const void* __restrict__ Wr1, bf16* __restrict__ hp,
                         float* __restrict__ WpWl0, float* __restrict__ WpWl1,
                         float* __restrict__ vecs, bf16* __restrict__ w23bT1,
                         bf16* __restrict__ xpb, const int* __restrict__ flags) {
    int b = blockIdx.x, t = threadIdx.x;
    if (b < RB0) {
        int bin = b * 256 + t;
        if (bin < NL) {
            unsigned int run = 0;
            for (int k = 0; k < LABHB; ++k) {
                unsigned int x = labHist[(size_t)k * NL + bin];
                labHist[(size_t)k * NL + bin] = run;
                run += x;
            }
            cnt[bin] = (int)run;
        }
    } else if (b < RB1) {
        int bin = (b - RB0) * 256 + t;
        if (bin < ND) {
            unsigned int run = 0;
            for (int k = 0; k < DISHB; ++k) {
                unsigned int x = disHist[(size_t)k * ND + bin];
                disHist[(size_t)k * ND + bin] = run;
                run += x;
            }
            cnt[NL + bin] = (int)run;
        }
    } else if (b < RB2) {
        int w = (b - RB1) * 256 + t;
        if (w < NPW) {
            unsigned int run = 0;  // 4 byte-lanes scanned in parallel; degree < 256 so no carry
            for (int c = 0; c < NCH1; ++c) {
                unsigned int x = labHistP[(size_t)c * NPW + w];
                labHistP[(size_t)c * NPW + w] = run;
                run += x;
            }
            int base = NL + ND + 4 * w;
            cnt[base] = (int)(run & 0xFFu);
            cnt[base + 1] = (int)((run >> 8) & 0xFFu);
            cnt[base + 2] = (int)((run >> 16) & 0xFFu);
            cnt[base + 3] = (int)(run >> 24);
        }
    } else if (b < RB3) {
        int w = (b - RB2) * 256 + t;
        if (w < NPW) {
            unsigned int run = 0;
            for (int c = 0; c < NCH2; ++c) {
                unsigned int x = disHistP[(size_t)c * NPW + w];
                disHistP[(size_t)c * NPW + w] = run;
                run += x;
            }
            int base = NL + ND + NP + 4 * w;
            cnt[base] = (int)(run & 0xFFu);
            cnt[base + 1] = (int)((run >> 8) & 0xFFu);
            cnt[base + 2] = (int)((run >> 16) & 0xFFu);
            cnt[base + 3] = (int)(run >> 24);
        }
    } else if (b < RB4) {
        int f32m = flags[0];
        int idx = (b - RB3) * 256 + t;
        int h = idx & 127;
        int i = idx >> 7;
        float acc = ldin(bp, h, f32m);
#pragma unroll
        for (int k = 0; k < 16; ++k)
            acc = fmaf(ldin(xp, (size_t)i * 16 + k, f32m), ldin(Wp, (size_t)k * H + h, f32m), acc);
        hp[idx] = __float2bfloat16(acc);
        if (h < 16)  // bf16 copy of xp for the stage1_L1 gather (halves its row bytes)
            xpb[(size_t)i * 16 + h] = __float2bfloat16(ldin(xp, (size_t)i * 16 + h, f32m));
    } else if (b < RB5) {
        int f32m = flags[0];
        int pb = b - RB4;
        bool first = pb < 8;
        size_t woff = first ? 0 : (size_t)HH;
        float* outp = first ? WpWl0 : WpWl1;
        int k = (first ? pb : pb - 8) * 2 + (t >> 7);
        int h = t & 127;
        float s = 0.f;
        for (int m = 0; m < H; ++m)
            s = fmaf(ldin(Wp, (size_t)k * H + m, f32m), ldin(Wl1, woff + (size_t)m * H + h, f32m), s);
        outp[k * H + h] = s;
    } else if (b < RB6) {
        int f32m = flags[0];
        int idx = (b - RB5) * 256 + t;
        if (idx < 13 * 128) {
            int v = idx >> 7, h = idx & 127;
            float s = 0.f;
            if (v == 12) {
                s = ldin(bl1, 2 * H + h, f32m) + ldin(bl1, 3 * H + h, f32m);
            } else {
                const void* A;
                size_t aoff = 0;
                const void* W;
                size_t woff;
                float add = 0.f;
                switch (v) {
                    case 0: A = Wlab; W = Wl1; woff = 2 * (size_t)HH; break;
                    case 1: A = blab; W = Wl1; woff = 2 * (size_t)HH; break;
                    case 2: A = Wdis; W = Wl1; woff = 3 * (size_t)HH; break;
                    case 3: A = Wdis; aoff = H; W = Wl1; woff = 3 * (size_t)HH; break;
                    case 4: A = bdis; W = Wl1; woff = 3 * (size_t)HH; break;
                    case 5: A = Wlab; W = Wr1; woff = 0; break;
                    case 6: A = blab; W = Wr1; woff = 0; add = ldin(bl1, h, f32m); break;
                    case 7: A = Wdis; W = Wr1; woff = (size_t)HH; break;
                    case 8: A = Wdis; aoff = H; W = Wr1; woff = (size_t)HH; break;
                    case 9: A = bdis; W = Wr1; woff = (size_t)HH; add = ldin(bl1, H + h, f32m); break;
                    case 10: A = bp; W = Wl1; woff = 0; break;
                    default: A = bp; W = Wl1; woff = (size_t)HH; break;
                }
                for (int m = 0; m < H; ++m)
                    s = fmaf(ldin(A, aoff + m, f32m), ldin(W, woff + (size_t)m * H + h, f32m), s);
                s += add;
            }
            vecs[v * 128 + h] = s;
        }
    } else {
        int f32m = flags[0];
        int idx = (b - RB6) * 256 + t;
        if (idx < HH) {
            int k = idx >> 7, n = idx & 127;
            float v = ldin(Wr1, (size_t)2 * HH + idx, f32m) + ldin(Wr1, (size_t)3 * HH + idx, f32m);
            w23bT1[(size_t)n * H + k] = __float2bfloat16(v);
        }
    }
}

#define SCAN_ELEMS 2048
__global__ void k_scan1(const int* __restrict__ in, int* __restrict__ out,
                        int* __restrict__ bsums, int n) {
    int t = threadIdx.x;
    int base = blockIdx.x * SCAN_ELEMS + t * 8;
    int v[8], tsum = 0;
#pragma unroll
    for (int j = 0; j < 8; ++j) {
        v[j] = (base + j < n) ? in[base + j] : 0;
        tsum += v[j];
    }
    __shared__ int sh[256];
    sh[t] = tsum;
    __syncthreads();
    for (int d = 1; d < 256; d <<= 1) {
        int x = (t >= d) ? sh[t - d] : 0;
        __syncthreads();
        sh[t] += x;
        __syncthreads();
    }
    int run = sh[t] - tsum;
    if (t == 255) bsums[blockIdx.x] = sh[255];
#pragma unroll
    for (int j = 0; j < 8; ++j) {
        if (base + j < n) out[base + j] = run;
        run += v[j];
    }
}

__global__ void k_scan2(int* __restrict__ bsums, int nb) {
    int t = threadIdx.x;
    int v = (t < nb) ? bsums[t] : 0;
    __shared__ int sh[256];
    sh[t] = v;
    __syncthreads();
    for (int d = 1; d < 256; d <<= 1) {
        int x = (t >= d) ? sh[t - d] : 0;
        __syncthreads();
        sh[t] += x;
        __syncthreads();
    }
    if (t < nb) bsums[t] = sh[t] - v;
}

__global__ void k_scan3(int* __restrict__ out, const int* __restrict__ bsums, int n) {
    int i = blockIdx.x * 256 + threadIdx.x;
    if (i < n) out[i] += bsums[i / SCAN_ELEMS];
}

// ---- fill (+ last block zeros bns: 8 segments) ----------------------------------------
__global__ void k_fill(const int* __restrict__ e1s, const int* __restrict__ e1d,
                       const int* __restrict__ e2s, const int* __restrict__ e2d,
                       const int* __restrict__ off, const unsigned char* __restrict__ r1s,
                       const unsigned char* __restrict__ r2s,
                       const unsigned char* __restrict__ labBase,
                       const unsigned char* __restrict__ disBase,
                       const unsigned int* __restrict__ labHist,
                       const unsigned int* __restrict__ disHist, int* __restrict__ nbr,
                       float* __restrict__ bns) {
    __shared__ unsigned int slot[NL];
    int b = blockIdx.x, t = threadIdx.x;
    if (b < CNT_BLOCKS) {
        int e = b * 256 + t;
        if (e < E1) {
            int ss = e1s[e];
            int c = e / CHP;
            int pos = off[NL + ND + ss] + (int)labBase[(size_t)c * NP + ss] + (int)r1s[e];
            nbr[pos] = e1d[e];
        } else if (e < E1 + E2) {
            int i = e - E1;
            int ss = e2s[i];
            int c = i / CHP;
            int pos = off[NL + ND + NP + ss] + (int)disBase[(size_t)c * NP + ss] + (int)r2s[i];
            nbr[pos] = e2d[i];
        }
    } else if (b < CNT_BLOCKS + LABHB) {
        int c = b - CNT_BLOCKS;
        for (int i = t; i < NL; i += 256)
            slot[i] = (unsigned int)off[i] + labHist[(size_t)c * NL + i];
        __syncthreads();
        int e0 = c * CHUNK, ee = min(E1, e0 + CHUNK);
        for (int e = e0 + t; e < ee; e += 256) {
            unsigned int pos = atomicAdd(&slot[e1d[e]], 1u);
            nbr[pos] = e1s[e];
        }
    } else if (b < CNT_BLOCKS + LABHB + DISHB) {
        int c = b - CNT_BLOCKS - LABHB;
        for (int i = t; i < ND; i += 256)
            slot[i] = (unsigned int)off[NL + i] + disHist[(size_t)c * ND + i];
        __syncthreads();
        int e0 = c * CHUNK, ee = min(E2, e0 + CHUNK);
        for (int e = e0 + t; e < ee; e += 256) {
            unsigned int pos = atomicAdd(&slot[e2d[e]], 1u);
            nbr[pos] = e2s[e];
        }
    } else {
        for (int i = t; i < 8 * H; i += 256) bns[i] = 0.f;
    }
}

// ---------------- L1 stage1: gather 16-dim mean of x_p per lab/dis row ------------------
// Lane-per-neighbor from the bf16 copy xpb: 32 B per neighbor row (half the f32 bytes),
// 64-128 gathers in flight per wave. Block LDS reduce at the end.
__global__ void k_stage1_L1(const bf16* __restrict__ xpb, const int* __restrict__ off,
                            const int* __restrict__ cnt, const int* __restrict__ nbr,
                            float* __restrict__ mxp) {
    __shared__ float red[4][64][16];  // 16 KB
    int t = threadIdx.x;
    int w = t >> 6, lane = t & 63;
    int row = blockIdx.x * 4 + w;
    float acc[16];
#pragma unroll
    for (int d = 0; d < 16; ++d) acc[d] = 0.f;
    if (row < NROW) {
        int s0 = off[row], c = cnt[row];
        const int* nb = nbr + s0;
        int j = lane;
        for (; j + 64 < c; j += 128) {
            int p0 = nb[j], p1 = nb[j + 64];
            const uint4* r0 = (const uint4*)(xpb + (size_t)p0 * 16);
            const uint4* r1 = (const uint4*)(xpb + (size_t)p1 * 16);
            uint4 u0 = r0[0], u1 = r0[1];
            uint4 v0 = r1[0], v1 = r1[1];
            bfacc2(acc[0], acc[1], u0.x);   bfacc2(acc[2], acc[3], u0.y);
            bfacc2(acc[4], acc[5], u0.z);   bfacc2(acc[6], acc[7], u0.w);
            bfacc2(acc[8], acc[9], u1.x);   bfacc2(acc[10], acc[11], u1.y);
            bfacc2(acc[12], acc[13], u1.z); bfacc2(acc[14], acc[15], u1.w);
            bfacc2(acc[0], acc[1], v0.x);   bfacc2(acc[2], acc[3], v0.y);
            bfacc2(acc[4], acc[5], v0.z);   bfacc2(acc[6], acc[7], v0.w);
            bfacc2(acc[8], acc[9], v1.x);   bfacc2(acc[10], acc[11], v1.y);
            bfacc2(acc[12], acc[13], v1.z); bfacc2(acc[14], acc[15], v1.w);
        }
        if (j < c) {
            const uint4* r0 = (const uint4*)(xpb + (size_t)nb[j] * 16);
            uint4 u0 = r0[0], u1 = r0[1];
            bfacc2(acc[0], acc[1], u0.x);   bfacc2(acc[2], acc[3], u0.y);
            bfacc2(acc[4], acc[5], u0.z);   bfacc2(acc[6], acc[7], u0.w);
            bfacc2(acc[8], acc[9], u1.x);   bfacc2(acc[10], acc[11], u1.y);
            bfacc2(acc[12], acc[13], u1.z); bfacc2(acc[14], acc[15], u1.w);
        }
    }
#pragma unroll
    for (int d = 0; d < 16; ++d) red[w][lane][d] = acc[d];
    __syncthreads();
    if (t < 64) {
        int w2 = t >> 4, d = t & 15;
        int row2 = blockIdx.x * 4 + w2;
        if (row2 < NROW) {
            float s = 0.f;
#pragma unroll 8
            for (int l = 0; l < 64; ++l) s += red[w2][l][d];
            mxp[(size_t)row2 * 16 + d] = s / fmaxf((float)cnt[row2], 1.f);
        }
    }
}

// -------- L1 patmm: scalar gathers + MFMA | lab/dis affine | per-block stats ------------
#define LD1_BLOCKS ((NROW + 1) / 2)
#define HPAD 136
#define APAD 132
__global__ void k_patmm_L1(const bf16* __restrict__ hp, const void* __restrict__ xl,
                           const void* __restrict__ xd, const int* __restrict__ off,
                           const int* __restrict__ cnt, const int* __restrict__ nbr,
                           const bf16* __restrict__ w23bT1, const float* __restrict__ vecs,
                           const float* __restrict__ WpWl0, const float* __restrict__ WpWl1,
                           const float* __restrict__ mxp, bf16* __restrict__ aggp,
                           float* __restrict__ bufL, float* __restrict__ bufD,
                           float* __restrict__ blocksums, const int* __restrict__ flags) {
    int t = threadIdx.x;
    int f32m = flags[0];
    if (blockIdx.x < PAT_BLOCKS) {
        __shared__ bf16 hpA[16][HPAD];
        __shared__ float accf[16][APAD];
        __shared__ float svec[6][128];
        __shared__ float s_mxl[16], s_onL[16], s_d0[16], s_d1[16], s_onD[16];
        int w = t >> 6, lane = t & 63;
        int p0 = blockIdx.x * 16;
        {
            const unsigned int* hpu = (const unsigned int*)(hp + (size_t)p0 * H);
            for (int i = t; i < 16 * 64; i += 256) {
                int r = i >> 6, c = i & 63;
                *(unsigned int*)&hpA[r][2 * c] = hpu[(size_t)r * 64 + c];
            }
        }
        {
            const int map[6] = {0, 1, 2, 3, 4, 12};
            for (int i = t; i < 6 * 128; i += 256)
                svec[i >> 7][i & 127] = vecs[map[i >> 7] * 128 + (i & 127)];
        }
        {
            int g = t >> 4, sl = t & 15;
            int p = p0 + g;
            int s1 = off[NL + ND + p], c1 = cnt[NL + ND + p];
            float a = 0.f;
            for (int j = sl; j < c1; j += 16) a += ldin(xl, nbr[s1 + j], f32m);
            a += __shfl_xor(a, 1);
            a += __shfl_xor(a, 2);
            a += __shfl_xor(a, 4);
            a += __shfl_xor(a, 8);
            int s2 = off[NL + ND + NP + p], c2 = cnt[NL + ND + NP + p];
            float d0 = 0.f, d1 = 0.f;
            for (int j = sl; j < c2; j += 16) {
                int q = nbr[s2 + j];
                d0 += ldin(xd, (size_t)2 * q, f32m);
                d1 += ldin(xd, (size_t)2 * q + 1, f32m);
            }
            d0 += __shfl_xor(d0, 1); d0 += __shfl_xor(d0, 2);
            d0 += __shfl_xor(d0, 4); d0 += __shfl_xor(d0, 8);
            d1 += __shfl_xor(d1, 1); d1 += __shfl_xor(d1, 2);
            d1 += __shfl_xor(d1, 4); d1 += __shfl_xor(d1, 8);
            if (sl == 0) {
                s_mxl[g] = a / fmaxf((float)c1, 1.f);
                s_onL[g] = (c1 > 0) ? 1.f : 0.f;
                s_d0[g] = d0 / fmaxf((float)c2, 1.f);
                s_d1[g] = d1 / fmaxf((float)c2, 1.f);
                s_onD[g] = (c2 > 0) ? 1.f : 0.f;
            }
        }
        __syncthreads();
        {
            int m = lane & 15, kg = lane >> 4;
            bf16x8 afr[4];
#pragma unroll
            for (int ks = 0; ks < 4; ++ks)
                afr[ks] = *(const bf16x8*)&hpA[m][ks * 32 + kg * 8];
            int n0 = w * 32;
#pragma unroll
            for (int tt = 0; tt < 2; ++tt) {
                int nc = n0 + tt * 16 + m;
                f32x4 acc = {0.f, 0.f, 0.f, 0.f};
#pragma unroll
                for (int ks = 0; ks < 4; ++ks) {
                    bf16x8 bfr = *(const bf16x8*)&w23bT1[(size_t)nc * H + ks * 32 + kg * 8];
                    acc = __builtin_amdgcn_mfma_f32_16x16x32_bf16(afr[ks], bfr, acc, 0, 0, 0);
                }
#pragma unroll
                for (int rg = 0; rg < 4; ++rg)
                    accf[kg * 4 + rg][nc] = acc[rg];
            }
        }
        __syncthreads();
        for (int i = t; i < 16 * 64; i += 256) {
            int r = i >> 6, cc = (i & 63) * 2;
            float l0 = s_onL[r] * fmaf(s_mxl[r], svec[0][cc], svec[1][cc]);
            float l1 = s_onL[r] * fmaf(s_mxl[r], svec[0][cc + 1], svec[1][cc + 1]);
            float q0 = s_onD[r] * (s_d0[r] * svec[2][cc] + s_d1[r] * svec[3][cc] + svec[4][cc]);
            float q1 = s_onD[r] * (s_d0[r] * svec[2][cc + 1] + s_d1[r] * svec[3][cc + 1] + svec[4][cc + 1]);
            float v0 = accf[r][cc] + l0 + q0 + svec[5][cc];
            float v1 = accf[r][cc + 1] + l1 + q1 + svec[5][cc + 1];
            accf[r][cc] = v0;
            accf[r][cc + 1] = v1;
            st_bf2(aggp + (size_t)(p0 + r) * H + cc, make_float2(v0, v1));
        }
        __syncthreads();
        if (t < 128) {
            float s = 0.f, q = 0.f;
#pragma unroll
            for (int r = 0; r < 16; ++r) {
                float v = accf[r][t];
                s += v;
                q = fmaf(v, v, q);
            }
            blocksums[(size_t)blockIdx.x * 256 + t] = s;
            blocksums[(size_t)blockIdx.x * 256 + 128 + t] = q;
        }
    } else {
        int bb = blockIdx.x - PAT_BLOCKS;
        int rr = bb * 2 + (t >> 7);
        int h = t & 127;
        if (rr >= NROW) return;
        if (rr < NL) {
            float acc = vecs[6 * 128 + h] + ldin(xl, rr, f32m) * vecs[5 * 128 + h];
            if (cnt[rr] > 0) {
                float s = vecs[10 * 128 + h];
                const float* mx = mxp + (size_t)rr * 16;
#pragma unroll
                for (int k = 0; k < 16; ++k) s = fmaf(mx[k], WpWl0[k * H + h], s);
                acc += s;
            }
            bufL[(size_t)rr * H + h] = acc;
        } else {
            int rd = rr - NL;
            float acc = vecs[9 * 128 + h] + ldin(xd, (size_t)2 * rd, f32m) * vecs[7 * 128 + h] +
                        ldin(xd, (size_t)2 * rd + 1, f32m) * vecs[8 * 128 + h];
            if (cnt[rr] > 0) {
                float s = vecs[11 * 128 + h];
                const float* mx = mxp + (size_t)rr * 16;
#pragma unroll
                for (int k = 0; k < 16; ++k) s = fmaf(mx[k], WpWl1[k * H + h], s);
                acc += s;
            }
            bufD[(size_t)rd * H + h] = acc;
        }
    }
}

// -------- bnred: patient stats from blocksums (+ lab/dis stats when grid>64) -----------
__global__ void k_bnred(const float* __restrict__ blocksums, const float* __restrict__ bufL,
                        const float* __restrict__ bufD, float* __restrict__ sums) {
    int b = blockIdx.x, t = threadIdx.x;
    if (b < 64) {
        float acc = 0.f;
        for (int r = b; r < PAT_BLOCKS; r += 64) acc += blocksums[(size_t)r * 256 + t];
        atomicAdd(&sums[t], acc);
        return;
    }
    int h = t & 127;
    int sub = t >> 7;
    float s = 0.f, s2 = 0.f;
    float* sm;
    if (b < 320) {
        int bid = b - 64;
        for (int i = bid * 2 + sub; i < NL; i += 512) {
            float v = bufL[(size_t)i * H + h];
            s += v;
            s2 = fmaf(v, v, s2);
        }
        sm = sums + 2 * H;
    } else {
        int bid = b - 320;
        for (int i = bid * 2 + sub; i < ND; i += 128) {
            float v = bufD[(size_t)i * H + h];
            s += v;
            s2 = fmaf(v, v, s2);
        }
        sm = sums + 4 * H;
    }
    __shared__ float ls[256], ls2[256];
    ls[t] = s;
    ls2[t] = s2;
    __syncthreads();
    if (sub == 0) {
        atomicAdd(&sm[h], s + ls[128 + h]);
        atomicAdd(&sm[H + h], s2 + ls2[128 + h]);
    }
}

// ---- L2 stage1: mm_small (L1 lab/dis BN inline) + prep23 + head-W1 precompute ----------
#define S2_MM 1313
#define S2_PREP 64
#define S2_TOTAL (S2_MM + S2_PREP)
__global__ void k_stage1_L2(const float* __restrict__ bufL, const float* __restrict__ bufD,
                            const float* __restrict__ bns, const void* __restrict__ bng1,
                            const void* __restrict__ bnb1, const void* __restrict__ Wl,
                            bf16* __restrict__ tlp, bf16* __restrict__ tdp,
                            const void* __restrict__ Wr, const void* __restrict__ bl,
                            bf16* __restrict__ w23bT, float* __restrict__ b23,
                            const void* __restrict__ W1in, bf16* __restrict__ w1T,
                            const int* __restrict__ flags) {
    __shared__ float smm[8][H];
    int b = blockIdx.x, t = threadIdx.x;
    int f32m = flags[0];
    if (b < S2_MM) {
        int bb = b;
        bool lab = bb < 1250;
        const float* buf = lab ? bufL : bufD;
        int N = lab ? NL : ND;
        float invN = lab ? 1.f / NL : 1.f / ND;
        int so = lab ? 2 * H : 4 * H;
        int go = lab ? H : 2 * H;
        bf16* outp = lab ? tlp : tdp;
        size_t woff = lab ? (size_t)2 * HH : (size_t)3 * HH;
        int r0 = (lab ? bb : bb - 1250) * 8;
        int h = t & 127, half = t >> 7;
        float m = bns[so + h] * invN;
        float v = fmaf(-m, m, bns[so + H + h] * invN);
        float sc = rsqrtf(v + 1e-5f) * ldin(bng1, go + h, f32m);
        float be = ldin(bnb1, go + h, f32m);
        for (int r = half; r < 8; r += 2) {
            int ri = r0 + r;
            float x = (ri < N) ? buf[(size_t)ri * H + h] : 0.f;
            smm[r][h] = (ri < N) ? fmaxf(fmaf(x - m, sc, be), 0.f) : 0.f;
        }
        __syncthreads();
        int rb = half * 4;
        float a0 = 0.f, a1 = 0.f, a2 = 0.f, a3 = 0.f;
        for (int k = 0; k < H; ++k) {
            float wv = ldin(Wl, woff + (size_t)k * H + h, f32m);
            a0 = fmaf(smm[rb + 0][k], wv, a0);
            a1 = fmaf(smm[rb + 1][k], wv, a1);
            a2 = fmaf(smm[rb + 2][k], wv, a2);
            a3 = fmaf(smm[rb + 3][k], wv, a3);
        }
        float acc[4] = {a0, a1, a2, a3};
#pragma unroll
        for (int r = 0; r < 4; ++r)
            if (r0 + rb + r < N)
                outp[(size_t)(r0 + rb + r) * H + h] = __float2bfloat16(acc[r]);
    } else {
        int pb = b - S2_MM;
        int idx = pb * 256 + t;
        if (idx < HH) {
            int k = idx >> 7, n = idx & 127;
            float v = ldin(Wr, (size_t)2 * HH + idx, f32m) + ldin(Wr, (size_t)3 * HH + idx, f32m);
            w23bT[(size_t)n * H + k] = __float2bfloat16(v);
        }
        if (idx < H)
            b23[idx] = ldin(bl, (size_t)2 * H + idx, f32m) + ldin(bl, (size_t)3 * H + idx, f32m);
        if (idx < 64 * H) {  // head FC1 weight, transposed to [n][k] bf16 for MFMA B-operand
            int n = idx >> 7, k = idx & 127;
            w1T[idx] = __float2bfloat16(ldin(W1in, (size_t)k * 64 + n, f32m));
        }
    }
}

// -------- L2 patmm: in-place aggp update (L1 pat BN inline) + per-block stats -----------
// Gather: half-wave (32 lanes) per patient row, 8 B (4 cols) per lane, software-pipelined
// index prefetch. aggp staging read is non-temporal (read-once). Stores temporal.
__global__ void k_patmm_L2(bf16* __restrict__ aggp, const bf16* __restrict__ tlp,
                           const bf16* __restrict__ tdp, const int* __restrict__ off,
                           const int* __restrict__ cnt, const int* __restrict__ nbr,
                           const bf16* __restrict__ w23bT, const float* __restrict__ b23,
                           const float* __restrict__ bns, const void* __restrict__ bng1,
                           const void* __restrict__ bnb1, float* __restrict__ blocksums,
                           const int* __restrict__ flags) {
    __shared__ bf16 hpA[16][HPAD];
    __shared__ __align__(16) float accf[16][APAD];
    int t = threadIdx.x;
    int f32m = flags[0];
    int w = t >> 6, lane = t & 63;
    int p0 = blockIdx.x * 16;
    {
        int cc = (t & 63) * 2;
        const float invN = 1.f / NP;
        float m0 = bns[cc] * invN, m1 = bns[cc + 1] * invN;
        float v0 = fmaf(-m0, m0, bns[128 + cc] * invN);
        float v1 = fmaf(-m1, m1, bns[128 + cc + 1] * invN);
        float sc0 = rsqrtf(v0 + 1e-5f) * ldin(bng1, cc, f32m);
        float sc1 = rsqrtf(v1 + 1e-5f) * ldin(bng1, cc + 1, f32m);
        float be0 = ldin(bnb1, cc, f32m), be1 = ldin(bnb1, cc + 1, f32m);
        for (int i = t; i < 16 * 64; i += 256) {
            int r = i >> 6;
            float2 v = ld_bf2_nt(aggp + (size_t)(p0 + r) * H + cc);
            st_bf2(&hpA[r][cc], make_float2(fmaxf(fmaf(v.x - m0, sc0, be0), 0.f),
                                            fmaxf(fmaf(v.y - m1, sc1, be1), 0.f)));
        }
    }
    {
        const int* off1 = off + NL + ND;
        const int* cnt1 = cnt + NL + ND;
        const int* off2 = off + NL + ND + NP;
        const int* cnt2 = cnt + NL + ND + NP;
        int hw = t >> 5, hl = t & 31;  // 8 half-waves; each owns 2 patients
        int cb = hl * 4;               // this lane's 4 columns
        float4 bbv = *(const float4*)(b23 + cb);
#pragma unroll
        for (int rp = 0; rp < 2; ++rp) {
            int p = p0 + hw * 2 + rp;
            int s1 = off1[p], c1 = cnt1[p];
            const int* nb1 = nbr + s1;
            float a0 = 0.f, a1 = 0.f, a2 = 0.f, a3 = 0.f;
            float g0 = 0.f, g1 = 0.f, g2 = 0.f, g3 = 0.f;
            int j = 0;
            int i0, i1, i2, i3;
            if (c1 >= 4) { i0 = nb1[0]; i1 = nb1[1]; i2 = nb1[2]; i3 = nb1[3]; }
            for (; j + 8 <= c1; j += 4) {
                uint2 v0 = *(const uint2*)(tlp + (size_t)i0 * H + cb);
                uint2 v1 = *(const uint2*)(tlp + (size_t)i1 * H + cb);
                uint2 v2 = *(const uint2*)(tlp + (size_t)i2 * H + cb);
                uint2 v3 = *(const uint2*)(tlp + (size_t)i3 * H + cb);
                int n0 = nb1[j + 4], n1 = nb1[j + 5], n2 = nb1[j + 6], n3 = nb1[j + 7];
                bfacc2(a0, a1, v0.x); bfacc2(a2, a3, v0.y);
                bfacc2(g0, g1, v1.x); bfacc2(g2, g3, v1.y);
                bfacc2(a0, a1, v2.x); bfacc2(a2, a3, v2.y);
                bfacc2(g0, g1, v3.x); bfacc2(g2, g3, v3.y);
                i0 = n0; i1 = n1; i2 = n2; i3 = n3;
            }
            if (j + 4 <= c1) {
                uint2 v0 = *(const uint2*)(tlp + (size_t)i0 * H + cb);
                uint2 v1 = *(const uint2*)(tlp + (size_t)i1 * H + cb);
                uint2 v2 = *(const uint2*)(tlp + (size_t)i2 * H + cb);
                uint2 v3 = *(const uint2*)(tlp + (size_t)i3 * H + cb);
                bfacc2(a0, a1, v0.x); bfacc2(a2, a3, v0.y);
                bfacc2(g0, g1, v1.x); bfacc2(g2, g3, v1.y);
                bfacc2(a0, a1, v2.x); bfacc2(a2, a3, v2.y);
                bfacc2(g0, g1, v3.x); bfacc2(g2, g3, v3.y);
                j += 4;
            }
            for (; j < c1; ++j) {
                uint2 v = *(const uint2*)(tlp + (size_t)nb1[j] * H + cb);
                bfacc2(a0, a1, v.x); bfacc2(a2, a3, v.y);
            }
            a0 += g0; a1 += g1; a2 += g2; a3 += g3;
            int s2 = off2[p], c2 = cnt2[p];
            const int* nb2 = nbr + s2;
            float d0 = 0.f, d1 = 0.f, d2 = 0.f, d3 = 0.f;
            float e0 = 0.f, e1 = 0.f, e2 = 0.f, e3 = 0.f;
            j = 0;
            int k0, k1;
            if (c2 >= 2) { k0 = nb2[0]; k1 = nb2[1]; }
            for (; j + 4 <= c2; j += 2) {
                uint2 v0 = *(const uint2*)(tdp + (size_t)k0 * H + cb);
                uint2 v1 = *(const uint2*)(tdp + (size_t)k1 * H + cb);
                int n0 = nb2[j + 2], n1 = nb2[j + 3];
                bfacc2(d0, d1, v0.x); bfacc2(d2, d3, v0.y);
                bfacc2(e0, e1, v1.x); bfacc2(e2, e3, v1.y);
                k0 = n0; k1 = n1;
            }
            if (j + 2 <= c2) {
                uint2 v0 = *(const uint2*)(tdp + (size_t)k0 * H + cb);
                uint2 v1 = *(const uint2*)(tdp + (size_t)k1 * H + cb);
                bfacc2(d0, d1, v0.x); bfacc2(d2, d3, v0.y);
                bfacc2(e0, e1, v1.x); bfacc2(e2, e3, v1.y);
                j += 2;
            }
            if (j < c2) {
                uint2 v = *(const uint2*)(tdp + (size_t)nb2[j] * H + cb);
                bfacc2(d0, d1, v.x); bfacc2(d2, d3, v.y);
            }
            d0 += e0; d1 += e1; d2 += e2; d3 += e3;
            float i1f = 1.f / fmaxf((float)c1, 1.f), i2f = 1.f / fmaxf((float)c2, 1.f);
            float4 res;
            res.x = a0 * i1f + d0 * i2f + bbv.x;
            res.y = a1 * i1f + d1 * i2f + bbv.y;
            res.z = a2 * i1f + d2 * i2f + bbv.z;
            res.w = a3 * i1f + d3 * i2f + bbv.w;
            *(float4*)&accf[hw * 2 + rp][cb] = res;
        }
    }
    __syncthreads();
    {
        int m = lane & 15, kg = lane >> 4;
        bf16x8 afr[4];
#pragma unroll
        for (int ks = 0; ks < 4; ++ks)
            afr[ks] = *(const bf16x8*)&hpA[m][ks * 32 + kg * 8];
        int n0 = w * 32;
#pragma unroll
        for (int tt = 0; tt < 2; ++tt) {
            int nc = n0 + tt * 16 + m;
            f32x4 acc = {0.f, 0.f, 0.f, 0.f};
#pragma unroll
            for (int ks = 0; ks < 4; ++ks) {
                bf16x8 bfr = *(const bf16x8*)&w23bT[(size_t)nc * H + ks * 32 + kg * 8];
                acc = __builtin_amdgcn_mfma_f32_16x16x32_bf16(afr[ks], bfr, acc, 0, 0, 0);
            }
#pragma unroll
            for (int rg = 0; rg < 4; ++rg)
                accf[kg * 4 + rg][nc] += acc[rg];
        }
    }
    __syncthreads();
    for (int i = t; i < 16 * 64; i += 256) {
        int r = i >> 6, cc = (i & 63) * 2;
        st_bf2(aggp + (size_t)(p0 + r) * H + cc, make_float2(accf[r][cc], accf[r][cc + 1]));
    }
    if (t < 128) {
        float s = 0.f, q = 0.f;
#pragma unroll
        for (int r = 0; r < 16; ++r) {
            float v = accf[r][t];
            s += v;
            q = fmaf(v, v, q);
        }
        blocksums[(size_t)blockIdx.x * 256 + t] = s;
        blocksums[(size_t)blockIdx.x * 256 + 128 + t] = q;
    }
}

// ---------------- head: fused L2 patient BN+ReLU -> MFMA FC1 -> FC2 -> log_softmax ------
__global__ void k_head(const bf16* __restrict__ aggp, const float* __restrict__ sums,
                       const void* __restrict__ bng, const void* __restrict__ bnb,
                       const bf16* __restrict__ w1T, const void* __restrict__ b1,
                       const void* __restrict__ W2, const void* __restrict__ b2f,
                       void* __restrict__ out, const int* __restrict__ flags) {
    int f32m = flags[0];
    __shared__ bf16 hpA[16][HPAD];
    __shared__ float h1s[16][68];
    __shared__ float lgs[16][16];
    __shared__ float W2s[64 * NOUT];
    __shared__ float b1s[64], b2s[NOUT];
    int t = threadIdx.x;
    int w = t >> 6, lane = t & 63;
    for (int i = t; i < 64 * NOUT; i += 256) W2s[i] = ldin(W2, i, f32m);
    if (t < 64) b1s[t] = ldin(b1, t, f32m);
    else if (t >= 64 && t < 64 + NOUT) b2s[t - 64] = ldin(b2f, t - 64, f32m);
    int p0 = blockIdx.x * 16;
    {
        int cc = (t & 63) * 2;
        const float invN = 1.f / NP;
        float m0 = sums[cc] * invN, m1 = sums[cc + 1] * invN;
        float v0 = fmaf(-m0, m0, sums[128 + cc] * invN);
        float v1 = fmaf(-m1, m1, sums[128 + cc + 1] * invN);
        float sc0 = rsqrtf(v0 + 1e-5f) * ldin(bng, cc, f32m);
        float sc1 = rsqrtf(v1 + 1e-5f) * ldin(bng, cc + 1, f32m);
        float be0 = ldin(bnb, cc, f32m), be1 = ldin(bnb, cc + 1, f32m);
        for (int i = t; i < 16 * 64; i += 256) {
            int r = i >> 6;
            float2 v = ld_bf2(aggp + (size_t)(p0 + r) * H + cc);
            st_bf2(&hpA[r][cc], make_float2(fmaxf(fmaf(v.x - m0, sc0, be0), 0.f),
                                            fmaxf(fmaf(v.y - m1, sc1, be1), 0.f)));
        }
    }
    __syncthreads();
    {
        // MFMA FC1: wave w computes output cols [w*16, w*16+16); K=128 over 4 ksteps.
        int m = lane & 15, kg = lane >> 4;
        bf16x8 afr[4];
#pragma unroll
        for (int ks = 0; ks < 4; ++ks)
            afr[ks] = *(const bf16x8*)&hpA[m][ks * 32 + kg * 8];
        int nc = w * 16 + m;
        f32x4 acc = {0.f, 0.f, 0.f, 0.f};
#pragma unroll
        for (int ks = 0; ks < 4; ++ks) {
            bf16x8 bfr = *(const bf16x8*)&w1T[(size_t)nc * H + ks * 32 + kg * 8];
            acc = __builtin_amdgcn_mfma_f32_16x16x32_bf16(afr[ks], bfr, acc, 0, 0, 0);
        }
        float bv = b1s[nc];
#pragma unroll
        for (int rg = 0; rg < 4; ++rg)
            h1s[kg * 4 + rg][nc] = fmaxf(acc[rg] + bv, 0.f);
    }
    __syncthreads();
    int pat = lane >> 4, oidx = lane & 15;
    int prow = 4 * w + pat;
    float lg = 0.f;
    if (oidx < NOUT) {
        lg = b2s[oidx];
        const float* hh = h1s[prow];
#pragma unroll 8
        for (int k = 0; k < 64; ++k) lg = fmaf(hh[k], W2s[k * NOUT + oidx], lg);
        lgs[prow][oidx] = lg;
    }
    __syncthreads();
    if (oidx < NOUT) {
        float m = -1e30f;
#pragma unroll
        for (int k = 0; k < NOUT; ++k) m = fmaxf(m, lgs[prow][k]);
        float s = 0.f;
#pragma unroll
        for (int k = 0; k < NOUT; ++k) s += __expf(lgs[prow][k] - m);
        float r = lg - m - __logf(s);
        if (f32m)
            ((float*)out)[(size_t)(p0 + prow) * NOUT + oidx] = r;
        else
            ((bf16*)out)[(size_t)(p0 + prow) * NOUT + oidx] = __float2bfloat16(r);
    }
}

extern "C" void kernel_launch(void* const* d_in, const int* in_sizes, int n_in, void* d_out,
                              int out_size, void* d_ws, size_t ws_size, hipStream_t stream) {
    const int* e1s = (const int*)d_in[23];
    const int* e1d = (const int*)d_in[24];
    const int* e2s = (const int*)d_in[25];
    const int* e2d = (const int*)d_in[26];
    const int NPOOL = 2 * (E1 + E2);

    char* wsb = (char*)d_ws;
    size_t o = 0;
    auto af = [&](size_t nwords) { void* p = wsb + o * 4; o += nwords; return p; };
    int* flags = (int*)af(16);
    bf16* w23bT = (bf16*)af(HH / 2);
    bf16* w23bT1 = (bf16*)af(HH / 2);
    bf16* w1T = (bf16*)af(64 * H / 2);
    float* b23 = (float*)af(H);
    float* bns = (float*)af(8 * H);
    int* bsums = (int*)af(256);
    float* WpWl0 = (float*)af(16 * H);
    float* WpWl1 = (float*)af(16 * H);
    float* vecs = (float*)af(13 * 128);
    int* cnt = (int*)af(NCNT);
    int* off = (int*)af(NCNT);
    int* nbr = (int*)af(NPOOL);
    bf16* hp = (bf16*)af((size_t)NP * H / 2);
    bf16* xpb = (bf16*)af((size_t)NP * 16 / 2);
    size_t arena = o;
    unsigned char* r1s = (unsigned char*)af(E1 / 4);
    unsigned char* r2s = (unsigned char*)af(E2 / 4);
    unsigned int* labHistP = (unsigned int*)af((size_t)NCH1 * NPW);
    unsigned int* disHistP = (unsigned int*)af((size_t)NCH2 * NPW);
    unsigned int* labHist = (unsigned int*)af((size_t)LABHB * NL);
    unsigned int* disHist = (unsigned int*)af((size_t)DISHB * ND);
    size_t endA = o;
    o = arena;
    float* bufL = (float*)af((size_t)NL * H);
    float* bufD = (float*)af((size_t)ND * H);
    bf16* tlp = (bf16*)af((size_t)NL * H / 2);
    bf16* tdp = (bf16*)af((size_t)ND * H / 2);
    bf16* aggp = (bf16*)af((size_t)NP * H / 2);
    float* mxp = (float*)af((size_t)NROW * 16);
    float* blocksums = (float*)af((size_t)PAT_BLOCKS * 256);
    size_t endB = o;
    o = endA > endB ? endA : endB;
    (void)ws_size;

    k_hist<<<HB3 + 1, 1024, 0, stream>>>(e1s, e1d, e2s, e2d, labHistP, disHistP, r1s, r2s,
                                         labHist, disHist, (const unsigned short*)d_in[0],
                                         flags);
    k_reduce<<<RB7, 256, 0, stream>>>(labHist, disHist, labHistP, disHistP, cnt, d_in[0],
                                      d_in[3], d_in[4], d_in[5], d_in[6], d_in[7], d_in[8],
                                      d_in[9], d_in[10], d_in[11], hp, WpWl0, WpWl1, vecs,
                                      w23bT1, xpb, flags);
    int nb = (NCNT + SCAN_ELEMS - 1) / SCAN_ELEMS;
    k_scan1<<<nb, 256, 0, stream>>>(cnt, off, bsums, NCNT);
    k_scan2<<<1, 256, 0, stream>>>(bsums, nb);
    k_scan3<<<(NCNT + 255) / 256, 256, 0, stream>>>(off, bsums, NCNT);
    k_fill<<<CNT_BLOCKS + LABHB + DISHB + 1, 256, 0, stream>>>(
        e1s, e1d, e2s, e2d, off, r1s, r2s, (const unsigned char*)labHistP,
        (const unsigned char*)disHistP, labHist, disHist, nbr, bns);

    // ---- layer 1 (algebraically collapsed) ----
    k_stage1_L1<<<(NROW + 3) / 4, 256, 0, stream>>>(xpb, off, cnt, nbr, mxp);
    k_patmm_L1<<<PAT_BLOCKS + LD1_BLOCKS, 256, 0, stream>>>(hp, d_in[1], d_in[2], off, cnt, nbr,
                                                            w23bT1, vecs, WpWl0, WpWl1, mxp,
                                                            aggp, bufL, bufD, blocksums, flags);
    k_bnred<<<384, 256, 0, stream>>>(blocksums, bufL, bufD, bns);

    // ---- layer 2: all BN applications fused into consumers ----
    k_stage1_L2<<<S2_TOTAL, 256, 0, stream>>>(bufL, bufD, bns, d_in[15], d_in[16], d_in[12],
                                              tlp, tdp, d_in[14], d_in[13], w23bT, b23,
                                              d_in[19], w1T, flags);
    k_patmm_L2<<<PAT_BLOCKS, 256, 0, stream>>>(aggp, tlp, tdp, off, cnt, nbr, w23bT, b23, bns,
                                               d_in[15], d_in[16], blocksums, flags);
    k_bnred<<<64, 256, 0, stream>>>(blocksums, bufL, bufD, bns + 6 * H);
    k_head<<<NP / 16, 256, 0, stream>>>(aggp, bns + 6 * H, d_in[17], d_in[18], w1T,
                                        d_in[20], d_in[21], d_in[22], d_out, flags);
}

// Round 10
// 560.669 us; speedup vs baseline: 1.2852x; 1.0292x over previous
//
#include <hip/hip_runtime.h>
#include <hip/hip_bf16.h>

#define NP 100000
#define NL 10000
#define ND 500
#define H 128
#define HH (H * H)
#define E1 2000000
#define E2 500000
#define NOUT 10
#define NCNT (NL + ND + 2 * NP)
#define NROW (NL + ND)
#define CHUNK 8192
#define LABHB ((E1 + CHUNK - 1) / CHUNK)
#define DISHB ((E2 + CHUNK - 1) / CHUNK)
#define CNT_BLOCKS ((E1 + E2 + 255) / 256)
#define EMBP ((NP * H + 255) / 256)
#define RED_LAB ((NL + 255) / 256)
#define RED_DIS ((ND + 255) / 256)
#define PAT_BLOCKS (NP / 16)

// patient-side chunked LDS histogram sort (replaces global atomics)
#define CHP 15625
#define NCH1 (E1 / CHP) /* 128 */
#define NCH2 (E2 / CHP) /* 32 */
#define NPW (NP / 4)    /* 25000 packed-byte words = 100 KB LDS */
#define RPW ((NPW + 255) / 256)

typedef __hip_bfloat16 bf16;
typedef __attribute__((ext_vector_type(8))) short bf16x8;
typedef __attribute__((ext_vector_type(4))) float f32x4;

__device__ __forceinline__ float bfbits2f(unsigned short s) {
    union { unsigned int u; float f; } v;
    v.u = (unsigned int)s << 16;
    return v.f;
}
__device__ __forceinline__ float2 ld_bf2(const bf16* p) {
    unsigned int u = *(const unsigned int*)p;
    return make_float2(bfbits2f((unsigned short)(u & 0xFFFFu)), bfbits2f((unsigned short)(u >> 16)));
}
__device__ __forceinline__ float2 ld_bf2_nt(const bf16* p) {
    unsigned int u = __builtin_nontemporal_load((const unsigned int*)p);
    return make_float2(bfbits2f((unsigned short)(u & 0xFFFFu)), bfbits2f((unsigned short)(u >> 16)));
}
__device__ __forceinline__ void st_bf2(bf16* p, float2 v) {
    union { unsigned int u; bf16 b[2]; } t;
    t.b[0] = __float2bfloat16(v.x);
    t.b[1] = __float2bfloat16(v.y);
    *(unsigned int*)p = t.u;
}
__device__ __forceinline__ float ldin(const void* p, size_t i, int f32m) {
    return f32m ? ((const float*)p)[i] : __bfloat162float(((const bf16*)p)[i]);
}
// accumulate 2 packed bf16 (one u32) into two f32 accumulators: 2 unpack + 2 add VALU
__device__ __forceinline__ void bfacc2(float& x, float& y, unsigned int u) {
    union { unsigned int q; float f; } lo, hi;
    lo.q = u << 16;
    hi.q = u & 0xFFFF0000u;
    x += lo.f;
    y += hi.f;
}

// ---- k_hist: all histograms via LDS (no global atomics), 1024 threads -----------------
// Last block (b == HB3) performs input-dtype detection (folded k_detect).
#define HB0 NCH1
#define HB1 (HB0 + NCH2)
#define HB2 (HB1 + LABHB)
#define HB3 (HB2 + DISHB)
__global__ void k_hist(const int* __restrict__ e1s, const int* __restrict__ e1d,
                       const int* __restrict__ e2s, const int* __restrict__ e2d,
                       unsigned int* __restrict__ labHistP, unsigned int* __restrict__ disHistP,
                       unsigned char* __restrict__ r1s, unsigned char* __restrict__ r2s,
                       unsigned int* __restrict__ labHist, unsigned int* __restrict__ disHist,
                       const unsigned short* __restrict__ xpw, int* __restrict__ flags) {
    __shared__ unsigned int sh[NPW];  // 100 KB: byte-packed patient counters / reused by dest hists
    int b = blockIdx.x, t = threadIdx.x;
    if (b < HB1) {
        for (int i = t; i < NPW; i += 1024) sh[i] = 0;
        __syncthreads();
        if (b < HB0) {
            int e0 = b * CHP;
            for (int j = t; j < CHP; j += 1024) {
                int e = e0 + j;
                int ss = e1s[e];
                unsigned int old = atomicAdd(&sh[ss >> 2], 1u << (8 * (ss & 3)));
                r1s[e] = (unsigned char)(old >> (8 * (ss & 3)));
            }
            __syncthreads();
            unsigned int* out = labHistP + (size_t)b * NPW;
            for (int i = t; i < NPW; i += 1024) out[i] = sh[i];
        } else {
            int c = b - HB0;
            int e0 = c * CHP;
            for (int j = t; j < CHP; j += 1024) {
                int e = e0 + j;
                int ss = e2s[e];
                unsigned int old = atomicAdd(&sh[ss >> 2], 1u << (8 * (ss & 3)));
                r2s[e] = (unsigned char)(old >> (8 * (ss & 3)));
            }
            __syncthreads();
            unsigned int* out = disHistP + (size_t)c * NPW;
            for (int i = t; i < NPW; i += 1024) out[i] = sh[i];
        }
    } else if (b < HB2) {
        int c = b - HB1;
        for (int i = t; i < NL / 2; i += 1024) sh[i] = 0;
        __syncthreads();
        int e0 = c * CHUNK, ee = min(E1, e0 + CHUNK);
        for (int e = e0 + t; e < ee; e += 1024) {
            int dd = e1d[e];
            atomicAdd(&sh[dd >> 1], 1u << (16 * (dd & 1)));
        }
        __syncthreads();
        for (int i = t; i < NL; i += 1024)
            labHist[(size_t)c * NL + i] = (sh[i >> 1] >> (16 * (i & 1))) & 0xFFFFu;
    } else if (b < HB3) {
        int c = b - HB2;
        for (int i = t; i < ND / 2; i += 1024) sh[i] = 0;
        __syncthreads();
        int e0 = c * CHUNK, ee = min(E2, e0 + CHUNK);
        for (int e = e0 + t; e < ee; e += 1024) {
            int dd = e2d[e];
            atomicAdd(&sh[dd >> 1], 1u << (16 * (dd & 1)));
        }
        __syncthreads();
        for (int i = t; i < ND; i += 1024)
            disHist[(size_t)c * ND + i] = (sh[i >> 1] >> (16 * (i & 1))) & 0xFFFFu;
    } else {
        // dtype detection (flags consumed first by k_reduce, next in stream order)
        int cnt = 0;
        for (int i = t; i < 4096; i += 1024) {
            unsigned short w = xpw[2 * i];
            int e = (w >> 7) & 0xFF;
            if (w == 0 || (e >= 114 && e <= 141)) cnt++;
        }
        int* shi = (int*)sh;
        shi[t] = cnt;
        __syncthreads();
        for (int s = 512; s > 0; s >>= 1) {
            if (t < s) shi[t] += shi[t + s];
            __syncthreads();
        }
        if (t == 0) flags[0] = (shi[0] < 2048) ? 1 : 0;
    }
}

// ---- reduce: chunk exclusive bases (packed-byte scan for patients); totals -> cnt ------
#define RB0 RED_LAB
#define RB1 (RB0 + RED_DIS)
#define RB2 (RB1 + RPW)
#define RB3 (RB2 + RPW)
#define RB4 (RB3 + EMBP)
#define RB5 (RB4 + 16)
#define RB6 (RB5 + 7)
#define RB7 (RB6 + 64)
__global__ void k_reduce(unsigned int* __restrict__ labHist, unsigned int* __restrict__ disHist,
                         unsigned int* __restrict__ labHistP, unsigned int* __restrict__ disHistP,
                         int* __restrict__ cnt, const void* __restrict__ xp,
                         const void* __restrict__ Wp, const void* __restrict__ bp,
                         const void* __restrict__ Wlab, const void* __restrict__ blab,
                         const void* __restrict__ Wdis, const void* __restrict__ bdis,
                         const void* __restrict__ Wl1, const void* __restrict__ bl1,
                         const void* __restrict__ Wr1, bf16* __restrict__ hp,
                         float* __restrict__ WpWl0, float* __restrict__ WpWl1,
                         float* __restrict__ vecs, bf16* __restrict__ w23bT1,
                         bf16* __restrict__ xpb, const int* __restrict__ flags) {
    int b = blockIdx.x, t = threadIdx.x;
    if (b < RB0) {
        int bin = b * 256 + t;
        if (bin < NL) {
            unsigned int run = 0;
            for (int k = 0; k < LABHB; ++k) {
                unsigned int x = labHist[(size_t)k * NL + bin];
                labHist[(size_t)k * NL + bin] = run;
                run += x;
            }
            cnt[bin] = (int)run;
        }
    } else if (b < RB1) {
        int bin = (b - RB0) * 256 + t;
        if (bin < ND) {
            unsigned int run = 0;
            for (int k = 0; k < DISHB; ++k) {
                unsigned int x = disHist[(size_t)k * ND + bin];
                disHist[(size_t)k * ND + bin] = run;
                run += x;
            }
            cnt[NL + bin] = (int)run;
        }
    } else if (b < RB2) {
        int w = (b - RB1) * 256 + t;
        if (w < NPW) {
            unsigned int run = 0;  // 4 byte-lanes scanned in parallel; degree < 256 so no carry
            for (int c = 0; c < NCH1; ++c) {
                unsigned int x = labHistP[(size_t)c * NPW + w];
                labHistP[(size_t)c * NPW + w] = run;
                run += x;
            }
            int base = NL + ND + 4 * w;
            cnt[base] = (int)(run & 0xFFu);
            cnt[base + 1] = (int)((run >> 8) & 0xFFu);
            cnt[base + 2] = (int)((run >> 16) & 0xFFu);
            cnt[base + 3] = (int)(run >> 24);
        }
    } else if (b < RB3) {
        int w = (b - RB2) * 256 + t;
        if (w < NPW) {
            unsigned int run = 0;
            for (int c = 0; c < NCH2; ++c) {
                unsigned int x = disHistP[(size_t)c * NPW + w];
                disHistP[(size_t)c * NPW + w] = run;
                run += x;
            }
            int base = NL + ND + NP + 4 * w;
            cnt[base] = (int)(run & 0xFFu);
            cnt[base + 1] = (int)((run >> 8) & 0xFFu);
            cnt[base + 2] = (int)((run >> 16) & 0xFFu);
            cnt[base + 3] = (int)(run >> 24);
        }
    } else if (b < RB4) {
        int f32m = flags[0];
        int idx = (b - RB3) * 256 + t;
        int h = idx & 127;
        int i = idx >> 7;
        float acc = ldin(bp, h, f32m);
#pragma unroll
        for (int k = 0; k < 16; ++k)
            acc = fmaf(ldin(xp, (size_t)i * 16 + k, f32m), ldin(Wp, (size_t)k * H + h, f32m), acc);
        hp[idx] = __float2bfloat16(acc);
        if (h < 16)  // bf16 copy of xp for the stage1_L1 gather (halves its row bytes)
            xpb[(size_t)i * 16 + h] = __float2bfloat16(ldin(xp, (size_t)i * 16 + h, f32m));
    } else if (b < RB5) {
        int f32m = flags[0];
        int pb = b - RB4;
        bool first = pb < 8;
        size_t woff = first ? 0 : (size_t)HH;
        float* outp = first ? WpWl0 : WpWl1;
        int k = (first ? pb : pb - 8) * 2 + (t >> 7);
        int h = t & 127;
        float s = 0.f;
        for (int m = 0; m < H; ++m)
            s = fmaf(ldin(Wp, (size_t)k * H + m, f32m), ldin(Wl1, woff + (size_t)m * H + h, f32m), s);
        outp[k * H + h] = s;
    } else if (b < RB6) {
        int f32m = flags[0];
        int idx = (b - RB5) * 256 + t;
        if (idx < 13 * 128) {
            int v = idx >> 7, h = idx & 127;
            float s = 0.f;
            if (v == 12) {
                s = ldin(bl1, 2 * H + h, f32m) + ldin(bl1, 3 * H + h, f32m);
            } else {
                const void* A;
                size_t aoff = 0;
                const void* W;
                size_t woff;
                float add = 0.f;
                switch (v) {
                    case 0: A = Wlab; W = Wl1; woff = 2 * (size_t)HH; break;
                    case 1: A = blab; W = Wl1; woff = 2 * (size_t)HH; break;
                    case 2: A = Wdis; W = Wl1; woff = 3 * (size_t)HH; break;
                    case 3: A = Wdis; aoff = H; W = Wl1; woff = 3 * (size_t)HH; break;
                    case 4: A = bdis; W = Wl1; woff = 3 * (size_t)HH; break;
                    case 5: A = Wlab; W = Wr1; woff = 0; break;
                    case 6: A = blab; W = Wr1; woff = 0; add = ldin(bl1, h, f32m); break;
                    case 7: A = Wdis; W = Wr1; woff = (size_t)HH; break;
                    case 8: A = Wdis; aoff = H; W = Wr1; woff = (size_t)HH; break;
                    case 9: A = bdis; W = Wr1; woff = (size_t)HH; add = ldin(bl1, H + h, f32m); break;
                    case 10: A = bp; W = Wl1; woff = 0; break;
                    default: A = bp; W = Wl1; woff = (size_t)HH; break;
                }
                for (int m = 0; m < H; ++m)
                    s = fmaf(ldin(A, aoff + m, f32m), ldin(W, woff + (size_t)m * H + h, f32m), s);
                s += add;
            }
            vecs[v * 128 + h] = s;
        }
    } else {
        int f32m = flags[0];
        int idx = (b - RB6) * 256 + t;
        if (idx < HH) {
            int k = idx >> 7, n = idx & 127;
            float v = ldin(Wr1, (size_t)2 * HH + idx, f32m) + ldin(Wr1, (size_t)3 * HH + idx, f32m);
            w23bT1[(size_t)n * H + k] = __float2bfloat16(v);
        }
    }
}

#define SCAN_ELEMS 2048
__global__ void k_scan1(const int* __restrict__ in, int* __restrict__ out,
                        int* __restrict__ bsums, int n) {
    int t = threadIdx.x;
    int base = blockIdx.x * SCAN_ELEMS + t * 8;
    int v[8], tsum = 0;
#pragma unroll
    for (int j = 0; j < 8; ++j) {
        v[j] = (base + j < n) ? in[base + j] : 0;
        tsum += v[j];
    }
    __shared__ int sh[256];
    sh[t] = tsum;
    __syncthreads();
    for (int d = 1; d < 256; d <<= 1) {
        int x = (t >= d) ? sh[t - d] : 0;
        __syncthreads();
        sh[t] += x;
        __syncthreads();
    }
    int run = sh[t] - tsum;
    if (t == 255) bsums[blockIdx.x] = sh[255];
#pragma unroll
    for (int j = 0; j < 8; ++j) {
        if (base + j < n) out[base + j] = run;
        run += v[j];
    }
}

__global__ void k_scan2(int* __restrict__ bsums, int nb) {
    int t = threadIdx.x;
    int v = (t < nb) ? bsums[t] : 0;
    __shared__ int sh[256];
    sh[t] = v;
    __syncthreads();
    for (int d = 1; d < 256; d <<= 1) {
        int x = (t >= d) ? sh[t - d] : 0;
        __syncthreads();
        sh[t] += x;
        __syncthreads();
    }
    if (t < nb) bsums[t] = sh[t] - v;
}

__global__ void k_scan3(int* __restrict__ out, const int* __restrict__ bsums, int n) {
    int i = blockIdx.x * 256 + threadIdx.x;
    if (i < n) out[i] += bsums[i / SCAN_ELEMS];
}

// ---- fill (+ last block zeros bns: 8 segments) ----------------------------------------
__global__ void k_fill(const int* __restrict__ e1s, const int* __restrict__ e1d,
                       const int* __restrict__ e2s, const int* __restrict__ e2d,
                       const int* __restrict__ off, const unsigned char* __restrict__ r1s,
                       const unsigned char* __restrict__ r2s,
                       const unsigned char* __restrict__ labBase,
                       const unsigned char* __restrict__ disBase,
                       const unsigned int* __restrict__ labHist,
                       const unsigned int* __restrict__ disHist, int* __restrict__ nbr,
                       float* __restrict__ bns) {
    __shared__ unsigned int slot[NL];
    int b = blockIdx.x, t = threadIdx.x;
    if (b < CNT_BLOCKS) {
        int e = b * 256 + t;
        if (e < E1) {
            int ss = e1s[e];
            int c = e / CHP;
            int pos = off[NL + ND + ss] + (int)labBase[(size_t)c * NP + ss] + (int)r1s[e];
            nbr[pos] = e1d[e];
        } else if (e < E1 + E2) {
            int i = e - E1;
            int ss = e2s[i];
            int c = i / CHP;
            int pos = off[NL + ND + NP + ss] + (int)disBase[(size_t)c * NP + ss] + (int)r2s[i];
            nbr[pos] = e2d[i];
        }
    } else if (b < CNT_BLOCKS + LABHB) {
        int c = b - CNT_BLOCKS;
        for (int i = t; i < NL; i += 256)
            slot[i] = (unsigned int)off[i] + labHist[(size_t)c * NL + i];
        __syncthreads();
        int e0 = c * CHUNK, ee = min(E1, e0 + CHUNK);
        for (int e = e0 + t; e < ee; e += 256) {
            unsigned int pos = atomicAdd(&slot[e1d[e]], 1u);
            nbr[pos] = e1s[e];
        }
    } else if (b < CNT_BLOCKS + LABHB + DISHB) {
        int c = b - CNT_BLOCKS - LABHB;
        for (int i = t; i < ND; i += 256)
            slot[i] = (unsigned int)off[NL + i] + disHist[(size_t)c * ND + i];
        __syncthreads();
        int e0 = c * CHUNK, ee = min(E2, e0 + CHUNK);
        for (int e = e0 + t; e < ee; e += 256) {
            unsigned int pos = atomicAdd(&slot[e2d[e]], 1u);
            nbr[pos] = e2s[e];
        }
    } else {
        for (int i = t; i < 8 * H; i += 256) bns[i] = 0.f;
    }
}

// ---------------- L1 stage1: gather 16-dim mean of x_p per lab/dis row ------------------
// Lane-per-neighbor from the bf16 copy xpb: 32 B per neighbor row (half the f32 bytes),
// 64-128 gathers in flight per wave. Block LDS reduce at the end.
__global__ void k_stage1_L1(const bf16* __restrict__ xpb, const int* __restrict__ off,
                            const int* __restrict__ cnt, const int* __restrict__ nbr,
                            float* __restrict__ mxp) {
    __shared__ float red[4][64][16];  // 16 KB
    int t = threadIdx.x;
    int w = t >> 6, lane = t & 63;
    int row = blockIdx.x * 4 + w;
    float acc[16];
#pragma unroll
    for (int d = 0; d < 16; ++d) acc[d] = 0.f;
    if (row < NROW) {
        int s0 = off[row], c = cnt[row];
        const int* nb = nbr + s0;
        int j = lane;
        for (; j + 64 < c; j += 128) {
            int p0 = nb[j], p1 = nb[j + 64];
            const uint4* r0 = (const uint4*)(xpb + (size_t)p0 * 16);
            const uint4* r1 = (const uint4*)(xpb + (size_t)p1 * 16);
            uint4 u0 = r0[0], u1 = r0[1];
            uint4 v0 = r1[0], v1 = r1[1];
            bfacc2(acc[0], acc[1], u0.x);   bfacc2(acc[2], acc[3], u0.y);
            bfacc2(acc[4], acc[5], u0.z);   bfacc2(acc[6], acc[7], u0.w);
            bfacc2(acc[8], acc[9], u1.x);   bfacc2(acc[10], acc[11], u1.y);
            bfacc2(acc[12], acc[13], u1.z); bfacc2(acc[14], acc[15], u1.w);
            bfacc2(acc[0], acc[1], v0.x);   bfacc2(acc[2], acc[3], v0.y);
            bfacc2(acc[4], acc[5], v0.z);   bfacc2(acc[6], acc[7], v0.w);
            bfacc2(acc[8], acc[9], v1.x);   bfacc2(acc[10], acc[11], v1.y);
            bfacc2(acc[12], acc[13], v1.z); bfacc2(acc[14], acc[15], v1.w);
        }
        if (j < c) {
            const uint4* r0 = (const uint4*)(xpb + (size_t)nb[j] * 16);
            uint4 u0 = r0[0], u1 = r0[1];
            bfacc2(acc[0], acc[1], u0.x);   bfacc2(acc[2], acc[3], u0.y);
            bfacc2(acc[4], acc[5], u0.z);   bfacc2(acc[6], acc[7], u0.w);
            bfacc2(acc[8], acc[9], u1.x);   bfacc2(acc[10], acc[11], u1.y);
            bfacc2(acc[12], acc[13], u1.z); bfacc2(acc[14], acc[15], u1.w);
        }
    }
#pragma unroll
    for (int d = 0; d < 16; ++d) red[w][lane][d] = acc[d];
    __syncthreads();
    if (t < 64) {
        int w2 = t >> 4, d = t & 15;
        int row2 = blockIdx.x * 4 + w2;
        if (row2 < NROW) {
            float s = 0.f;
#pragma unroll 8
            for (int l = 0; l < 64; ++l) s += red[w2][l][d];
            mxp[(size_t)row2 * 16 + d] = s / fmaxf((float)cnt[row2], 1.f);
        }
    }
}

// -------- L1 patmm: scalar gathers + MFMA | lab/dis affine | per-block stats ------------
#define LD1_BLOCKS ((NROW + 1) / 2)
#define HPAD 136
#define APAD 132
__global__ void k_patmm_L1(const bf16* __restrict__ hp, const void* __restrict__ xl,
                           const void* __restrict__ xd, const int* __restrict__ off,
                           const int* __restrict__ cnt, const int* __restrict__ nbr,
                           const bf16* __restrict__ w23bT1, const float* __restrict__ vecs,
                           const float* __restrict__ WpWl0, const float* __restrict__ WpWl1,
                           const float* __restrict__ mxp, bf16* __restrict__ aggp,
                           float* __restrict__ bufL, float* __restrict__ bufD,
                           float* __restrict__ blocksums, const int* __restrict__ flags) {
    int t = threadIdx.x;
    int f32m = flags[0];
    if (blockIdx.x < PAT_BLOCKS) {
        __shared__ bf16 hpA[16][HPAD];
        __shared__ float accf[16][APAD];
        __shared__ float svec[6][128];
        __shared__ float s_mxl[16], s_onL[16], s_d0[16], s_d1[16], s_onD[16];
        int w = t >> 6, lane = t & 63;
        int p0 = blockIdx.x * 16;
        {
            const unsigned int* hpu = (const unsigned int*)(hp + (size_t)p0 * H);
            for (int i = t; i < 16 * 64; i += 256) {
                int r = i >> 6, c = i & 63;
                *(unsigned int*)&hpA[r][2 * c] = hpu[(size_t)r * 64 + c];
            }
        }
        {
            const int map[6] = {0, 1, 2, 3, 4, 12};
            for (int i = t; i < 6 * 128; i += 256)
                svec[i >> 7][i & 127] = vecs[map[i >> 7] * 128 + (i & 127)];
        }
        {
            int g = t >> 4, sl = t & 15;
            int p = p0 + g;
            int s1 = off[NL + ND + p], c1 = cnt[NL + ND + p];
            float a = 0.f;
            for (int j = sl; j < c1; j += 16) a += ldin(xl, nbr[s1 + j], f32m);
            a += __shfl_xor(a, 1);
            a += __shfl_xor(a, 2);
            a += __shfl_xor(a, 4);
            a += __shfl_xor(a, 8);
            int s2 = off[NL + ND + NP + p], c2 = cnt[NL + ND + NP + p];
            float d0 = 0.f, d1 = 0.f;
            for (int j = sl; j < c2; j += 16) {
                int q = nbr[s2 + j];
                d0 += ldin(xd, (size_t)2 * q, f32m);
                d1 += ldin(xd, (size_t)2 * q + 1, f32m);
            }
            d0 += __shfl_xor(d0, 1); d0 += __shfl_xor(d0, 2);
            d0 += __shfl_xor(d0, 4); d0 += __shfl_xor(d0, 8);
            d1 += __shfl_xor(d1, 1); d1 += __shfl_xor(d1, 2);
            d1 += __shfl_xor(d1, 4); d1 += __shfl_xor(d1, 8);
            if (sl == 0) {
                s_mxl[g] = a / fmaxf((float)c1, 1.f);
                s_onL[g] = (c1 > 0) ? 1.f : 0.f;
                s_d0[g] = d0 / fmaxf((float)c2, 1.f);
                s_d1[g] = d1 / fmaxf((float)c2, 1.f);
                s_onD[g] = (c2 > 0) ? 1.f : 0.f;
            }
        }
        __syncthreads();
        {
            int m = lane & 15, kg = lane >> 4;
            bf16x8 afr[4];
#pragma unroll
            for (int ks = 0; ks < 4; ++ks)
                afr[ks] = *(const bf16x8*)&hpA[m][ks * 32 + kg * 8];
            int n0 = w * 32;
#pragma unroll
            for (int tt = 0; tt < 2; ++tt) {
                int nc = n0 + tt * 16 + m;
                f32x4 acc = {0.f, 0.f, 0.f, 0.f};
#pragma unroll
                for (int ks = 0; ks < 4; ++ks) {
                    bf16x8 bfr = *(const bf16x8*)&w23bT1[(size_t)nc * H + ks * 32 + kg * 8];
                    acc = __builtin_amdgcn_mfma_f32_16x16x32_bf16(afr[ks], bfr, acc, 0, 0, 0);
                }
#pragma unroll
                for (int rg = 0; rg < 4; ++rg)
                    accf[kg * 4 + rg][nc] = acc[rg];
            }
        }
        __syncthreads();
        for (int i = t; i < 16 * 64; i += 256) {
            int r = i >> 6, cc = (i & 63) * 2;
            float l0 = s_onL[r] * fmaf(s_mxl[r], svec[0][cc], svec[1][cc]);
            float l1 = s_onL[r] * fmaf(s_mxl[r], svec[0][cc + 1], svec[1][cc + 1]);
            float q0 = s_onD[r] * (s_d0[r] * svec[2][cc] + s_d1[r] * svec[3][cc] + svec[4][cc]);
            float q1 = s_onD[r] * (s_d0[r] * svec[2][cc + 1] + s_d1[r] * svec[3][cc + 1] + svec[4][cc + 1]);
            float v0 = accf[r][cc] + l0 + q0 + svec[5][cc];
            float v1 = accf[r][cc + 1] + l1 + q1 + svec[5][cc + 1];
            accf[r][cc] = v0;
            accf[r][cc + 1] = v1;
            st_bf2(aggp + (size_t)(p0 + r) * H + cc, make_float2(v0, v1));
        }
        __syncthreads();
        if (t < 128) {
            float s = 0.f, q = 0.f;
#pragma unroll
            for (int r = 0; r < 16; ++r) {
                float v = accf[r][t];
                s += v;
                q = fmaf(v, v, q);
            }
            blocksums[(size_t)blockIdx.x * 256 + t] = s;
            blocksums[(size_t)blockIdx.x * 256 + 128 + t] = q;
        }
    } else {
        int bb = blockIdx.x - PAT_BLOCKS;
        int rr = bb * 2 + (t >> 7);
        int h = t & 127;
        if (rr >= NROW) return;
        if (rr < NL) {
            float acc = vecs[6 * 128 + h] + ldin(xl, rr, f32m) * vecs[5 * 128 + h];
            if (cnt[rr] > 0) {
                float s = vecs[10 * 128 + h];
                const float* mx = mxp + (size_t)rr * 16;
#pragma unroll
                for (int k = 0; k < 16; ++k) s = fmaf(mx[k], WpWl0[k * H + h], s);
                acc += s;
            }
            bufL[(size_t)rr * H + h] = acc;
        } else {
            int rd = rr - NL;
            float acc = vecs[9 * 128 + h] + ldin(xd, (size_t)2 * rd, f32m) * vecs[7 * 128 + h] +
                        ldin(xd, (size_t)2 * rd + 1, f32m) * vecs[8 * 128 + h];
            if (cnt[rr] > 0) {
                float s = vecs[11 * 128 + h];
                const float* mx = mxp + (size_t)rr * 16;
#pragma unroll
                for (int k = 0; k < 16; ++k) s = fmaf(mx[k], WpWl1[k * H + h], s);
                acc += s;
            }
            bufD[(size_t)rd * H + h] = acc;
        }
    }
}

// -------- bnred: patient stats from blocksums (+ lab/dis stats when grid>64) -----------
__global__ void k_bnred(const float* __restrict__ blocksums, const float* __restrict__ bufL,
                        const float* __restrict__ bufD, float* __restrict__ sums) {
    int b = blockIdx.x, t = threadIdx.x;
    if (b < 64) {
        float acc = 0.f;
        for (int r = b; r < PAT_BLOCKS; r += 64) acc += blocksums[(size_t)r * 256 + t];
        atomicAdd(&sums[t], acc);
        return;
    }
    int h = t & 127;
    int sub = t >> 7;
    float s = 0.f, s2 = 0.f;
    float* sm;
    if (b < 320) {
        int bid = b - 64;
        for (int i = bid * 2 + sub; i < NL; i += 512) {
            float v = bufL[(size_t)i * H + h];
            s += v;
            s2 = fmaf(v, v, s2);
        }
        sm = sums + 2 * H;
    } else {
        int bid = b - 320;
        for (int i = bid * 2 + sub; i < ND; i += 128) {
            float v = bufD[(size_t)i * H + h];
            s += v;
            s2 = fmaf(v, v, s2);
        }
        sm = sums + 4 * H;
    }
    __shared__ float ls[256], ls2[256];
    ls[t] = s;
    ls2[t] = s2;
    __syncthreads();
    if (sub == 0) {
        atomicAdd(&sm[h], s + ls[128 + h]);
        atomicAdd(&sm[H + h], s2 + ls2[128 + h]);
    }
}

// ---- L2 stage1: mm_small (L1 lab/dis BN inline) + prep23 + head-W1 precompute ----------
#define S2_MM 1313
#define S2_PREP 64
#define S2_TOTAL (S2_MM + S2_PREP)
__global__ void k_stage1_L2(const float* __restrict__ bufL, const float* __restrict__ bufD,
                            const float* __restrict__ bns, const void* __restrict__ bng1,
                            const void* __restrict__ bnb1, const void* __restrict__ Wl,
                            bf16* __restrict__ tlp, bf16* __restrict__ tdp,
                            const void* __restrict__ Wr, const void* __restrict__ bl,
                            bf16* __restrict__ w23bT, float* __restrict__ b23,
                            const void* __restrict__ W1in, bf16* __restrict__ w1T,
                            const int* __restrict__ flags) {
    __shared__ float smm[8][H];
    int b = blockIdx.x, t = threadIdx.x;
    int f32m = flags[0];
    if (b < S2_MM) {
        int bb = b;
        bool lab = bb < 1250;
        const float* buf = lab ? bufL : bufD;
        int N = lab ? NL : ND;
        float invN = lab ? 1.f / NL : 1.f / ND;
        int so = lab ? 2 * H : 4 * H;
        int go = lab ? H : 2 * H;
        bf16* outp = lab ? tlp : tdp;
        size_t woff = lab ? (size_t)2 * HH : (size_t)3 * HH;
        int r0 = (lab ? bb : bb - 1250) * 8;
        int h = t & 127, half = t >> 7;
        float m = bns[so + h] * invN;
        float v = fmaf(-m, m, bns[so + H + h] * invN);
        float sc = rsqrtf(v + 1e-5f) * ldin(bng1, go + h, f32m);
        float be = ldin(bnb1, go + h, f32m);
        for (int r = half; r < 8; r += 2) {
            int ri = r0 + r;
            float x = (ri < N) ? buf[(size_t)ri * H + h] : 0.f;
            smm[r][h] = (ri < N) ? fmaxf(fmaf(x - m, sc, be), 0.f) : 0.f;
        }
        __syncthreads();
        int rb = half * 4;
        float a0 = 0.f, a1 = 0.f, a2 = 0.f, a3 = 0.f;
        for (int k = 0; k < H; ++k) {
            float wv = ldin(Wl, woff + (size_t)k * H + h, f32m);
            a0 = fmaf(smm[rb + 0][k], wv, a0);
            a1 = fmaf(smm[rb + 1][k], wv, a1);
            a2 = fmaf(smm[rb + 2][k], wv, a2);
            a3 = fmaf(smm[rb + 3][k], wv, a3);
        }
        float acc[4] = {a0, a1, a2, a3};
#pragma unroll
        for (int r = 0; r < 4; ++r)
            if (r0 + rb + r < N)
                outp[(size_t)(r0 + rb + r) * H + h] = __float2bfloat16(acc[r]);
    } else {
        int pb = b - S2_MM;
        int idx = pb * 256 + t;
        if (idx < HH) {
            int k = idx >> 7, n = idx & 127;
            float v = ldin(Wr, (size_t)2 * HH + idx, f32m) + ldin(Wr, (size_t)3 * HH + idx, f32m);
            w23bT[(size_t)n * H + k] = __float2bfloat16(v);
        }
        if (idx < H)
            b23[idx] = ldin(bl, (size_t)2 * H + idx, f32m) + ldin(bl, (size_t)3 * H + idx, f32m);
        if (idx < 64 * H) {  // head FC1 weight, transposed to [n][k] bf16 for MFMA B-operand
            int n = idx >> 7, k = idx & 127;
            w1T[idx] = __float2bfloat16(ldin(W1in, (size_t)k * 64 + n, f32m));
        }
    }
}

// -------- L2 patmm: in-place aggp update (L1 pat BN inline) + per-block stats -----------
// Gather: QUARTER-wave (16 lanes) per patient row, 16 B (8 cols) per lane. Each
// quarter-wave owns exactly one patient (no serial rp loop) -> half the dependent
// iterations per wave and half the vmem instructions per edge. SW-pipelined index
// prefetch. aggp staging read is non-temporal (read-once). Stores temporal.
__global__ void k_patmm_L2(bf16* __restrict__ aggp, const bf16* __restrict__ tlp,
                           const bf16* __restrict__ tdp, const int* __restrict__ off,
                           const int* __restrict__ cnt, const int* __restrict__ nbr,
                           const bf16* __restrict__ w23bT, const float* __restrict__ b23,
                           const float* __restrict__ bns, const void* __restrict__ bng1,
                           const void* __restrict__ bnb1, float* __restrict__ blocksums,
                           const int* __restrict__ flags) {
    __shared__ bf16 hpA[16][HPAD];
    __shared__ __align__(16) float accf[16][APAD];
    int t = threadIdx.x;
    int f32m = flags[0];
    int w = t >> 6, lane = t & 63;
    int p0 = blockIdx.x * 16;
    {
        int cc = (t & 63) * 2;
        const float invN = 1.f / NP;
        float m0 = bns[cc] * invN, m1 = bns[cc + 1] * invN;
        float v0 = fmaf(-m0, m0, bns[128 + cc] * invN);
        float v1 = fmaf(-m1, m1, bns[128 + cc + 1] * invN);
        float sc0 = rsqrtf(v0 + 1e-5f) * ldin(bng1, cc, f32m);
        float sc1 = rsqrtf(v1 + 1e-5f) * ldin(bng1, cc + 1, f32m);
        float be0 = ldin(bnb1, cc, f32m), be1 = ldin(bnb1, cc + 1, f32m);
        for (int i = t; i < 16 * 64; i += 256) {
            int r = i >> 6;
            float2 v = ld_bf2_nt(aggp + (size_t)(p0 + r) * H + cc);
            st_bf2(&hpA[r][cc], make_float2(fmaxf(fmaf(v.x - m0, sc0, be0), 0.f),
                                            fmaxf(fmaf(v.y - m1, sc1, be1), 0.f)));
        }
    }
    {
        const int* off1 = off + NL + ND;
        const int* cnt1 = cnt + NL + ND;
        const int* off2 = off + NL + ND + NP;
        const int* cnt2 = cnt + NL + ND + NP;
        int qw = lane >> 4, ql = lane & 15;  // 16 quarter-waves; each owns ONE patient
        int p = p0 + w * 4 + qw;
        int cb = ql * 8;                     // this lane's 8 columns (16 B)
        float4 bb0 = *(const float4*)(b23 + cb);
        float4 bb1 = *(const float4*)(b23 + cb + 4);
        int s1 = off1[p], c1 = cnt1[p];
        const int* nb1 = nbr + s1;
        float a0 = 0.f, a1 = 0.f, a2 = 0.f, a3 = 0.f, a4 = 0.f, a5 = 0.f, a6 = 0.f, a7 = 0.f;
        float g0 = 0.f, g1 = 0.f, g2 = 0.f, g3 = 0.f, g4 = 0.f, g5 = 0.f, g6 = 0.f, g7 = 0.f;
        int j = 0;
        int i0, i1, i2, i3;
        if (c1 >= 4) { i0 = nb1[0]; i1 = nb1[1]; i2 = nb1[2]; i3 = nb1[3]; }
        for (; j + 8 <= c1; j += 4) {
            uint4 v0 = *(const uint4*)(tlp + (size_t)i0 * H + cb);
            uint4 v1 = *(const uint4*)(tlp + (size_t)i1 * H + cb);
            uint4 v2 = *(const uint4*)(tlp + (size_t)i2 * H + cb);
            uint4 v3 = *(const uint4*)(tlp + (size_t)i3 * H + cb);
            int n0 = nb1[j + 4], n1 = nb1[j + 5], n2 = nb1[j + 6], n3 = nb1[j + 7];
            bfacc2(a0, a1, v0.x); bfacc2(a2, a3, v0.y); bfacc2(a4, a5, v0.z); bfacc2(a6, a7, v0.w);
            bfacc2(g0, g1, v1.x); bfacc2(g2, g3, v1.y); bfacc2(g4, g5, v1.z); bfacc2(g6, g7, v1.w);
            bfacc2(a0, a1, v2.x); bfacc2(a2, a3, v2.y); bfacc2(a4, a5, v2.z); bfacc2(a6, a7, v2.w);
            bfacc2(g0, g1, v3.x); bfacc2(g2, g3, v3.y); bfacc2(g4, g5, v3.z); bfacc2(g6, g7, v3.w);
            i0 = n0; i1 = n1; i2 = n2; i3 = n3;
        }
        if (j + 4 <= c1) {
            uint4 v0 = *(const uint4*)(tlp + (size_t)i0 * H + cb);
            uint4 v1 = *(const uint4*)(tlp + (size_t)i1 * H + cb);
            uint4 v2 = *(const uint4*)(tlp + (size_t)i2 * H + cb);
            uint4 v3 = *(const uint4*)(tlp + (size_t)i3 * H + cb);
            bfacc2(a0, a1, v0.x); bfacc2(a2, a3, v0.y); bfacc2(a4, a5, v0.z); bfacc2(a6, a7, v0.w);
            bfacc2(g0, g1, v1.x); bfacc2(g2, g3, v1.y); bfacc2(g4, g5, v1.z); bfacc2(g6, g7, v1.w);
            bfacc2(a0, a1, v2.x); bfacc2(a2, a3, v2.y); bfacc2(a4, a5, v2.z); bfacc2(a6, a7, v2.w);
            bfacc2(g0, g1, v3.x); bfacc2(g2, g3, v3.y); bfacc2(g4, g5, v3.z); bfacc2(g6, g7, v3.w);
            j += 4;
        }
        for (; j < c1; ++j) {
            uint4 v = *(const uint4*)(tlp + (size_t)nb1[j] * H + cb);
            bfacc2(a0, a1, v.x); bfacc2(a2, a3, v.y); bfacc2(a4, a5, v.z); bfacc2(a6, a7, v.w);
        }
        a0 += g0; a1 += g1; a2 += g2; a3 += g3;
        a4 += g4; a5 += g5; a6 += g6; a7 += g7;
        int s2 = off2[p], c2 = cnt2[p];
        const int* nb2 = nbr + s2;
        float d0 = 0.f, d1 = 0.f, d2 = 0.f, d3 = 0.f, d4 = 0.f, d5 = 0.f, d6 = 0.f, d7 = 0.f;
        float e0 = 0.f, e1 = 0.f, e2 = 0.f, e3 = 0.f, e4 = 0.f, e5 = 0.f, e6 = 0.f, e7 = 0.f;
        j = 0;
        int k0, k1;
        if (c2 >= 2) { k0 = nb2[0]; k1 = nb2[1]; }
        for (; j + 4 <= c2; j += 2) {
            uint4 v0 = *(const uint4*)(tdp + (size_t)k0 * H + cb);
            uint4 v1 = *(const uint4*)(tdp + (size_t)k1 * H + cb);
            int n0 = nb2[j + 2], n1 = nb2[j + 3];
            bfacc2(d0, d1, v0.x); bfacc2(d2, d3, v0.y); bfacc2(d4, d5, v0.z); bfacc2(d6, d7, v0.w);
            bfacc2(e0, e1, v1.x); bfacc2(e2, e3, v1.y); bfacc2(e4, e5, v1.z); bfacc2(e6, e7, v1.w);
            k0 = n0; k1 = n1;
        }
        if (j + 2 <= c2) {
            uint4 v0 = *(const uint4*)(tdp + (size_t)k0 * H + cb);
            uint4 v1 = *(const uint4*)(tdp + (size_t)k1 * H + cb);
            bfacc2(d0, d1, v0.x); bfacc2(d2, d3, v0.y); bfacc2(d4, d5, v0.z); bfacc2(d6, d7, v0.w);
            bfacc2(e0, e1, v1.x); bfacc2(e2, e3, v1.y); bfacc2(e4, e5, v1.z); bfacc2(e6, e7, v1.w);
            j += 2;
        }
        if (j < c2) {
            uint4 v = *(const uint4*)(tdp + (size_t)nb2[j] * H + cb);
            bfacc2(d0, d1, v.x); bfacc2(d2, d3, v.y); bfacc2(d4, d5, v.z); bfacc2(d6, d7, v.w);
        }
        d0 += e0; d1 += e1; d2 += e2; d3 += e3;
        d4 += e4; d5 += e5; d6 += e6; d7 += e7;
        float i1f = 1.f / fmaxf((float)c1, 1.f), i2f = 1.f / fmaxf((float)c2, 1.f);
        float4 r0v, r1v;
        r0v.x = a0 * i1f + d0 * i2f + bb0.x;
        r0v.y = a1 * i1f + d1 * i2f + bb0.y;
        r0v.z = a2 * i1f + d2 * i2f + bb0.z;
        r0v.w = a3 * i1f + d3 * i2f + bb0.w;
        r1v.x = a4 * i1f + d4 * i2f + bb1.x;
        r1v.y = a5 * i1f + d5 * i2f + bb1.y;
        r1v.z = a6 * i1f + d6 * i2f + bb1.z;
        r1v.w = a7 * i1f + d7 * i2f + bb1.w;
        *(float4*)&accf[w * 4 + qw][cb] = r0v;
        *(float4*)&accf[w * 4 + qw][cb + 4] = r1v;
    }
    __syncthreads();
    {
        int m = lane & 15, kg = lane >> 4;
        bf16x8 afr[4];
#pragma unroll
        for (int ks = 0; ks < 4; ++ks)
            afr[ks] = *(const bf16x8*)&hpA[m][ks * 32 + kg * 8];
        int n0 = w * 32;
#pragma unroll
        for (int tt = 0; tt < 2; ++tt) {
            int nc = n0 + tt * 16 + m;
            f32x4 acc = {0.f, 0.f, 0.f, 0.f};
#pragma unroll
            for (int ks = 0; ks < 4; ++ks) {
                bf16x8 bfr = *(const bf16x8*)&w23bT[(size_t)nc * H + ks * 32 + kg * 8];
                acc = __builtin_amdgcn_mfma_f32_16x16x32_bf16(afr[ks], bfr, acc, 0, 0, 0);
            }
#pragma unroll
            for (int rg = 0; rg < 4; ++rg)
                accf[kg * 4 + rg][nc] += acc[rg];
        }
    }
    __syncthreads();
    for (int i = t; i < 16 * 64; i += 256) {
        int r = i >> 6, cc = (i & 63) * 2;
        st_bf2(aggp + (size_t)(p0 + r) * H + cc, make_float2(accf[r][cc], accf[r][cc + 1]));
    }
    if (t < 128) {
        float s = 0.f, q = 0.f;
#pragma unroll
        for (int r = 0; r < 16; ++r) {
            float v = accf[r][t];
            s += v;
            q = fmaf(v, v, q);
        }
        blocksums[(size_t)blockIdx.x * 256 + t] = s;
        blocksums[(size_t)blockIdx.x * 256 + 128 + t] = q;
    }
}

// ---------------- head: fused L2 patient BN+ReLU -> MFMA FC1 -> FC2 -> log_softmax ------
__global__ void k_head(const bf16* __restrict__ aggp, const float* __restrict__ sums,
                       const void* __restrict__ bng, const void* __restrict__ bnb,
                       const bf16* __restrict__ w1T, const void* __restrict__ b1,
                       const void* __restrict__ W2, const void* __restrict__ b2f,
                       void* __restrict__ out, const int* __restrict__ flags) {
    int f32m = flags[0];
    __shared__ bf16 hpA[16][HPAD];
    __shared__ float h1s[16][68];
    __shared__ float lgs[16][16];
    __shared__ float W2s[64 * NOUT];
    __shared__ float b1s[64], b2s[NOUT];
    int t = threadIdx.x;
    int w = t >> 6, lane = t & 63;
    for (int i = t; i < 64 * NOUT; i += 256) W2s[i] = ldin(W2, i, f32m);
    if (t < 64) b1s[t] = ldin(b1, t, f32m);
    else if (t >= 64 && t < 64 + NOUT) b2s[t - 64] = ldin(b2f, t - 64, f32m);
    int p0 = blockIdx.x * 16;
    {
        int cc = (t & 63) * 2;
        const float invN = 1.f / NP;
        float m0 = sums[cc] * invN, m1 = sums[cc + 1] * invN;
        float v0 = fmaf(-m0, m0, sums[128 + cc] * invN);
        float v1 = fmaf(-m1, m1, sums[128 + cc + 1] * invN);
        float sc0 = rsqrtf(v0 + 1e-5f) * ldin(bng, cc, f32m);
        float sc1 = rsqrtf(v1 + 1e-5f) * ldin(bng, cc + 1, f32m);
        float be0 = ldin(bnb, cc, f32m), be1 = ldin(bnb, cc + 1, f32m);
        for (int i = t; i < 16 * 64; i += 256) {
            int r = i >> 6;
            float2 v = ld_bf2_nt(aggp + (size_t)(p0 + r) * H + cc);
            st_bf2(&hpA[r][cc], make_float2(fmaxf(fmaf(v.x - m0, sc0, be0), 0.f),
                                            fmaxf(fmaf(v.y - m1, sc1, be1), 0.f)));
        }
    }
    __syncthreads();
    {
        // MFMA FC1: wave w computes output cols [w*16, w*16+16); K=128 over 4 ksteps.
        int m = lane & 15, kg = lane >> 4;
        bf16x8 afr[4];
#pragma unroll
        for (int ks = 0; ks < 4; ++ks)
            afr[ks] = *(const bf16x8*)&hpA[m][ks * 32 + kg * 8];
        int nc = w * 16 + m;
        f32x4 acc = {0.f, 0.f, 0.f, 0.f};
#pragma unroll
        for (int ks = 0; ks < 4; ++ks) {
            bf16x8 bfr = *(const bf16x8*)&w1T[(size_t)nc * H + ks * 32 + kg * 8];
            acc = __builtin_amdgcn_mfma_f32_16x16x32_bf16(afr[ks], bfr, acc, 0, 0, 0);
        }
        float bv = b1s[nc];
#pragma unroll
        for (int rg = 0; rg < 4; ++rg)
            h1s[kg * 4 + rg][nc] = fmaxf(acc[rg] + bv, 0.f);
    }
    __syncthreads();
    int pat = lane >> 4, oidx = lane & 15;
    int prow = 4 * w + pat;
    float lg = 0.f;
    if (oidx < NOUT) {
        lg = b2s[oidx];
        const float* hh = h1s[prow];
#pragma unroll 8
        for (int k = 0; k < 64; ++k) lg = fmaf(hh[k], W2s[k * NOUT + oidx], lg);
        lgs[prow][oidx] = lg;
    }
    __syncthreads();
    if (oidx < NOUT) {
        float m = -1e30f;
#pragma unroll
        for (int k = 0; k < NOUT; ++k) m = fmaxf(m, lgs[prow][k]);
        float s = 0.f;
#pragma unroll
        for (int k = 0; k < NOUT; ++k) s += __expf(lgs[prow][k] - m);
        float r = lg - m - __logf(s);
        if (f32m)
            ((float*)out)[(size_t)(p0 + prow) * NOUT + oidx] = r;
        else
            ((bf16*)out)[(size_t)(p0 + prow) * NOUT + oidx] = __float2bfloat16(r);
    }
}

extern "C" void kernel_launch(void* const* d_in, const int* in_sizes, int n_in, void* d_out,
                              int out_size, void* d_ws, size_t ws_size, hipStream_t stream) {
    const int* e1s = (const int*)d_in[23];
    const int* e1d = (const int*)d_in[24];
    const int* e2s = (const int*)d_in[25];
    const int* e2d = (const int*)d_in[26];
    const int NPOOL = 2 * (E1 + E2);

    char* wsb = (char*)d_ws;
    size_t o = 0;
    auto af = [&](size_t nwords) { void* p = wsb + o * 4; o += nwords; return p; };
    int* flags = (int*)af(16);
    bf16* w23bT = (bf16*)af(HH / 2);
    bf16* w23bT1 = (bf16*)af(HH / 2);
    bf16* w1T = (bf16*)af(64 * H / 2);
    float* b23 = (float*)af(H);
    float* bns = (float*)af(8 * H);
    int* bsums = (int*)af(256);
    float* WpWl0 = (float*)af(16 * H);
    float* WpWl1 = (float*)af(16 * H);
    float* vecs = (float*)af(13 * 128);
    int* cnt = (int*)af(NCNT);
    int* off = (int*)af(NCNT);
    int* nbr = (int*)af(NPOOL);
    bf16* hp = (bf16*)af((size_t)NP * H / 2);
    bf16* xpb = (bf16*)af((size_t)NP * 16 / 2);
    size_t arena = o;
    unsigned char* r1s = (unsigned char*)af(E1 / 4);
    unsigned char* r2s = (unsigned char*)af(E2 / 4);
    unsigned int* labHistP = (unsigned int*)af((size_t)NCH1 * NPW);
    unsigned int* disHistP = (unsigned int*)af((size_t)NCH2 * NPW);
    unsigned int* labHist = (unsigned int*)af((size_t)LABHB * NL);
    unsigned int* disHist = (unsigned int*)af((size_t)DISHB * ND);
    size_t endA = o;
    o = arena;
    float* bufL = (float*)af((size_t)NL * H);
    float* bufD = (float*)af((size_t)ND * H);
    bf16* tlp = (bf16*)af((size_t)NL * H / 2);
    bf16* tdp = (bf16*)af((size_t)ND * H / 2);
    bf16* aggp = (bf16*)af((size_t)NP * H / 2);
    float* mxp = (float*)af((size_t)NROW * 16);
    float* blocksums = (float*)af((size_t)PAT_BLOCKS * 256);
    size_t endB = o;
    o = endA > endB ? endA : endB;
    (void)ws_size;

    k_hist<<<HB3 + 1, 1024, 0, stream>>>(e1s, e1d, e2s, e2d, labHistP, disHistP, r1s, r2s,
                                         labHist, disHist, (const unsigned short*)d_in[0],
                                         flags);
    k_reduce<<<RB7, 256, 0, stream>>>(labHist, disHist, labHistP, disHistP, cnt, d_in[0],
                                      d_in[3], d_in[4], d_in[5], d_in[6], d_in[7], d_in[8],
                                      d_in[9], d_in[10], d_in[11], hp, WpWl0, WpWl1, vecs,
                                      w23bT1, xpb, flags);
    int nb = (NCNT + SCAN_ELEMS - 1) / SCAN_ELEMS;
    k_scan1<<<nb, 256, 0, stream>>>(cnt, off, bsums, NCNT);
    k_scan2<<<1, 256, 0, stream>>>(bsums, nb);
    k_scan3<<<(NCNT + 255) / 256, 256, 0, stream>>>(off, bsums, NCNT);
    k_fill<<<CNT_BLOCKS + LABHB + DISHB + 1, 256, 0, stream>>>(
        e1s, e1d, e2s, e2d, off, r1s, r2s, (const unsigned char*)labHistP,
        (const unsigned char*)disHistP, labHist, disHist, nbr, bns);

    // ---- layer 1 (algebraically collapsed) ----
    k_stage1_L1<<<(NROW + 3) / 4, 256, 0, stream>>>(xpb, off, cnt, nbr, mxp);
    k_patmm_L1<<<PAT_BLOCKS + LD1_BLOCKS, 256, 0, stream>>>(hp, d_in[1], d_in[2], off, cnt, nbr,
                                                            w23bT1, vecs, WpWl0, WpWl1, mxp,
                                                            aggp, bufL, bufD, blocksums, flags);
    k_bnred<<<384, 256, 0, stream>>>(blocksums, bufL, bufD, bns);

    // ---- layer 2: all BN applications fused into consumers ----
    k_stage1_L2<<<S2_TOTAL, 256, 0, stream>>>(bufL, bufD, bns, d_in[15], d_in[16], d_in[12],
                                              tlp, tdp, d_in[14], d_in[13], w23bT, b23,
                                              d_in[19], w1T, flags);
    k_patmm_L2<<<PAT_BLOCKS, 256, 0, stream>>>(aggp, tlp, tdp, off, cnt, nbr, w23bT, b23, bns,
                                               d_in[15], d_in[16], blocksums, flags);
    k_bnred<<<64, 256, 0, stream>>>(blocksums, bufL, bufD, bns + 6 * H);
    k_head<<<NP / 16, 256, 0, stream>>>(aggp, bns + 6 * H, d_in[17], d_in[18], w1T,
                                        d_in[20], d_in[21], d_in[22], d_out, flags);
}

// Round 11
// 538.598 us; speedup vs baseline: 1.3379x; 1.0410x over previous
//
#include <hip/hip_runtime.h>
#include <hip/hip_bf16.h>

#define NP 100000
#define NL 10000
#define ND 500
#define H 128
#define HH (H * H)
#define E1 2000000
#define E2 500000
#define NOUT 10
#define NCNT (NL + ND + 2 * NP)
#define NROW (NL + ND)
#define CHUNK 8192
#define LABHB ((E1 + CHUNK - 1) / CHUNK)
#define DISHB ((E2 + CHUNK - 1) / CHUNK)
#define CNT_BLOCKS ((E1 + E2 + 255) / 256)
#define RED_LAB ((NL + 255) / 256)
#define RED_DIS ((ND + 255) / 256)
#define PAT_BLOCKS (NP / 16)

// patient-side chunked LDS histogram sort (replaces global atomics)
#define CHP 15625
#define NCH1 (E1 / CHP) /* 128 */
#define NCH2 (E2 / CHP) /* 32 */
#define NPW (NP / 4)    /* 25000 packed-byte words = 100 KB LDS */
#define RPW ((NPW + 255) / 256)

typedef __hip_bfloat16 bf16;
typedef __attribute__((ext_vector_type(8))) short bf16x8;
typedef __attribute__((ext_vector_type(4))) float f32x4;

__device__ __forceinline__ float bfbits2f(unsigned short s) {
    union { unsigned int u; float f; } v;
    v.u = (unsigned int)s << 16;
    return v.f;
}
__device__ __forceinline__ float2 ld_bf2(const bf16* p) {
    unsigned int u = *(const unsigned int*)p;
    return make_float2(bfbits2f((unsigned short)(u & 0xFFFFu)), bfbits2f((unsigned short)(u >> 16)));
}
__device__ __forceinline__ float2 ld_bf2_nt(const bf16* p) {
    unsigned int u = __builtin_nontemporal_load((const unsigned int*)p);
    return make_float2(bfbits2f((unsigned short)(u & 0xFFFFu)), bfbits2f((unsigned short)(u >> 16)));
}
__device__ __forceinline__ void st_bf2(bf16* p, float2 v) {
    union { unsigned int u; bf16 b[2]; } t;
    t.b[0] = __float2bfloat16(v.x);
    t.b[1] = __float2bfloat16(v.y);
    *(unsigned int*)p = t.u;
}
__device__ __forceinline__ float ldin(const void* p, size_t i, int f32m) {
    return f32m ? ((const float*)p)[i] : __bfloat162float(((const bf16*)p)[i]);
}
// accumulate 2 packed bf16 (one u32) into two f32 accumulators: 2 unpack + 2 add VALU
__device__ __forceinline__ void bfacc2(float& x, float& y, unsigned int u) {
    union { unsigned int q; float f; } lo, hi;
    lo.q = u << 16;
    hi.q = u & 0xFFFF0000u;
    x += lo.f;
    y += hi.f;
}

// ---- k_hist: all histograms via LDS (no global atomics), 1024 threads -----------------
// Last block (b == HB3) performs input-dtype detection (folded k_detect).
#define HB0 NCH1
#define HB1 (HB0 + NCH2)
#define HB2 (HB1 + LABHB)
#define HB3 (HB2 + DISHB)
__global__ void k_hist(const int* __restrict__ e1s, const int* __restrict__ e1d,
                       const int* __restrict__ e2s, const int* __restrict__ e2d,
                       unsigned int* __restrict__ labHistP, unsigned int* __restrict__ disHistP,
                       unsigned char* __restrict__ r1s, unsigned char* __restrict__ r2s,
                       unsigned int* __restrict__ labHist, unsigned int* __restrict__ disHist,
                       const unsigned short* __restrict__ xpw, int* __restrict__ flags) {
    __shared__ unsigned int sh[NPW];  // 100 KB: byte-packed patient counters / reused by dest hists
    int b = blockIdx.x, t = threadIdx.x;
    if (b < HB1) {
        for (int i = t; i < NPW; i += 1024) sh[i] = 0;
        __syncthreads();
        if (b < HB0) {
            int e0 = b * CHP;
            for (int j = t; j < CHP; j += 1024) {
                int e = e0 + j;
                int ss = e1s[e];
                unsigned int old = atomicAdd(&sh[ss >> 2], 1u << (8 * (ss & 3)));
                r1s[e] = (unsigned char)(old >> (8 * (ss & 3)));
            }
            __syncthreads();
            unsigned int* out = labHistP + (size_t)b * NPW;
            for (int i = t; i < NPW; i += 1024) out[i] = sh[i];
        } else {
            int c = b - HB0;
            int e0 = c * CHP;
            for (int j = t; j < CHP; j += 1024) {
                int e = e0 + j;
                int ss = e2s[e];
                unsigned int old = atomicAdd(&sh[ss >> 2], 1u << (8 * (ss & 3)));
                r2s[e] = (unsigned char)(old >> (8 * (ss & 3)));
            }
            __syncthreads();
            unsigned int* out = disHistP + (size_t)c * NPW;
            for (int i = t; i < NPW; i += 1024) out[i] = sh[i];
        }
    } else if (b < HB2) {
        int c = b - HB1;
        for (int i = t; i < NL / 2; i += 1024) sh[i] = 0;
        __syncthreads();
        int e0 = c * CHUNK, ee = min(E1, e0 + CHUNK);
        for (int e = e0 + t; e < ee; e += 1024) {
            int dd = e1d[e];
            atomicAdd(&sh[dd >> 1], 1u << (16 * (dd & 1)));
        }
        __syncthreads();
        for (int i = t; i < NL; i += 1024)
            labHist[(size_t)c * NL + i] = (sh[i >> 1] >> (16 * (i & 1))) & 0xFFFFu;
    } else if (b < HB3) {
        int c = b - HB2;
        for (int i = t; i < ND / 2; i += 1024) sh[i] = 0;
        __syncthreads();
        int e0 = c * CHUNK, ee = min(E2, e0 + CHUNK);
        for (int e = e0 + t; e < ee; e += 1024) {
            int dd = e2d[e];
            atomicAdd(&sh[dd >> 1], 1u << (16 * (dd & 1)));
        }
        __syncthreads();
        for (int i = t; i < ND; i += 1024)
            disHist[(size_t)c * ND + i] = (sh[i >> 1] >> (16 * (i & 1))) & 0xFFFFu;
    } else {
        // dtype detection (flags consumed first by k_reduce, next in stream order)
        int cnt = 0;
        for (int i = t; i < 4096; i += 1024) {
            unsigned short w = xpw[2 * i];
            int e = (w >> 7) & 0xFF;
            if (w == 0 || (e >= 114 && e <= 141)) cnt++;
        }
        int* shi = (int*)sh;
        shi[t] = cnt;
        __syncthreads();
        for (int s = 512; s > 0; s >>= 1) {
            if (t < s) shi[t] += shi[t + s];
            __syncthreads();
        }
        if (t == 0) flags[0] = (shi[0] < 2048) ? 1 : 0;
    }
}

// ---- reduce: chunk exclusive bases (packed-byte scan for patients); totals -> cnt ------
// Embed branch is block-tiled: 256 patients/block, Wp in LDS, xp row in registers.
#define EMB2 ((NP + 255) / 256)
#define RB0 RED_LAB
#define RB1 (RB0 + RED_DIS)
#define RB2 (RB1 + RPW)
#define RB3 (RB2 + RPW)
#define RB4 (RB3 + EMB2)
#define RB5 (RB4 + 16)
#define RB6 (RB5 + 7)
#define RB7 (RB6 + 64)
__global__ void k_reduce(unsigned int* __restrict__ labHist, unsigned int* __restrict__ disHist,
                         unsigned int* __restrict__ labHistP, unsigned int* __restrict__ disHistP,
                         int* __restrict__ cnt, const void* __restrict__ xp,
                         const void* __restrict__ Wp, const void* __restrict__ bp,
                         const void* __restrict__ Wlab, const void* __restrict__ blab,
                         const void* __restrict__ Wdis, const void* __restrict__ bdis,
                         const void* __restrict__ Wl1, const void* __restrict__ bl1,
                         const void* __restrict__ Wr1, bf16* __restrict__ hp,
                         float* __restrict__ WpWl0, float* __restrict__ WpWl1,
                         float* __restrict__ vecs, bf16* __restrict__ w23bT1,
                         bf16* __restrict__ xpb, const int* __restrict__ flags) {
    int b = blockIdx.x, t = threadIdx.x;
    if (b < RB0) {
        int bin = b * 256 + t;
        if (bin < NL) {
            unsigned int run = 0;
            for (int k = 0; k < LABHB; ++k) {
                unsigned int x = labHist[(size_t)k * NL + bin];
                labHist[(size_t)k * NL + bin] = run;
                run += x;
            }
            cnt[bin] = (int)run;
        }
    } else if (b < RB1) {
        int bin = (b - RB0) * 256 + t;
        if (bin < ND) {
            unsigned int run = 0;
            for (int k = 0; k < DISHB; ++k) {
                unsigned int x = disHist[(size_t)k * ND + bin];
                disHist[(size_t)k * ND + bin] = run;
                run += x;
            }
            cnt[NL + bin] = (int)run;
        }
    } else if (b < RB2) {
        int w = (b - RB1) * 256 + t;
        if (w < NPW) {
            unsigned int run = 0;  // 4 byte-lanes scanned in parallel; degree < 256 so no carry
            for (int c = 0; c < NCH1; ++c) {
                unsigned int x = labHistP[(size_t)c * NPW + w];
                labHistP[(size_t)c * NPW + w] = run;
                run += x;
            }
            int base = NL + ND + 4 * w;
            cnt[base] = (int)(run & 0xFFu);
            cnt[base + 1] = (int)((run >> 8) & 0xFFu);
            cnt[base + 2] = (int)((run >> 16) & 0xFFu);
            cnt[base + 3] = (int)(run >> 24);
        }
    } else if (b < RB3) {
        int w = (b - RB2) * 256 + t;
        if (w < NPW) {
            unsigned int run = 0;
            for (int c = 0; c < NCH2; ++c) {
                unsigned int x = disHistP[(size_t)c * NPW + w];
                disHistP[(size_t)c * NPW + w] = run;
                run += x;
            }
            int base = NL + ND + NP + 4 * w;
            cnt[base] = (int)(run & 0xFFu);
            cnt[base + 1] = (int)((run >> 8) & 0xFFu);
            cnt[base + 2] = (int)((run >> 16) & 0xFFu);
            cnt[base + 3] = (int)(run >> 24);
        }
    } else if (b < RB4) {
        // block-tiled embed: 256 patients/block; Wp+bp staged in LDS (wave-uniform
        // broadcast reads); xp row held in registers; vectorized bf16 stores.
        __shared__ float Wps[16 * 128];
        __shared__ float bps[128];
        int f32m = flags[0];
        for (int i = t; i < 16 * 128; i += 256) Wps[i] = ldin(Wp, i, f32m);
        if (t < 128) bps[t] = ldin(bp, t, f32m);
        __syncthreads();
        int p = (b - RB3) * 256 + t;
        if (p < NP) {
            float xr[16];
#pragma unroll
            for (int k = 0; k < 16; ++k) xr[k] = ldin(xp, (size_t)p * 16 + k, f32m);
            unsigned int xw[8];
#pragma unroll
            for (int k2 = 0; k2 < 8; ++k2) {
                union { unsigned int u; bf16 b2[2]; } tt;
                tt.b2[0] = __float2bfloat16(xr[2 * k2]);
                tt.b2[1] = __float2bfloat16(xr[2 * k2 + 1]);
                xw[k2] = tt.u;
            }
            *(uint4*)(xpb + (size_t)p * 16) = make_uint4(xw[0], xw[1], xw[2], xw[3]);
            *(uint4*)(xpb + (size_t)p * 16 + 8) = make_uint4(xw[4], xw[5], xw[6], xw[7]);
            bf16* hrow = hp + (size_t)p * H;
            for (int hc = 0; hc < 16; ++hc) {
                unsigned int ow[4];
#pragma unroll
                for (int hh = 0; hh < 8; hh += 2) {
                    int h0 = hc * 8 + hh;
                    float a0 = bps[h0], a1 = bps[h0 + 1];
#pragma unroll
                    for (int k = 0; k < 16; ++k) {
                        a0 = fmaf(xr[k], Wps[k * 128 + h0], a0);
                        a1 = fmaf(xr[k], Wps[k * 128 + h0 + 1], a1);
                    }
                    union { unsigned int u; bf16 b2[2]; } tt;
                    tt.b2[0] = __float2bfloat16(a0);
                    tt.b2[1] = __float2bfloat16(a1);
                    ow[hh >> 1] = tt.u;
                }
                *(uint4*)(hrow + hc * 8) = make_uint4(ow[0], ow[1], ow[2], ow[3]);
            }
        }
    } else if (b < RB5) {
        int f32m = flags[0];
        int pb = b - RB4;
        bool first = pb < 8;
        size_t woff = first ? 0 : (size_t)HH;
        float* outp = first ? WpWl0 : WpWl1;
        int k = (first ? pb : pb - 8) * 2 + (t >> 7);
        int h = t & 127;
        float s = 0.f;
        for (int m = 0; m < H; ++m)
            s = fmaf(ldin(Wp, (size_t)k * H + m, f32m), ldin(Wl1, woff + (size_t)m * H + h, f32m), s);
        outp[k * H + h] = s;
    } else if (b < RB6) {
        int f32m = flags[0];
        int idx = (b - RB5) * 256 + t;
        if (idx < 13 * 128) {
            int v = idx >> 7, h = idx & 127;
            float s = 0.f;
            if (v == 12) {
                s = ldin(bl1, 2 * H + h, f32m) + ldin(bl1, 3 * H + h, f32m);
            } else {
                const void* A;
                size_t aoff = 0;
                const void* W;
                size_t woff;
                float add = 0.f;
                switch (v) {
                    case 0: A = Wlab; W = Wl1; woff = 2 * (size_t)HH; break;
                    case 1: A = blab; W = Wl1; woff = 2 * (size_t)HH; break;
                    case 2: A = Wdis; W = Wl1; woff = 3 * (size_t)HH; break;
                    case 3: A = Wdis; aoff = H; W = Wl1; woff = 3 * (size_t)HH; break;
                    case 4: A = bdis; W = Wl1; woff = 3 * (size_t)HH; break;
                    case 5: A = Wlab; W = Wr1; woff = 0; break;
                    case 6: A = blab; W = Wr1; woff = 0; add = ldin(bl1, h, f32m); break;
                    case 7: A = Wdis; W = Wr1; woff = (size_t)HH; break;
                    case 8: A = Wdis; aoff = H; W = Wr1; woff = (size_t)HH; break;
                    case 9: A = bdis; W = Wr1; woff = (size_t)HH; add = ldin(bl1, H + h, f32m); break;
                    case 10: A = bp; W = Wl1; woff = 0; break;
                    default: A = bp; W = Wl1; woff = (size_t)HH; break;
                }
                for (int m = 0; m < H; ++m)
                    s = fmaf(ldin(A, aoff + m, f32m), ldin(W, woff + (size_t)m * H + h, f32m), s);
                s += add;
            }
            vecs[v * 128 + h] = s;
        }
    } else {
        int f32m = flags[0];
        int idx = (b - RB6) * 256 + t;
        if (idx < HH) {
            int k = idx >> 7, n = idx & 127;
            float v = ldin(Wr1, (size_t)2 * HH + idx, f32m) + ldin(Wr1, (size_t)3 * HH + idx, f32m);
            w23bT1[(size_t)n * H + k] = __float2bfloat16(v);
        }
    }
}

#define SCAN_ELEMS 2048
__global__ void k_scan1(const int* __restrict__ in, int* __restrict__ out,
                        int* __restrict__ bsums, int n) {
    int t = threadIdx.x;
    int base = blockIdx.x * SCAN_ELEMS + t * 8;
    int v[8], tsum = 0;
#pragma unroll
    for (int j = 0; j < 8; ++j) {
        v[j] = (base + j < n) ? in[base + j] : 0;
        tsum += v[j];
    }
    __shared__ int sh[256];
    sh[t] = tsum;
    __syncthreads();
    for (int d = 1; d < 256; d <<= 1) {
        int x = (t >= d) ? sh[t - d] : 0;
        __syncthreads();
        sh[t] += x;
        __syncthreads();
    }
    int run = sh[t] - tsum;
    if (t == 255) bsums[blockIdx.x] = sh[255];
#pragma unroll
    for (int j = 0; j < 8; ++j) {
        if (base + j < n) out[base + j] = run;
        run += v[j];
    }
}

__global__ void k_scan2(int* __restrict__ bsums, int nb) {
    int t = threadIdx.x;
    int v = (t < nb) ? bsums[t] : 0;
    __shared__ int sh[256];
    sh[t] = v;
    __syncthreads();
    for (int d = 1; d < 256; d <<= 1) {
        int x = (t >= d) ? sh[t - d] : 0;
        __syncthreads();
        sh[t] += x;
        __syncthreads();
    }
    if (t < nb) bsums[t] = sh[t] - v;
}

__global__ void k_scan3(int* __restrict__ out, const int* __restrict__ bsums, int n) {
    int i = blockIdx.x * 256 + threadIdx.x;
    if (i < n) out[i] += bsums[i / SCAN_ELEMS];
}

// ---- fill (+ last block zeros bns: 8 segments) ----------------------------------------
__global__ void k_fill(const int* __restrict__ e1s, const int* __restrict__ e1d,
                       const int* __restrict__ e2s, const int* __restrict__ e2d,
                       const int* __restrict__ off, const unsigned char* __restrict__ r1s,
                       const unsigned char* __restrict__ r2s,
                       const unsigned char* __restrict__ labBase,
                       const unsigned char* __restrict__ disBase,
                       const unsigned int* __restrict__ labHist,
                       const unsigned int* __restrict__ disHist, int* __restrict__ nbr,
                       float* __restrict__ bns) {
    __shared__ unsigned int slot[NL];
    int b = blockIdx.x, t = threadIdx.x;
    if (b < CNT_BLOCKS) {
        int e = b * 256 + t;
        if (e < E1) {
            int ss = e1s[e];
            int c = e / CHP;
            int pos = off[NL + ND + ss] + (int)labBase[(size_t)c * NP + ss] + (int)r1s[e];
            nbr[pos] = e1d[e];
        } else if (e < E1 + E2) {
            int i = e - E1;
            int ss = e2s[i];
            int c = i / CHP;
            int pos = off[NL + ND + NP + ss] + (int)disBase[(size_t)c * NP + ss] + (int)r2s[i];
            nbr[pos] = e2d[i];
        }
    } else if (b < CNT_BLOCKS + LABHB) {
        int c = b - CNT_BLOCKS;
        for (int i = t; i < NL; i += 256)
            slot[i] = (unsigned int)off[i] + labHist[(size_t)c * NL + i];
        __syncthreads();
        int e0 = c * CHUNK, ee = min(E1, e0 + CHUNK);
        for (int e = e0 + t; e < ee; e += 256) {
            unsigned int pos = atomicAdd(&slot[e1d[e]], 1u);
            nbr[pos] = e1s[e];
        }
    } else if (b < CNT_BLOCKS + LABHB + DISHB) {
        int c = b - CNT_BLOCKS - LABHB;
        for (int i = t; i < ND; i += 256)
            slot[i] = (unsigned int)off[NL + i] + disHist[(size_t)c * ND + i];
        __syncthreads();
        int e0 = c * CHUNK, ee = min(E2, e0 + CHUNK);
        for (int e = e0 + t; e < ee; e += 256) {
            unsigned int pos = atomicAdd(&slot[e2d[e]], 1u);
            nbr[pos] = e2s[e];
        }
    } else {
        for (int i = t; i < 8 * H; i += 256) bns[i] = 0.f;
    }
}

// ---------------- L1 stage1: gather 16-dim mean of x_p per lab/dis row ------------------
// Lane-per-neighbor from the bf16 copy xpb: 32 B per neighbor row (half the f32 bytes),
// 64-128 gathers in flight per wave. Block LDS reduce at the end.
__global__ void k_stage1_L1(const bf16* __restrict__ xpb, const int* __restrict__ off,
                            const int* __restrict__ cnt, const int* __restrict__ nbr,
                            float* __restrict__ mxp) {
    __shared__ float red[4][64][16];  // 16 KB
    int t = threadIdx.x;
    int w = t >> 6, lane = t & 63;
    int row = blockIdx.x * 4 + w;
    float acc[16];
#pragma unroll
    for (int d = 0; d < 16; ++d) acc[d] = 0.f;
    if (row < NROW) {
        int s0 = off[row], c = cnt[row];
        const int* nb = nbr + s0;
        int j = lane;
        for (; j + 64 < c; j += 128) {
            int p0 = nb[j], p1 = nb[j + 64];
            const uint4* r0 = (const uint4*)(xpb + (size_t)p0 * 16);
            const uint4* r1 = (const uint4*)(xpb + (size_t)p1 * 16);
            uint4 u0 = r0[0], u1 = r0[1];
            uint4 v0 = r1[0], v1 = r1[1];
            bfacc2(acc[0], acc[1], u0.x);   bfacc2(acc[2], acc[3], u0.y);
            bfacc2(acc[4], acc[5], u0.z);   bfacc2(acc[6], acc[7], u0.w);
            bfacc2(acc[8], acc[9], u1.x);   bfacc2(acc[10], acc[11], u1.y);
            bfacc2(acc[12], acc[13], u1.z); bfacc2(acc[14], acc[15], u1.w);
            bfacc2(acc[0], acc[1], v0.x);   bfacc2(acc[2], acc[3], v0.y);
            bfacc2(acc[4], acc[5], v0.z);   bfacc2(acc[6], acc[7], v0.w);
            bfacc2(acc[8], acc[9], v1.x);   bfacc2(acc[10], acc[11], v1.y);
            bfacc2(acc[12], acc[13], v1.z); bfacc2(acc[14], acc[15], v1.w);
        }
        if (j < c) {
            const uint4* r0 = (const uint4*)(xpb + (size_t)nb[j] * 16);
            uint4 u0 = r0[0], u1 = r0[1];
            bfacc2(acc[0], acc[1], u0.x);   bfacc2(acc[2], acc[3], u0.y);
            bfacc2(acc[4], acc[5], u0.z);   bfacc2(acc[6], acc[7], u0.w);
            bfacc2(acc[8], acc[9], u1.x);   bfacc2(acc[10], acc[11], u1.y);
            bfacc2(acc[12], acc[13], u1.z); bfacc2(acc[14], acc[15], u1.w);
        }
    }
#pragma unroll
    for (int d = 0; d < 16; ++d) red[w][lane][d] = acc[d];
    __syncthreads();
    if (t < 64) {
        int w2 = t >> 4, d = t & 15;
        int row2 = blockIdx.x * 4 + w2;
        if (row2 < NROW) {
            float s = 0.f;
#pragma unroll 8
            for (int l = 0; l < 64; ++l) s += red[w2][l][d];
            mxp[(size_t)row2 * 16 + d] = s / fmaxf((float)cnt[row2], 1.f);
        }
    }
}

// -------- L1 patmm: scalar gathers + MFMA | lab/dis affine | per-block stats ------------
#define LD1_BLOCKS ((NROW + 1) / 2)
#define HPAD 136
#define APAD 132
__global__ void k_patmm_L1(const bf16* __restrict__ hp, const void* __restrict__ xl,
                           const void* __restrict__ xd, const int* __restrict__ off,
                           const int* __restrict__ cnt, const int* __restrict__ nbr,
                           const bf16* __restrict__ w23bT1, const float* __restrict__ vecs,
                           const float* __restrict__ WpWl0, const float* __restrict__ WpWl1,
                           const float* __restrict__ mxp, bf16* __restrict__ aggp,
                           float* __restrict__ bufL, float* __restrict__ bufD,
                           float* __restrict__ blocksums, const int* __restrict__ flags) {
    int t = threadIdx.x;
    int f32m = flags[0];
    if (blockIdx.x < PAT_BLOCKS) {
        __shared__ bf16 hpA[16][HPAD];
        __shared__ float accf[16][APAD];
        __shared__ float svec[6][128];
        __shared__ float s_mxl[16], s_onL[16], s_d0[16], s_d1[16], s_onD[16];
        int w = t >> 6, lane = t & 63;
        int p0 = blockIdx.x * 16;
        {
            const unsigned int* hpu = (const unsigned int*)(hp + (size_t)p0 * H);
            for (int i = t; i < 16 * 64; i += 256) {
                int r = i >> 6, c = i & 63;
                *(unsigned int*)&hpA[r][2 * c] = hpu[(size_t)r * 64 + c];
            }
        }
        {
            const int map[6] = {0, 1, 2, 3, 4, 12};
            for (int i = t; i < 6 * 128; i += 256)
                svec[i >> 7][i & 127] = vecs[map[i >> 7] * 128 + (i & 127)];
        }
        {
            int g = t >> 4, sl = t & 15;
            int p = p0 + g;
            int s1 = off[NL + ND + p], c1 = cnt[NL + ND + p];
            float a = 0.f;
            for (int j = sl; j < c1; j += 16) a += ldin(xl, nbr[s1 + j], f32m);
            a += __shfl_xor(a, 1);
            a += __shfl_xor(a, 2);
            a += __shfl_xor(a, 4);
            a += __shfl_xor(a, 8);
            int s2 = off[NL + ND + NP + p], c2 = cnt[NL + ND + NP + p];
            float d0 = 0.f, d1 = 0.f;
            for (int j = sl; j < c2; j += 16) {
                int q = nbr[s2 + j];
                d0 += ldin(xd, (size_t)2 * q, f32m);
                d1 += ldin(xd, (size_t)2 * q + 1, f32m);
            }
            d0 += __shfl_xor(d0, 1); d0 += __shfl_xor(d0, 2);
            d0 += __shfl_xor(d0, 4); d0 += __shfl_xor(d0, 8);
            d1 += __shfl_xor(d1, 1); d1 += __shfl_xor(d1, 2);
            d1 += __shfl_xor(d1, 4); d1 += __shfl_xor(d1, 8);
            if (sl == 0) {
                s_mxl[g] = a / fmaxf((float)c1, 1.f);
                s_onL[g] = (c1 > 0) ? 1.f : 0.f;
                s_d0[g] = d0 / fmaxf((float)c2, 1.f);
                s_d1[g] = d1 / fmaxf((float)c2, 1.f);
                s_onD[g] = (c2 > 0) ? 1.f : 0.f;
            }
        }
        __syncthreads();
        {
            int m = lane & 15, kg = lane >> 4;
            bf16x8 afr[4];
#pragma unroll
            for (int ks = 0; ks < 4; ++ks)
                afr[ks] = *(const bf16x8*)&hpA[m][ks * 32 + kg * 8];
            int n0 = w * 32;
#pragma unroll
            for (int tt = 0; tt < 2; ++tt) {
                int nc = n0 + tt * 16 + m;
                f32x4 acc = {0.f, 0.f, 0.f, 0.f};
#pragma unroll
                for (int ks = 0; ks < 4; ++ks) {
                    bf16x8 bfr = *(const bf16x8*)&w23bT1[(size_t)nc * H + ks * 32 + kg * 8];
                    acc = __builtin_amdgcn_mfma_f32_16x16x32_bf16(afr[ks], bfr, acc, 0, 0, 0);
                }
#pragma unroll
                for (int rg = 0; rg < 4; ++rg)
                    accf[kg * 4 + rg][nc] = acc[rg];
            }
        }
        __syncthreads();
        for (int i = t; i < 16 * 64; i += 256) {
            int r = i >> 6, cc = (i & 63) * 2;
            float l0 = s_onL[r] * fmaf(s_mxl[r], svec[0][cc], svec[1][cc]);
            float l1 = s_onL[r] * fmaf(s_mxl[r], svec[0][cc + 1], svec[1][cc + 1]);
            float q0 = s_onD[r] * (s_d0[r] * svec[2][cc] + s_d1[r] * svec[3][cc] + svec[4][cc]);
            float q1 = s_onD[r] * (s_d0[r] * svec[2][cc + 1] + s_d1[r] * svec[3][cc + 1] + svec[4][cc + 1]);
            float v0 = accf[r][cc] + l0 + q0 + svec[5][cc];
            float v1 = accf[r][cc + 1] + l1 + q1 + svec[5][cc + 1];
            accf[r][cc] = v0;
            accf[r][cc + 1] = v1;
            st_bf2(aggp + (size_t)(p0 + r) * H + cc, make_float2(v0, v1));
        }
        __syncthreads();
        if (t < 128) {
            float s = 0.f, q = 0.f;
#pragma unroll
            for (int r = 0; r < 16; ++r) {
                float v = accf[r][t];
                s += v;
                q = fmaf(v, v, q);
            }
            blocksums[(size_t)blockIdx.x * 256 + t] = s;
            blocksums[(size_t)blockIdx.x * 256 + 128 + t] = q;
        }
    } else {
        int bb = blockIdx.x - PAT_BLOCKS;
        int rr = bb * 2 + (t >> 7);
        int h = t & 127;
        if (rr >= NROW) return;
        if (rr < NL) {
            float acc = vecs[6 * 128 + h] + ldin(xl, rr, f32m) * vecs[5 * 128 + h];
            if (cnt[rr] > 0) {
                float s = vecs[10 * 128 + h];
                const float* mx = mxp + (size_t)rr * 16;
#pragma unroll
                for (int k = 0; k < 16; ++k) s = fmaf(mx[k], WpWl0[k * H + h], s);
                acc += s;
            }
            bufL[(size_t)rr * H + h] = acc;
        } else {
            int rd = rr - NL;
            float acc = vecs[9 * 128 + h] + ldin(xd, (size_t)2 * rd, f32m) * vecs[7 * 128 + h] +
                        ldin(xd, (size_t)2 * rd + 1, f32m) * vecs[8 * 128 + h];
            if (cnt[rr] > 0) {
                float s = vecs[11 * 128 + h];
                const float* mx = mxp + (size_t)rr * 16;
#pragma unroll
                for (int k = 0; k < 16; ++k) s = fmaf(mx[k], WpWl1[k * H + h], s);
                acc += s;
            }
            bufD[(size_t)rd * H + h] = acc;
        }
    }
}

// -------- bnred: patient stats from blocksums (+ lab/dis stats when grid>64) -----------
__global__ void k_bnred(const float* __restrict__ blocksums, const float* __restrict__ bufL,
                        const float* __restrict__ bufD, float* __restrict__ sums) {
    int b = blockIdx.x, t = threadIdx.x;
    if (b < 64) {
        float acc = 0.f;
        for (int r = b; r < PAT_BLOCKS; r += 64) acc += blocksums[(size_t)r * 256 + t];
        atomicAdd(&sums[t], acc);
        return;
    }
    int h = t & 127;
    int sub = t >> 7;
    float s = 0.f, s2 = 0.f;
    float* sm;
    if (b < 320) {
        int bid = b - 64;
        for (int i = bid * 2 + sub; i < NL; i += 512) {
            float v = bufL[(size_t)i * H + h];
            s += v;
            s2 = fmaf(v, v, s2);
        }
        sm = sums + 2 * H;
    } else {
        int bid = b - 320;
        for (int i = bid * 2 + sub; i < ND; i += 128) {
            float v = bufD[(size_t)i * H + h];
            s += v;
            s2 = fmaf(v, v, s2);
        }
        sm = sums + 4 * H;
    }
    __shared__ float ls[256], ls2[256];
    ls[t] = s;
    ls2[t] = s2;
    __syncthreads();
    if (sub == 0) {
        atomicAdd(&sm[h], s + ls[128 + h]);
        atomicAdd(&sm[H + h], s2 + ls2[128 + h]);
    }
}

// ---- L2 stage1: mm_small (L1 lab/dis BN inline) + prep23 + head-W1 precompute ----------
#define S2_MM 1313
#define S2_PREP 64
#define S2_TOTAL (S2_MM + S2_PREP)
__global__ void k_stage1_L2(const float* __restrict__ bufL, const float* __restrict__ bufD,
                            const float* __restrict__ bns, const void* __restrict__ bng1,
                            const void* __restrict__ bnb1, const void* __restrict__ Wl,
                            bf16* __restrict__ tlp, bf16* __restrict__ tdp,
                            const void* __restrict__ Wr, const void* __restrict__ bl,
                            bf16* __restrict__ w23bT, float* __restrict__ b23,
                            const void* __restrict__ W1in, bf16* __restrict__ w1T,
                            const int* __restrict__ flags) {
    __shared__ float smm[8][H];
    int b = blockIdx.x, t = threadIdx.x;
    int f32m = flags[0];
    if (b < S2_MM) {
        int bb = b;
        bool lab = bb < 1250;
        const float* buf = lab ? bufL : bufD;
        int N = lab ? NL : ND;
        float invN = lab ? 1.f / NL : 1.f / ND;
        int so = lab ? 2 * H : 4 * H;
        int go = lab ? H : 2 * H;
        bf16* outp = lab ? tlp : tdp;
        size_t woff = lab ? (size_t)2 * HH : (size_t)3 * HH;
        int r0 = (lab ? bb : bb - 1250) * 8;
        int h = t & 127, half = t >> 7;
        float m = bns[so + h] * invN;
        float v = fmaf(-m, m, bns[so + H + h] * invN);
        float sc = rsqrtf(v + 1e-5f) * ldin(bng1, go + h, f32m);
        float be = ldin(bnb1, go + h, f32m);
        for (int r = half; r < 8; r += 2) {
            int ri = r0 + r;
            float x = (ri < N) ? buf[(size_t)ri * H + h] : 0.f;
            smm[r][h] = (ri < N) ? fmaxf(fmaf(x - m, sc, be), 0.f) : 0.f;
        }
        __syncthreads();
        int rb = half * 4;
        float a0 = 0.f, a1 = 0.f, a2 = 0.f, a3 = 0.f;
        for (int k = 0; k < H; ++k) {
            float wv = ldin(Wl, woff + (size_t)k * H + h, f32m);
            a0 = fmaf(smm[rb + 0][k], wv, a0);
            a1 = fmaf(smm[rb + 1][k], wv, a1);
            a2 = fmaf(smm[rb + 2][k], wv, a2);
            a3 = fmaf(smm[rb + 3][k], wv, a3);
        }
        float acc[4] = {a0, a1, a2, a3};
#pragma unroll
        for (int r = 0; r < 4; ++r)
            if (r0 + rb + r < N)
                outp[(size_t)(r0 + rb + r) * H + h] = __float2bfloat16(acc[r]);
    } else {
        int pb = b - S2_MM;
        int idx = pb * 256 + t;
        if (idx < HH) {
            int k = idx >> 7, n = idx & 127;
            float v = ldin(Wr, (size_t)2 * HH + idx, f32m) + ldin(Wr, (size_t)3 * HH + idx, f32m);
            w23bT[(size_t)n * H + k] = __float2bfloat16(v);
        }
        if (idx < H)
            b23[idx] = ldin(bl, (size_t)2 * H + idx, f32m) + ldin(bl, (size_t)3 * H + idx, f32m);
        if (idx < 64 * H) {  // head FC1 weight, transposed to [n][k] bf16 for MFMA B-operand
            int n = idx >> 7, k = idx & 127;
            w1T[idx] = __float2bfloat16(ldin(W1in, (size_t)k * 64 + n, f32m));
        }
    }
}

// -------- L2 patmm: in-place aggp update (L1 pat BN inline) + per-block stats -----------
// Gather: QUARTER-wave (16 lanes) per patient row, 16 B (8 cols) per lane. Each
// quarter-wave owns exactly one patient (no serial rp loop) -> half the dependent
// iterations per wave and half the vmem instructions per edge. SW-pipelined index
// prefetch. aggp staging read is non-temporal (read-once). Stores temporal.
__global__ void k_patmm_L2(bf16* __restrict__ aggp, const bf16* __restrict__ tlp,
                           const bf16* __restrict__ tdp, const int* __restrict__ off,
                           const int* __restrict__ cnt, const int* __restrict__ nbr,
                           const bf16* __restrict__ w23bT, const float* __restrict__ b23,
                           const float* __restrict__ bns, const void* __restrict__ bng1,
                           const void* __restrict__ bnb1, float* __restrict__ blocksums,
                           const int* __restrict__ flags) {
    __shared__ bf16 hpA[16][HPAD];
    __shared__ __align__(16) float accf[16][APAD];
    int t = threadIdx.x;
    int f32m = flags[0];
    int w = t >> 6, lane = t & 63;
    int p0 = blockIdx.x * 16;
    {
        int cc = (t & 63) * 2;
        const float invN = 1.f / NP;
        float m0 = bns[cc] * invN, m1 = bns[cc + 1] * invN;
        float v0 = fmaf(-m0, m0, bns[128 + cc] * invN);
        float v1 = fmaf(-m1, m1, bns[128 + cc + 1] * invN);
        float sc0 = rsqrtf(v0 + 1e-5f) * ldin(bng1, cc, f32m);
        float sc1 = rsqrtf(v1 + 1e-5f) * ldin(bng1, cc + 1, f32m);
        float be0 = ldin(bnb1, cc, f32m), be1 = ldin(bnb1, cc + 1, f32m);
        for (int i = t; i < 16 * 64; i += 256) {
            int r = i >> 6;
            float2 v = ld_bf2_nt(aggp + (size_t)(p0 + r) * H + cc);
            st_bf2(&hpA[r][cc], make_float2(fmaxf(fmaf(v.x - m0, sc0, be0), 0.f),
                                            fmaxf(fmaf(v.y - m1, sc1, be1), 0.f)));
        }
    }
    {
        const int* off1 = off + NL + ND;
        const int* cnt1 = cnt + NL + ND;
        const int* off2 = off + NL + ND + NP;
        const int* cnt2 = cnt + NL + ND + NP;
        int qw = lane >> 4, ql = lane & 15;  // 16 quarter-waves; each owns ONE patient
        int p = p0 + w * 4 + qw;
        int cb = ql * 8;                     // this lane's 8 columns (16 B)
        float4 bb0 = *(const float4*)(b23 + cb);
        float4 bb1 = *(const float4*)(b23 + cb + 4);
        int s1 = off1[p], c1 = cnt1[p];
        const int* nb1 = nbr + s1;
        float a0 = 0.f, a1 = 0.f, a2 = 0.f, a3 = 0.f, a4 = 0.f, a5 = 0.f, a6 = 0.f, a7 = 0.f;
        float g0 = 0.f, g1 = 0.f, g2 = 0.f, g3 = 0.f, g4 = 0.f, g5 = 0.f, g6 = 0.f, g7 = 0.f;
        int j = 0;
        int i0, i1, i2, i3;
        if (c1 >= 4) { i0 = nb1[0]; i1 = nb1[1]; i2 = nb1[2]; i3 = nb1[3]; }
        for (; j + 8 <= c1; j += 4) {
            uint4 v0 = *(const uint4*)(tlp + (size_t)i0 * H + cb);
            uint4 v1 = *(const uint4*)(tlp + (size_t)i1 * H + cb);
            uint4 v2 = *(const uint4*)(tlp + (size_t)i2 * H + cb);
            uint4 v3 = *(const uint4*)(tlp + (size_t)i3 * H + cb);
            int n0 = nb1[j + 4], n1 = nb1[j + 5], n2 = nb1[j + 6], n3 = nb1[j + 7];
            bfacc2(a0, a1, v0.x); bfacc2(a2, a3, v0.y); bfacc2(a4, a5, v0.z); bfacc2(a6, a7, v0.w);
            bfacc2(g0, g1, v1.x); bfacc2(g2, g3, v1.y); bfacc2(g4, g5, v1.z); bfacc2(g6, g7, v1.w);
            bfacc2(a0, a1, v2.x); bfacc2(a2, a3, v2.y); bfacc2(a4, a5, v2.z); bfacc2(a6, a7, v2.w);
            bfacc2(g0, g1, v3.x); bfacc2(g2, g3, v3.y); bfacc2(g4, g5, v3.z); bfacc2(g6, g7, v3.w);
            i0 = n0; i1 = n1; i2 = n2; i3 = n3;
        }
        if (j + 4 <= c1) {
            uint4 v0 = *(const uint4*)(tlp + (size_t)i0 * H + cb);
            uint4 v1 = *(const uint4*)(tlp + (size_t)i1 * H + cb);
            uint4 v2 = *(const uint4*)(tlp + (size_t)i2 * H + cb);
            uint4 v3 = *(const uint4*)(tlp + (size_t)i3 * H + cb);
            bfacc2(a0, a1, v0.x); bfacc2(a2, a3, v0.y); bfacc2(a4, a5, v0.z); bfacc2(a6, a7, v0.w);
            bfacc2(g0, g1, v1.x); bfacc2(g2, g3, v1.y); bfacc2(g4, g5, v1.z); bfacc2(g6, g7, v1.w);
            bfacc2(a0, a1, v2.x); bfacc2(a2, a3, v2.y); bfacc2(a4, a5, v2.z); bfacc2(a6, a7, v2.w);
            bfacc2(g0, g1, v3.x); bfacc2(g2, g3, v3.y); bfacc2(g4, g5, v3.z); bfacc2(g6, g7, v3.w);
            j += 4;
        }
        for (; j < c1; ++j) {
            uint4 v = *(const uint4*)(tlp + (size_t)nb1[j] * H + cb);
            bfacc2(a0, a1, v.x); bfacc2(a2, a3, v.y); bfacc2(a4, a5, v.z); bfacc2(a6, a7, v.w);
        }
        a0 += g0; a1 += g1; a2 += g2; a3 += g3;
        a4 += g4; a5 += g5; a6 += g6; a7 += g7;
        int s2 = off2[p], c2 = cnt2[p];
        const int* nb2 = nbr + s2;
        float d0 = 0.f, d1 = 0.f, d2 = 0.f, d3 = 0.f, d4 = 0.f, d5 = 0.f, d6 = 0.f, d7 = 0.f;
        float e0 = 0.f, e1 = 0.f, e2 = 0.f, e3 = 0.f, e4 = 0.f, e5 = 0.f, e6 = 0.f, e7 = 0.f;
        j = 0;
        int k0, k1;
        if (c2 >= 2) { k0 = nb2[0]; k1 = nb2[1]; }
        for (; j + 4 <= c2; j += 2) {
            uint4 v0 = *(const uint4*)(tdp + (size_t)k0 * H + cb);
            uint4 v1 = *(const uint4*)(tdp + (size_t)k1 * H + cb);
            int n0 = nb2[j + 2], n1 = nb2[j + 3];
            bfacc2(d0, d1, v0.x); bfacc2(d2, d3, v0.y); bfacc2(d4, d5, v0.z); bfacc2(d6, d7, v0.w);
            bfacc2(e0, e1, v1.x); bfacc2(e2, e3, v1.y); bfacc2(e4, e5, v1.z); bfacc2(e6, e7, v1.w);
            k0 = n0; k1 = n1;
        }
        if (j + 2 <= c2) {
            uint4 v0 = *(const uint4*)(tdp + (size_t)k0 * H + cb);
            uint4 v1 = *(const uint4*)(tdp + (size_t)k1 * H + cb);
            bfacc2(d0, d1, v0.x); bfacc2(d2, d3, v0.y); bfacc2(d4, d5, v0.z); bfacc2(d6, d7, v0.w);
            bfacc2(e0, e1, v1.x); bfacc2(e2, e3, v1.y); bfacc2(e4, e5, v1.z); bfacc2(e6, e7, v1.w);
            j += 2;
        }
        if (j < c2) {
            uint4 v = *(const uint4*)(tdp + (size_t)nb2[j] * H + cb);
            bfacc2(d0, d1, v.x); bfacc2(d2, d3, v.y); bfacc2(d4, d5, v.z); bfacc2(d6, d7, v.w);
        }
        d0 += e0; d1 += e1; d2 += e2; d3 += e3;
        d4 += e4; d5 += e5; d6 += e6; d7 += e7;
        float i1f = 1.f / fmaxf((float)c1, 1.f), i2f = 1.f / fmaxf((float)c2, 1.f);
        float4 r0v, r1v;
        r0v.x = a0 * i1f + d0 * i2f + bb0.x;
        r0v.y = a1 * i1f + d1 * i2f + bb0.y;
        r0v.z = a2 * i1f + d2 * i2f + bb0.z;
        r0v.w = a3 * i1f + d3 * i2f + bb0.w;
        r1v.x = a4 * i1f + d4 * i2f + bb1.x;
        r1v.y = a5 * i1f + d5 * i2f + bb1.y;
        r1v.z = a6 * i1f + d6 * i2f + bb1.z;
        r1v.w = a7 * i1f + d7 * i2f + bb1.w;
        *(float4*)&accf[w * 4 + qw][cb] = r0v;
        *(float4*)&accf[w * 4 + qw][cb + 4] = r1v;
    }
    __syncthreads();
    {
        int m = lane & 15, kg = lane >> 4;
        bf16x8 afr[4];
#pragma unroll
        for (int ks = 0; ks < 4; ++ks)
            afr[ks] = *(const bf16x8*)&hpA[m][ks * 32 + kg * 8];
        int n0 = w * 32;
#pragma unroll
        for (int tt = 0; tt < 2; ++tt) {
            int nc = n0 + tt * 16 + m;
            f32x4 acc = {0.f, 0.f, 0.f, 0.f};
#pragma unroll
            for (int ks = 0; ks < 4; ++ks) {
                bf16x8 bfr = *(const bf16x8*)&w23bT[(size_t)nc * H + ks * 32 + kg * 8];
                acc = __builtin_amdgcn_mfma_f32_16x16x32_bf16(afr[ks], bfr, acc, 0, 0, 0);
            }
#pragma unroll
            for (int rg = 0; rg < 4; ++rg)
                accf[kg * 4 + rg][nc] += acc[rg];
        }
    }
    __syncthreads();
    for (int i = t; i < 16 * 64; i += 256) {
        int r = i >> 6, cc = (i & 63) * 2;
        st_bf2(aggp + (size_t)(p0 + r) * H + cc, make_float2(accf[r][cc], accf[r][cc + 1]));
    }
    if (t < 128) {
        float s = 0.f, q = 0.f;
#pragma unroll
        for (int r = 0; r < 16; ++r) {
            float v = accf[r][t];
            s += v;
            q = fmaf(v, v, q);
        }
        blocksums[(size_t)blockIdx.x * 256 + t] = s;
        blocksums[(size_t)blockIdx.x * 256 + 128 + t] = q;
    }
}

// ---------------- head: fused L2 patient BN+ReLU -> MFMA FC1 -> FC2 -> log_softmax ------
__global__ void k_head(const bf16* __restrict__ aggp, const float* __restrict__ sums,
                       const void* __restrict__ bng, const void* __restrict__ bnb,
                       const bf16* __restrict__ w1T, const void* __restrict__ b1,
                       const void* __restrict__ W2, const void* __restrict__ b2f,
                       void* __restrict__ out, const int* __restrict__ flags) {
    int f32m = flags[0];
    __shared__ bf16 hpA[16][HPAD];
    __shared__ float h1s[16][68];
    __shared__ float lgs[16][16];
    __shared__ float W2s[64 * NOUT];
    __shared__ float b1s[64], b2s[NOUT];
    int t = threadIdx.x;
    int w = t >> 6, lane = t & 63;
    for (int i = t; i < 64 * NOUT; i += 256) W2s[i] = ldin(W2, i, f32m);
    if (t < 64) b1s[t] = ldin(b1, t, f32m);
    else if (t >= 64 && t < 64 + NOUT) b2s[t - 64] = ldin(b2f, t - 64, f32m);
    int p0 = blockIdx.x * 16;
    {
        int cc = (t & 63) * 2;
        const float invN = 1.f / NP;
        float m0 = sums[cc] * invN, m1 = sums[cc + 1] * invN;
        float v0 = fmaf(-m0, m0, sums[128 + cc] * invN);
        float v1 = fmaf(-m1, m1, sums[128 + cc + 1] * invN);
        float sc0 = rsqrtf(v0 + 1e-5f) * ldin(bng, cc, f32m);
        float sc1 = rsqrtf(v1 + 1e-5f) * ldin(bng, cc + 1, f32m);
        float be0 = ldin(bnb, cc, f32m), be1 = ldin(bnb, cc + 1, f32m);
        for (int i = t; i < 16 * 64; i += 256) {
            int r = i >> 6;
            float2 v = ld_bf2_nt(aggp + (size_t)(p0 + r) * H + cc);
            st_bf2(&hpA[r][cc], make_float2(fmaxf(fmaf(v.x - m0, sc0, be0), 0.f),
                                            fmaxf(fmaf(v.y - m1, sc1, be1), 0.f)));
        }
    }
    __syncthreads();
    {
        // MFMA FC1: wave w computes output cols [w*16, w*16+16); K=128 over 4 ksteps.
        int m = lane & 15, kg = lane >> 4;
        bf16x8 afr[4];
#pragma unroll
        for (int ks = 0; ks < 4; ++ks)
            afr[ks] = *(const bf16x8*)&hpA[m][ks * 32 + kg * 8];
        int nc = w * 16 + m;
        f32x4 acc = {0.f, 0.f, 0.f, 0.f};
#pragma unroll
        for (int ks = 0; ks < 4; ++ks) {
            bf16x8 bfr = *(const bf16x8*)&w1T[(size_t)nc * H + ks * 32 + kg * 8];
            acc = __builtin_amdgcn_mfma_f32_16x16x32_bf16(afr[ks], bfr, acc, 0, 0, 0);
        }
        float bv = b1s[nc];
#pragma unroll
        for (int rg = 0; rg < 4; ++rg)
            h1s[kg * 4 + rg][nc] = fmaxf(acc[rg] + bv, 0.f);
    }
    __syncthreads();
    int pat = lane >> 4, oidx = lane & 15;
    int prow = 4 * w + pat;
    float lg = 0.f;
    if (oidx < NOUT) {
        lg = b2s[oidx];
        const float* hh = h1s[prow];
#pragma unroll 8
        for (int k = 0; k < 64; ++k) lg = fmaf(hh[k], W2s[k * NOUT + oidx], lg);
        lgs[prow][oidx] = lg;
    }
    __syncthreads();
    if (oidx < NOUT) {
        float m = -1e30f;
#pragma unroll
        for (int k = 0; k < NOUT; ++k) m = fmaxf(m, lgs[prow][k]);
        float s = 0.f;
#pragma unroll
        for (int k = 0; k < NOUT; ++k) s += __expf(lgs[prow][k] - m);
        float r = lg - m - __logf(s);
        if (f32m)
            ((float*)out)[(size_t)(p0 + prow) * NOUT + oidx] = r;
        else
            ((bf16*)out)[(size_t)(p0 + prow) * NOUT + oidx] = __float2bfloat16(r);
    }
}

extern "C" void kernel_launch(void* const* d_in, const int* in_sizes, int n_in, void* d_out,
                              int out_size, void* d_ws, size_t ws_size, hipStream_t stream) {
    const int* e1s = (const int*)d_in[23];
    const int* e1d = (const int*)d_in[24];
    const int* e2s = (const int*)d_in[25];
    const int* e2d = (const int*)d_in[26];
    const int NPOOL = 2 * (E1 + E2);

    char* wsb = (char*)d_ws;
    size_t o = 0;
    auto af = [&](size_t nwords) { void* p = wsb + o * 4; o += nwords; return p; };
    int* flags = (int*)af(16);
    bf16* w23bT = (bf16*)af(HH / 2);
    bf16* w23bT1 = (bf16*)af(HH / 2);
    bf16* w1T = (bf16*)af(64 * H / 2);
    float* b23 = (float*)af(H);
    float* bns = (float*)af(8 * H);
    int* bsums = (int*)af(256);
    float* WpWl0 = (float*)af(16 * H);
    float* WpWl1 = (float*)af(16 * H);
    float* vecs = (float*)af(13 * 128);
    int* cnt = (int*)af(NCNT);
    int* off = (int*)af(NCNT);
    int* nbr = (int*)af(NPOOL);
    bf16* hp = (bf16*)af((size_t)NP * H / 2);
    bf16* xpb = (bf16*)af((size_t)NP * 16 / 2);
    size_t arena = o;
    unsigned char* r1s = (unsigned char*)af(E1 / 4);
    unsigned char* r2s = (unsigned char*)af(E2 / 4);
    unsigned int* labHistP = (unsigned int*)af((size_t)NCH1 * NPW);
    unsigned int* disHistP = (unsigned int*)af((size_t)NCH2 * NPW);
    unsigned int* labHist = (unsigned int*)af((size_t)LABHB * NL);
    unsigned int* disHist = (unsigned int*)af((size_t)DISHB * ND);
    size_t endA = o;
    o = arena;
    float* bufL = (float*)af((size_t)NL * H);
    float* bufD = (float*)af((size_t)ND * H);
    bf16* tlp = (bf16*)af((size_t)NL * H / 2);
    bf16* tdp = (bf16*)af((size_t)ND * H / 2);
    bf16* aggp = (bf16*)af((size_t)NP * H / 2);
    float* mxp = (float*)af((size_t)NROW * 16);
    float* blocksums = (float*)af((size_t)PAT_BLOCKS * 256);
    size_t endB = o;
    o = endA > endB ? endA : endB;
    (void)ws_size;

    k_hist<<<HB3 + 1, 1024, 0, stream>>>(e1s, e1d, e2s, e2d, labHistP, disHistP, r1s, r2s,
                                         labHist, disHist, (const unsigned short*)d_in[0],
                                         flags);
    k_reduce<<<RB7, 256, 0, stream>>>(labHist, disHist, labHistP, disHistP, cnt, d_in[0],
                                      d_in[3], d_in[4], d_in[5], d_in[6], d_in[7], d_in[8],
                                      d_in[9], d_in[10], d_in[11], hp, WpWl0, WpWl1, vecs,
                                      w23bT1, xpb, flags);
    int nb = (NCNT + SCAN_ELEMS - 1) / SCAN_ELEMS;
    k_scan1<<<nb, 256, 0, stream>>>(cnt, off, bsums, NCNT);
    k_scan2<<<1, 256, 0, stream>>>(bsums, nb);
    k_scan3<<<(NCNT + 255) / 256, 256, 0, stream>>>(off, bsums, NCNT);
    k_fill<<<CNT_BLOCKS + LABHB + DISHB + 1, 256, 0, stream>>>(
        e1s, e1d, e2s, e2d, off, r1s, r2s, (const unsigned char*)labHistP,
        (const unsigned char*)disHistP, labHist, disHist, nbr, bns);

    // ---- layer 1 (algebraically collapsed) ----
    k_stage1_L1<<<(NROW + 3) / 4, 256, 0, stream>>>(xpb, off, cnt, nbr, mxp);
    k_patmm_L1<<<PAT_BLOCKS + LD1_BLOCKS, 256, 0, stream>>>(hp, d_in[1], d_in[2], off, cnt, nbr,
                                                            w23bT1, vecs, WpWl0, WpWl1, mxp,
                                                            aggp, bufL, bufD, blocksums, flags);
    k_bnred<<<384, 256, 0, stream>>>(blocksums, bufL, bufD, bns);

    // ---- layer 2: all BN applications fused into consumers ----
    k_stage1_L2<<<S2_TOTAL, 256, 0, stream>>>(bufL, bufD, bns, d_in[15], d_in[16], d_in[12],
                                              tlp, tdp, d_in[14], d_in[13], w23bT, b23,
                                              d_in[19], w1T, flags);
    k_patmm_L2<<<PAT_BLOCKS, 256, 0, stream>>>(aggp, tlp, tdp, off, cnt, nbr, w23bT, b23, bns,
                                               d_in[15], d_in[16], blocksums, flags);
    k_bnred<<<64, 256, 0, stream>>>(blocksums, bufL, bufD, bns + 6 * H);
    k_head<<<NP / 16, 256, 0, stream>>>(aggp, bns + 6 * H, d_in[17], d_in[18], w1T,
                                        d_in[20], d_in[21], d_in[22], d_out, flags);
}

// Round 12
// 538.522 us; speedup vs baseline: 1.3381x; 1.0001x over previous
//
#include <hip/hip_runtime.h>
#include <hip/hip_bf16.h>

#define NP 100000
#define NL 10000
#define ND 500
#define H 128
#define HH (H * H)
#define E1 2000000
#define E2 500000
#define EP (E1 + E2)
#define NOUT 10
#define NCNT (NL + ND + 2 * NP)
#define NROW (NL + ND)
#define CHUNK 8192
#define LABHB ((E1 + CHUNK - 1) / CHUNK)
#define DISHB ((E2 + CHUNK - 1) / CHUNK)
#define CNT_BLOCKS ((E1 + E2 + 255) / 256)
#define RED_LAB ((NL + 255) / 256)
#define RED_DIS ((ND + 255) / 256)
#define PAT_BLOCKS (NP / 16)

// patient-side chunked LDS histogram sort (replaces global atomics)
#define CHP 15625
#define NCH1 (E1 / CHP) /* 128 */
#define NCH2 (E2 / CHP) /* 32 */
#define NPW (NP / 4)    /* 25000 packed-byte words = 100 KB LDS */
#define RPW ((NPW + 255) / 256)

typedef __hip_bfloat16 bf16;
typedef __attribute__((ext_vector_type(8))) short bf16x8;
typedef __attribute__((ext_vector_type(4))) float f32x4;

__device__ __forceinline__ float bfbits2f(unsigned short s) {
    union { unsigned int u; float f; } v;
    v.u = (unsigned int)s << 16;
    return v.f;
}
__device__ __forceinline__ float2 ld_bf2(const bf16* p) {
    unsigned int u = *(const unsigned int*)p;
    return make_float2(bfbits2f((unsigned short)(u & 0xFFFFu)), bfbits2f((unsigned short)(u >> 16)));
}
__device__ __forceinline__ float2 ld_bf2_nt(const bf16* p) {
    unsigned int u = __builtin_nontemporal_load((const unsigned int*)p);
    return make_float2(bfbits2f((unsigned short)(u & 0xFFFFu)), bfbits2f((unsigned short)(u >> 16)));
}
__device__ __forceinline__ void st_bf2(bf16* p, float2 v) {
    union { unsigned int u; bf16 b[2]; } t;
    t.b[0] = __float2bfloat16(v.x);
    t.b[1] = __float2bfloat16(v.y);
    *(unsigned int*)p = t.u;
}
__device__ __forceinline__ float ldin(const void* p, size_t i, int f32m) {
    return f32m ? ((const float*)p)[i] : __bfloat162float(((const bf16*)p)[i]);
}
// accumulate 2 packed bf16 (one u32) into two f32 accumulators: 2 unpack + 2 add VALU
__device__ __forceinline__ void bfacc2(float& x, float& y, unsigned int u) {
    union { unsigned int q; float f; } lo, hi;
    lo.q = u << 16;
    hi.q = u & 0xFFFF0000u;
    x += lo.f;
    y += hi.f;
}

// ---- k_hist: all histograms via LDS (no global atomics), 1024 threads -----------------
// Last block (b == HB3) performs input-dtype detection (folded k_detect).
#define HB0 NCH1
#define HB1 (HB0 + NCH2)
#define HB2 (HB1 + LABHB)
#define HB3 (HB2 + DISHB)
__global__ void k_hist(const int* __restrict__ e1s, const int* __restrict__ e1d,
                       const int* __restrict__ e2s, const int* __restrict__ e2d,
                       unsigned int* __restrict__ labHistP, unsigned int* __restrict__ disHistP,
                       unsigned char* __restrict__ r1s, unsigned char* __restrict__ r2s,
                       unsigned int* __restrict__ labHist, unsigned int* __restrict__ disHist,
                       const unsigned short* __restrict__ xpw, int* __restrict__ flags) {
    __shared__ unsigned int sh[NPW];  // 100 KB: byte-packed patient counters / reused by dest hists
    int b = blockIdx.x, t = threadIdx.x;
    if (b < HB1) {
        for (int i = t; i < NPW; i += 1024) sh[i] = 0;
        __syncthreads();
        if (b < HB0) {
            int e0 = b * CHP;
            for (int j = t; j < CHP; j += 1024) {
                int e = e0 + j;
                int ss = e1s[e];
                unsigned int old = atomicAdd(&sh[ss >> 2], 1u << (8 * (ss & 3)));
                r1s[e] = (unsigned char)(old >> (8 * (ss & 3)));
            }
            __syncthreads();
            unsigned int* out = labHistP + (size_t)b * NPW;
            for (int i = t; i < NPW; i += 1024) out[i] = sh[i];
        } else {
            int c = b - HB0;
            int e0 = c * CHP;
            for (int j = t; j < CHP; j += 1024) {
                int e = e0 + j;
                int ss = e2s[e];
                unsigned int old = atomicAdd(&sh[ss >> 2], 1u << (8 * (ss & 3)));
                r2s[e] = (unsigned char)(old >> (8 * (ss & 3)));
            }
            __syncthreads();
            unsigned int* out = disHistP + (size_t)c * NPW;
            for (int i = t; i < NPW; i += 1024) out[i] = sh[i];
        }
    } else if (b < HB2) {
        int c = b - HB1;
        for (int i = t; i < NL / 2; i += 1024) sh[i] = 0;
        __syncthreads();
        int e0 = c * CHUNK, ee = min(E1, e0 + CHUNK);
        for (int e = e0 + t; e < ee; e += 1024) {
            int dd = e1d[e];
            atomicAdd(&sh[dd >> 1], 1u << (16 * (dd & 1)));
        }
        __syncthreads();
        for (int i = t; i < NL; i += 1024)
            labHist[(size_t)c * NL + i] = (sh[i >> 1] >> (16 * (i & 1))) & 0xFFFFu;
    } else if (b < HB3) {
        int c = b - HB2;
        for (int i = t; i < ND / 2; i += 1024) sh[i] = 0;
        __syncthreads();
        int e0 = c * CHUNK, ee = min(E2, e0 + CHUNK);
        for (int e = e0 + t; e < ee; e += 1024) {
            int dd = e2d[e];
            atomicAdd(&sh[dd >> 1], 1u << (16 * (dd & 1)));
        }
        __syncthreads();
        for (int i = t; i < ND; i += 1024)
            disHist[(size_t)c * ND + i] = (sh[i >> 1] >> (16 * (i & 1))) & 0xFFFFu;
    } else {
        // dtype detection (flags consumed first by k_reduce, next in stream order)
        int cnt = 0;
        for (int i = t; i < 4096; i += 1024) {
            unsigned short w = xpw[2 * i];
            int e = (w >> 7) & 0xFF;
            if (w == 0 || (e >= 114 && e <= 141)) cnt++;
        }
        int* shi = (int*)sh;
        shi[t] = cnt;
        __syncthreads();
        for (int s = 512; s > 0; s >>= 1) {
            if (t < s) shi[t] += shi[t + s];
            __syncthreads();
        }
        if (t == 0) flags[0] = (shi[0] < 2048) ? 1 : 0;
    }
}

// ---- reduce: chunk exclusive bases (packed-byte scan for patients); totals -> cnt ------
// Embed branch is block-tiled: 256 patients/block, Wp in LDS, xp row in registers.
#define EMB2 ((NP + 255) / 256)
#define RB0 RED_LAB
#define RB1 (RB0 + RED_DIS)
#define RB2 (RB1 + RPW)
#define RB3 (RB2 + RPW)
#define RB4 (RB3 + EMB2)
#define RB5 (RB4 + 16)
#define RB6 (RB5 + 7)
#define RB7 (RB6 + 64)
__global__ void k_reduce(unsigned int* __restrict__ labHist, unsigned int* __restrict__ disHist,
                         unsigned int* __restrict__ labHistP, unsigned int* __restrict__ disHistP,
                         int* __restrict__ cnt, const void* __restrict__ xp,
                         const void* __restrict__ Wp, const void* __restrict__ bp,
                         const void* __restrict__ Wlab, const void* __restrict__ blab,
                         const void* __restrict__ Wdis, const void* __restrict__ bdis,
                         const void* __restrict__ Wl1, const void* __restrict__ bl1,
                         const void* __restrict__ Wr1, bf16* __restrict__ hp,
                         float* __restrict__ WpWl0, float* __restrict__ WpWl1,
                         float* __restrict__ vecs, bf16* __restrict__ w23bT1,
                         bf16* __restrict__ xpb, const int* __restrict__ flags) {
    int b = blockIdx.x, t = threadIdx.x;
    if (b < RB0) {
        int bin = b * 256 + t;
        if (bin < NL) {
            unsigned int run = 0;
            for (int k = 0; k < LABHB; ++k) {
                unsigned int x = labHist[(size_t)k * NL + bin];
                labHist[(size_t)k * NL + bin] = run;
                run += x;
            }
            cnt[bin] = (int)run;
        }
    } else if (b < RB1) {
        int bin = (b - RB0) * 256 + t;
        if (bin < ND) {
            unsigned int run = 0;
            for (int k = 0; k < DISHB; ++k) {
                unsigned int x = disHist[(size_t)k * ND + bin];
                disHist[(size_t)k * ND + bin] = run;
                run += x;
            }
            cnt[NL + bin] = (int)run;
        }
    } else if (b < RB2) {
        int w = (b - RB1) * 256 + t;
        if (w < NPW) {
            unsigned int run = 0;  // 4 byte-lanes scanned in parallel; degree < 256 so no carry
            for (int c = 0; c < NCH1; ++c) {
                unsigned int x = labHistP[(size_t)c * NPW + w];
                labHistP[(size_t)c * NPW + w] = run;
                run += x;
            }
            int base = NL + ND + 4 * w;
            cnt[base] = (int)(run & 0xFFu);
            cnt[base + 1] = (int)((run >> 8) & 0xFFu);
            cnt[base + 2] = (int)((run >> 16) & 0xFFu);
            cnt[base + 3] = (int)(run >> 24);
        }
    } else if (b < RB3) {
        int w = (b - RB2) * 256 + t;
        if (w < NPW) {
            unsigned int run = 0;
            for (int c = 0; c < NCH2; ++c) {
                unsigned int x = disHistP[(size_t)c * NPW + w];
                disHistP[(size_t)c * NPW + w] = run;
                run += x;
            }
            int base = NL + ND + NP + 4 * w;
            cnt[base] = (int)(run & 0xFFu);
            cnt[base + 1] = (int)((run >> 8) & 0xFFu);
            cnt[base + 2] = (int)((run >> 16) & 0xFFu);
            cnt[base + 3] = (int)(run >> 24);
        }
    } else if (b < RB4) {
        // block-tiled embed: 256 patients/block; Wp+bp staged in LDS (wave-uniform
        // broadcast reads); xp row held in registers; vectorized bf16 stores.
        __shared__ float Wps[16 * 128];
        __shared__ float bps[128];
        int f32m = flags[0];
        for (int i = t; i < 16 * 128; i += 256) Wps[i] = ldin(Wp, i, f32m);
        if (t < 128) bps[t] = ldin(bp, t, f32m);
        __syncthreads();
        int p = (b - RB3) * 256 + t;
        if (p < NP) {
            float xr[16];
#pragma unroll
            for (int k = 0; k < 16; ++k) xr[k] = ldin(xp, (size_t)p * 16 + k, f32m);
            unsigned int xw[8];
#pragma unroll
            for (int k2 = 0; k2 < 8; ++k2) {
                union { unsigned int u; bf16 b2[2]; } tt;
                tt.b2[0] = __float2bfloat16(xr[2 * k2]);
                tt.b2[1] = __float2bfloat16(xr[2 * k2 + 1]);
                xw[k2] = tt.u;
            }
            *(uint4*)(xpb + (size_t)p * 16) = make_uint4(xw[0], xw[1], xw[2], xw[3]);
            *(uint4*)(xpb + (size_t)p * 16 + 8) = make_uint4(xw[4], xw[5], xw[6], xw[7]);
            bf16* hrow = hp + (size_t)p * H;
            for (int hc = 0; hc < 16; ++hc) {
                unsigned int ow[4];
#pragma unroll
                for (int hh = 0; hh < 8; hh += 2) {
                    int h0 = hc * 8 + hh;
                    float a0 = bps[h0], a1 = bps[h0 + 1];
#pragma unroll
                    for (int k = 0; k < 16; ++k) {
                        a0 = fmaf(xr[k], Wps[k * 128 + h0], a0);
                        a1 = fmaf(xr[k], Wps[k * 128 + h0 + 1], a1);
                    }
                    union { unsigned int u; bf16 b2[2]; } tt;
                    tt.b2[0] = __float2bfloat16(a0);
                    tt.b2[1] = __float2bfloat16(a1);
                    ow[hh >> 1] = tt.u;
                }
                *(uint4*)(hrow + hc * 8) = make_uint4(ow[0], ow[1], ow[2], ow[3]);
            }
        }
    } else if (b < RB5) {
        int f32m = flags[0];
        int pb = b - RB4;
        bool first = pb < 8;
        size_t woff = first ? 0 : (size_t)HH;
        float* outp = first ? WpWl0 : WpWl1;
        int k = (first ? pb : pb - 8) * 2 + (t >> 7);
        int h = t & 127;
        float s = 0.f;
        for (int m = 0; m < H; ++m)
            s = fmaf(ldin(Wp, (size_t)k * H + m, f32m), ldin(Wl1, woff + (size_t)m * H + h, f32m), s);
        outp[k * H + h] = s;
    } else if (b < RB6) {
        int f32m = flags[0];
        int idx = (b - RB5) * 256 + t;
        if (idx < 13 * 128) {
            int v = idx >> 7, h = idx & 127;
            float s = 0.f;
            if (v == 12) {
                s = ldin(bl1, 2 * H + h, f32m) + ldin(bl1, 3 * H + h, f32m);
            } else {
                const void* A;
                size_t aoff = 0;
                const void* W;
                size_t woff;
                float add = 0.f;
                switch (v) {
                    case 0: A = Wlab; W = Wl1; woff = 2 * (size_t)HH; break;
                    case 1: A = blab; W = Wl1; woff = 2 * (size_t)HH; break;
                    case 2: A = Wdis; W = Wl1; woff = 3 * (size_t)HH; break;
                    case 3: A = Wdis; aoff = H; W = Wl1; woff = 3 * (size_t)HH; break;
                    case 4: A = bdis; W = Wl1; woff = 3 * (size_t)HH; break;
                    case 5: A = Wlab; W = Wr1; woff = 0; break;
                    case 6: A = blab; W = Wr1; woff = 0; add = ldin(bl1, h, f32m); break;
                    case 7: A = Wdis; W = Wr1; woff = (size_t)HH; break;
                    case 8: A = Wdis; aoff = H; W = Wr1; woff = (size_t)HH; break;
                    case 9: A = bdis; W = Wr1; woff = (size_t)HH; add = ldin(bl1, H + h, f32m); break;
                    case 10: A = bp; W = Wl1; woff = 0; break;
                    default: A = bp; W = Wl1; woff = (size_t)HH; break;
                }
                for (int m = 0; m < H; ++m)
                    s = fmaf(ldin(A, aoff + m, f32m), ldin(W, woff + (size_t)m * H + h, f32m), s);
                s += add;
            }
            vecs[v * 128 + h] = s;
        }
    } else {
        int f32m = flags[0];
        int idx = (b - RB6) * 256 + t;
        if (idx < HH) {
            int k = idx >> 7, n = idx & 127;
            float v = ldin(Wr1, (size_t)2 * HH + idx, f32m) + ldin(Wr1, (size_t)3 * HH + idx, f32m);
            w23bT1[(size_t)n * H + k] = __float2bfloat16(v);
        }
    }
}

#define SCAN_ELEMS 2048
__global__ void k_scan1(const int* __restrict__ in, int* __restrict__ out,
                        int* __restrict__ bsums, int n) {
    int t = threadIdx.x;
    int base = blockIdx.x * SCAN_ELEMS + t * 8;
    int v[8], tsum = 0;
#pragma unroll
    for (int j = 0; j < 8; ++j) {
        v[j] = (base + j < n) ? in[base + j] : 0;
        tsum += v[j];
    }
    __shared__ int sh[256];
    sh[t] = tsum;
    __syncthreads();
    for (int d = 1; d < 256; d <<= 1) {
        int x = (t >= d) ? sh[t - d] : 0;
        __syncthreads();
        sh[t] += x;
        __syncthreads();
    }
    int run = sh[t] - tsum;
    if (t == 255) bsums[blockIdx.x] = sh[255];
#pragma unroll
    for (int j = 0; j < 8; ++j) {
        if (base + j < n) out[base + j] = run;
        run += v[j];
    }
}

__global__ void k_scan2(int* __restrict__ bsums, int nb) {
    int t = threadIdx.x;
    int v = (t < nb) ? bsums[t] : 0;
    __shared__ int sh[256];
    sh[t] = v;
    __syncthreads();
    for (int d = 1; d < 256; d <<= 1) {
        int x = (t >= d) ? sh[t - d] : 0;
        __syncthreads();
        sh[t] += x;
        __syncthreads();
    }
    if (t < nb) bsums[t] = sh[t] - v;
}

__global__ void k_scan3(int* __restrict__ out, const int* __restrict__ bsums, int n) {
    int i = blockIdx.x * 256 + threadIdx.x;
    if (i < n) out[i] += bsums[i / SCAN_ELEMS];
}

// ---- fill (+ last block zeros bns: 8 segments) ----------------------------------------
// Patient-CSR destinations (lab<10000, dis<500) stored as u16 in nbrP: halves the
// scattered line count -> halves cross-XCD RFO + partial-writeback traffic.
__global__ void k_fill(const int* __restrict__ e1s, const int* __restrict__ e1d,
                       const int* __restrict__ e2s, const int* __restrict__ e2d,
                       const int* __restrict__ off, const unsigned char* __restrict__ r1s,
                       const unsigned char* __restrict__ r2s,
                       const unsigned char* __restrict__ labBase,
                       const unsigned char* __restrict__ disBase,
                       const unsigned int* __restrict__ labHist,
                       const unsigned int* __restrict__ disHist, int* __restrict__ nbr,
                       unsigned short* __restrict__ nbrP, float* __restrict__ bns) {
    __shared__ unsigned int slot[NL];
    int b = blockIdx.x, t = threadIdx.x;
    if (b < CNT_BLOCKS) {
        int e = b * 256 + t;
        if (e < E1) {
            int ss = e1s[e];
            int c = e / CHP;
            int pos = off[NL + ND + ss] + (int)labBase[(size_t)c * NP + ss] + (int)r1s[e] - EP;
            nbrP[pos] = (unsigned short)e1d[e];
        } else if (e < E1 + E2) {
            int i = e - E1;
            int ss = e2s[i];
            int c = i / CHP;
            int pos = off[NL + ND + NP + ss] + (int)disBase[(size_t)c * NP + ss] + (int)r2s[i] - EP;
            nbrP[pos] = (unsigned short)e2d[i];
        }
    } else if (b < CNT_BLOCKS + LABHB) {
        int c = b - CNT_BLOCKS;
        for (int i = t; i < NL; i += 256)
            slot[i] = (unsigned int)off[i] + labHist[(size_t)c * NL + i];
        __syncthreads();
        int e0 = c * CHUNK, ee = min(E1, e0 + CHUNK);
        for (int e = e0 + t; e < ee; e += 256) {
            unsigned int pos = atomicAdd(&slot[e1d[e]], 1u);
            nbr[pos] = e1s[e];
        }
    } else if (b < CNT_BLOCKS + LABHB + DISHB) {
        int c = b - CNT_BLOCKS - LABHB;
        for (int i = t; i < ND; i += 256)
            slot[i] = (unsigned int)off[NL + i] + disHist[(size_t)c * ND + i];
        __syncthreads();
        int e0 = c * CHUNK, ee = min(E2, e0 + CHUNK);
        for (int e = e0 + t; e < ee; e += 256) {
            unsigned int pos = atomicAdd(&slot[e2d[e]], 1u);
            nbr[pos] = e2s[e];
        }
    } else {
        for (int i = t; i < 8 * H; i += 256) bns[i] = 0.f;
    }
}

// ---------------- L1 stage1: gather 16-dim mean of x_p per lab/dis row ------------------
// Lane-per-neighbor from the bf16 copy xpb: 32 B per neighbor row (half the f32 bytes),
// 64-128 gathers in flight per wave. Block LDS reduce at the end.
__global__ void k_stage1_L1(const bf16* __restrict__ xpb, const int* __restrict__ off,
                            const int* __restrict__ cnt, const int* __restrict__ nbr,
                            float* __restrict__ mxp) {
    __shared__ float red[4][64][16];  // 16 KB
    int t = threadIdx.x;
    int w = t >> 6, lane = t & 63;
    int row = blockIdx.x * 4 + w;
    float acc[16];
#pragma unroll
    for (int d = 0; d < 16; ++d) acc[d] = 0.f;
    if (row < NROW) {
        int s0 = off[row], c = cnt[row];
        const int* nb = nbr + s0;
        int j = lane;
        for (; j + 64 < c; j += 128) {
            int p0 = nb[j], p1 = nb[j + 64];
            const uint4* r0 = (const uint4*)(xpb + (size_t)p0 * 16);
            const uint4* r1 = (const uint4*)(xpb + (size_t)p1 * 16);
            uint4 u0 = r0[0], u1 = r0[1];
            uint4 v0 = r1[0], v1 = r1[1];
            bfacc2(acc[0], acc[1], u0.x);   bfacc2(acc[2], acc[3], u0.y);
            bfacc2(acc[4], acc[5], u0.z);   bfacc2(acc[6], acc[7], u0.w);
            bfacc2(acc[8], acc[9], u1.x);   bfacc2(acc[10], acc[11], u1.y);
            bfacc2(acc[12], acc[13], u1.z); bfacc2(acc[14], acc[15], u1.w);
            bfacc2(acc[0], acc[1], v0.x);   bfacc2(acc[2], acc[3], v0.y);
            bfacc2(acc[4], acc[5], v0.z);   bfacc2(acc[6], acc[7], v0.w);
            bfacc2(acc[8], acc[9], v1.x);   bfacc2(acc[10], acc[11], v1.y);
            bfacc2(acc[12], acc[13], v1.z); bfacc2(acc[14], acc[15], v1.w);
        }
        if (j < c) {
            const uint4* r0 = (const uint4*)(xpb + (size_t)nb[j] * 16);
            uint4 u0 = r0[0], u1 = r0[1];
            bfacc2(acc[0], acc[1], u0.x);   bfacc2(acc[2], acc[3], u0.y);
            bfacc2(acc[4], acc[5], u0.z);   bfacc2(acc[6], acc[7], u0.w);
            bfacc2(acc[8], acc[9], u1.x);   bfacc2(acc[10], acc[11], u1.y);
            bfacc2(acc[12], acc[13], u1.z); bfacc2(acc[14], acc[15], u1.w);
        }
    }
#pragma unroll
    for (int d = 0; d < 16; ++d) red[w][lane][d] = acc[d];
    __syncthreads();
    if (t < 64) {
        int w2 = t >> 4, d = t & 15;
        int row2 = blockIdx.x * 4 + w2;
        if (row2 < NROW) {
            float s = 0.f;
#pragma unroll 8
            for (int l = 0; l < 64; ++l) s += red[w2][l][d];
            mxp[(size_t)row2 * 16 + d] = s / fmaxf((float)cnt[row2], 1.f);
        }
    }
}

// -------- L1 patmm: scalar gathers + MFMA | lab/dis affine | per-block stats ------------
#define LD1_BLOCKS ((NROW + 1) / 2)
#define HPAD 136
#define APAD 132
__global__ void k_patmm_L1(const bf16* __restrict__ hp, const void* __restrict__ xl,
                           const void* __restrict__ xd, const int* __restrict__ off,
                           const int* __restrict__ cnt, const unsigned short* __restrict__ nbrP,
                           const bf16* __restrict__ w23bT1, const float* __restrict__ vecs,
                           const float* __restrict__ WpWl0, const float* __restrict__ WpWl1,
                           const float* __restrict__ mxp, bf16* __restrict__ aggp,
                           float* __restrict__ bufL, float* __restrict__ bufD,
                           float* __restrict__ blocksums, const int* __restrict__ flags) {
    int t = threadIdx.x;
    int f32m = flags[0];
    if (blockIdx.x < PAT_BLOCKS) {
        __shared__ bf16 hpA[16][HPAD];
        __shared__ float accf[16][APAD];
        __shared__ float svec[6][128];
        __shared__ float s_mxl[16], s_onL[16], s_d0[16], s_d1[16], s_onD[16];
        int w = t >> 6, lane = t & 63;
        int p0 = blockIdx.x * 16;
        {
            const unsigned int* hpu = (const unsigned int*)(hp + (size_t)p0 * H);
            for (int i = t; i < 16 * 64; i += 256) {
                int r = i >> 6, c = i & 63;
                *(unsigned int*)&hpA[r][2 * c] = hpu[(size_t)r * 64 + c];
            }
        }
        {
            const int map[6] = {0, 1, 2, 3, 4, 12};
            for (int i = t; i < 6 * 128; i += 256)
                svec[i >> 7][i & 127] = vecs[map[i >> 7] * 128 + (i & 127)];
        }
        {
            int g = t >> 4, sl = t & 15;
            int p = p0 + g;
            int s1 = off[NL + ND + p] - EP, c1 = cnt[NL + ND + p];
            float a = 0.f;
            for (int j = sl; j < c1; j += 16) a += ldin(xl, nbrP[s1 + j], f32m);
            a += __shfl_xor(a, 1);
            a += __shfl_xor(a, 2);
            a += __shfl_xor(a, 4);
            a += __shfl_xor(a, 8);
            int s2 = off[NL + ND + NP + p] - EP, c2 = cnt[NL + ND + NP + p];
            float d0 = 0.f, d1 = 0.f;
            for (int j = sl; j < c2; j += 16) {
                int q = nbrP[s2 + j];
                d0 += ldin(xd, (size_t)2 * q, f32m);
                d1 += ldin(xd, (size_t)2 * q + 1, f32m);
            }
            d0 += __shfl_xor(d0, 1); d0 += __shfl_xor(d0, 2);
            d0 += __shfl_xor(d0, 4); d0 += __shfl_xor(d0, 8);
            d1 += __shfl_xor(d1, 1); d1 += __shfl_xor(d1, 2);
            d1 += __shfl_xor(d1, 4); d1 += __shfl_xor(d1, 8);
            if (sl == 0) {
                s_mxl[g] = a / fmaxf((float)c1, 1.f);
                s_onL[g] = (c1 > 0) ? 1.f : 0.f;
                s_d0[g] = d0 / fmaxf((float)c2, 1.f);
                s_d1[g] = d1 / fmaxf((float)c2, 1.f);
                s_onD[g] = (c2 > 0) ? 1.f : 0.f;
            }
        }
        __syncthreads();
        {
            int m = lane & 15, kg = lane >> 4;
            bf16x8 afr[4];
#pragma unroll
            for (int ks = 0; ks < 4; ++ks)
                afr[ks] = *(const bf16x8*)&hpA[m][ks * 32 + kg * 8];
            int n0 = w * 32;
#pragma unroll
            for (int tt = 0; tt < 2; ++tt) {
                int nc = n0 + tt * 16 + m;
                f32x4 acc = {0.f, 0.f, 0.f, 0.f};
#pragma unroll
                for (int ks = 0; ks < 4; ++ks) {
                    bf16x8 bfr = *(const bf16x8*)&w23bT1[(size_t)nc * H + ks * 32 + kg * 8];
                    acc = __builtin_amdgcn_mfma_f32_16x16x32_bf16(afr[ks], bfr, acc, 0, 0, 0);
                }
#pragma unroll
                for (int rg = 0; rg < 4; ++rg)
                    accf[kg * 4 + rg][nc] = acc[rg];
            }
        }
        __syncthreads();
        for (int i = t; i < 16 * 64; i += 256) {
            int r = i >> 6, cc = (i & 63) * 2;
            float l0 = s_onL[r] * fmaf(s_mxl[r], svec[0][cc], svec[1][cc]);
            float l1 = s_onL[r] * fmaf(s_mxl[r], svec[0][cc + 1], svec[1][cc + 1]);
            float q0 = s_onD[r] * (s_d0[r] * svec[2][cc] + s_d1[r] * svec[3][cc] + svec[4][cc]);
            float q1 = s_onD[r] * (s_d0[r] * svec[2][cc + 1] + s_d1[r] * svec[3][cc + 1] + svec[4][cc + 1]);
            float v0 = accf[r][cc] + l0 + q0 + svec[5][cc];
            float v1 = accf[r][cc + 1] + l1 + q1 + svec[5][cc + 1];
            accf[r][cc] = v0;
            accf[r][cc + 1] = v1;
            st_bf2(aggp + (size_t)(p0 + r) * H + cc, make_float2(v0, v1));
        }
        __syncthreads();
        if (t < 128) {
            float s = 0.f, q = 0.f;
#pragma unroll
            for (int r = 0; r < 16; ++r) {
                float v = accf[r][t];
                s += v;
                q = fmaf(v, v, q);
            }
            blocksums[(size_t)blockIdx.x * 256 + t] = s;
            blocksums[(size_t)blockIdx.x * 256 + 128 + t] = q;
        }
    } else {
        int bb = blockIdx.x - PAT_BLOCKS;
        int rr = bb * 2 + (t >> 7);
        int h = t & 127;
        if (rr >= NROW) return;
        if (rr < NL) {
            float acc = vecs[6 * 128 + h] + ldin(xl, rr, f32m) * vecs[5 * 128 + h];
            if (cnt[rr] > 0) {
                float s = vecs[10 * 128 + h];
                const float* mx = mxp + (size_t)rr * 16;
#pragma unroll
                for (int k = 0; k < 16; ++k) s = fmaf(mx[k], WpWl0[k * H + h], s);
                acc += s;
            }
            bufL[(size_t)rr * H + h] = acc;
        } else {
            int rd = rr - NL;
            float acc = vecs[9 * 128 + h] + ldin(xd, (size_t)2 * rd, f32m) * vecs[7 * 128 + h] +
                        ldin(xd, (size_t)2 * rd + 1, f32m) * vecs[8 * 128 + h];
            if (cnt[rr] > 0) {
                float s = vecs[11 * 128 + h];
                const float* mx = mxp + (size_t)rr * 16;
#pragma unroll
                for (int k = 0; k < 16; ++k) s = fmaf(mx[k], WpWl1[k * H + h], s);
                acc += s;
            }
            bufD[(size_t)rd * H + h] = acc;
        }
    }
}

// -------- bnred: patient stats from blocksums (+ lab/dis stats when grid>64) -----------
__global__ void k_bnred(const float* __restrict__ blocksums, const float* __restrict__ bufL,
                        const float* __restrict__ bufD, float* __restrict__ sums) {
    int b = blockIdx.x, t = threadIdx.x;
    if (b < 64) {
        float acc = 0.f;
        for (int r = b; r < PAT_BLOCKS; r += 64) acc += blocksums[(size_t)r * 256 + t];
        atomicAdd(&sums[t], acc);
        return;
    }
    int h = t & 127;
    int sub = t >> 7;
    float s = 0.f, s2 = 0.f;
    float* sm;
    if (b < 320) {
        int bid = b - 64;
        for (int i = bid * 2 + sub; i < NL; i += 512) {
            float v = bufL[(size_t)i * H + h];
            s += v;
            s2 = fmaf(v, v, s2);
        }
        sm = sums + 2 * H;
    } else {
        int bid = b - 320;
        for (int i = bid * 2 + sub; i < ND; i += 128) {
            float v = bufD[(size_t)i * H + h];
            s += v;
            s2 = fmaf(v, v, s2);
        }
        sm = sums + 4 * H;
    }
    __shared__ float ls[256], ls2[256];
    ls[t] = s;
    ls2[t] = s2;
    __syncthreads();
    if (sub == 0) {
        atomicAdd(&sm[h], s + ls[128 + h]);
        atomicAdd(&sm[H + h], s2 + ls2[128 + h]);
    }
}

// ---- L2 stage1: mm_small (L1 lab/dis BN inline) + prep23 + head-W1 precompute ----------
#define S2_MM 1313
#define S2_PREP 64
#define S2_TOTAL (S2_MM + S2_PREP)
__global__ void k_stage1_L2(const float* __restrict__ bufL, const float* __restrict__ bufD,
                            const float* __restrict__ bns, const void* __restrict__ bng1,
                            const void* __restrict__ bnb1, const void* __restrict__ Wl,
                            bf16* __restrict__ tlp, bf16* __restrict__ tdp,
                            const void* __restrict__ Wr, const void* __restrict__ bl,
                            bf16* __restrict__ w23bT, float* __restrict__ b23,
                            const void* __restrict__ W1in, bf16* __restrict__ w1T,
                            const int* __restrict__ flags) {
    __shared__ float smm[8][H];
    int b = blockIdx.x, t = threadIdx.x;
    int f32m = flags[0];
    if (b < S2_MM) {
        int bb = b;
        bool lab = bb < 1250;
        const float* buf = lab ? bufL : bufD;
        int N = lab ? NL : ND;
        float invN = lab ? 1.f / NL : 1.f / ND;
        int so = lab ? 2 * H : 4 * H;
        int go = lab ? H : 2 * H;
        bf16* outp = lab ? tlp : tdp;
        size_t woff = lab ? (size_t)2 * HH : (size_t)3 * HH;
        int r0 = (lab ? bb : bb - 1250) * 8;
        int h = t & 127, half = t >> 7;
        float m = bns[so + h] * invN;
        float v = fmaf(-m, m, bns[so + H + h] * invN);
        float sc = rsqrtf(v + 1e-5f) * ldin(bng1, go + h, f32m);
        float be = ldin(bnb1, go + h, f32m);
        for (int r = half; r < 8; r += 2) {
            int ri = r0 + r;
            float x = (ri < N) ? buf[(size_t)ri * H + h] : 0.f;
            smm[r][h] = (ri < N) ? fmaxf(fmaf(x - m, sc, be), 0.f) : 0.f;
        }
        __syncthreads();
        int rb = half * 4;
        float a0 = 0.f, a1 = 0.f, a2 = 0.f, a3 = 0.f;
        for (int k = 0; k < H; ++k) {
            float wv = ldin(Wl, woff + (size_t)k * H + h, f32m);
            a0 = fmaf(smm[rb + 0][k], wv, a0);
            a1 = fmaf(smm[rb + 1][k], wv, a1);
            a2 = fmaf(smm[rb + 2][k], wv, a2);
            a3 = fmaf(smm[rb + 3][k], wv, a3);
        }
        float acc[4] = {a0, a1, a2, a3};
#pragma unroll
        for (int r = 0; r < 4; ++r)
            if (r0 + rb + r < N)
                outp[(size_t)(r0 + rb + r) * H + h] = __float2bfloat16(acc[r]);
    } else {
        int pb = b - S2_MM;
        int idx = pb * 256 + t;
        if (idx < HH) {
            int k = idx >> 7, n = idx & 127;
            float v = ldin(Wr, (size_t)2 * HH + idx, f32m) + ldin(Wr, (size_t)3 * HH + idx, f32m);
            w23bT[(size_t)n * H + k] = __float2bfloat16(v);
        }
        if (idx < H)
            b23[idx] = ldin(bl, (size_t)2 * H + idx, f32m) + ldin(bl, (size_t)3 * H + idx, f32m);
        if (idx < 64 * H) {  // head FC1 weight, transposed to [n][k] bf16 for MFMA B-operand
            int n = idx >> 7, k = idx & 127;
            w1T[idx] = __float2bfloat16(ldin(W1in, (size_t)k * 64 + n, f32m));
        }
    }
}

// -------- L2 patmm: in-place aggp update (L1 pat BN inline) + per-block stats -----------
// Gather: QUARTER-wave (16 lanes) per patient row, 16 B (8 cols) per lane; u16 CSR
// indices (nbrP). SW-pipelined index prefetch. aggp staging read non-temporal.
__global__ void k_patmm_L2(bf16* __restrict__ aggp, const bf16* __restrict__ tlp,
                           const bf16* __restrict__ tdp, const int* __restrict__ off,
                           const int* __restrict__ cnt, const unsigned short* __restrict__ nbrP,
                           const bf16* __restrict__ w23bT, const float* __restrict__ b23,
                           const float* __restrict__ bns, const void* __restrict__ bng1,
                           const void* __restrict__ bnb1, float* __restrict__ blocksums,
                           const int* __restrict__ flags) {
    __shared__ bf16 hpA[16][HPAD];
    __shared__ __align__(16) float accf[16][APAD];
    int t = threadIdx.x;
    int f32m = flags[0];
    int w = t >> 6, lane = t & 63;
    int p0 = blockIdx.x * 16;
    {
        int cc = (t & 63) * 2;
        const float invN = 1.f / NP;
        float m0 = bns[cc] * invN, m1 = bns[cc + 1] * invN;
        float v0 = fmaf(-m0, m0, bns[128 + cc] * invN);
        float v1 = fmaf(-m1, m1, bns[128 + cc + 1] * invN);
        float sc0 = rsqrtf(v0 + 1e-5f) * ldin(bng1, cc, f32m);
        float sc1 = rsqrtf(v1 + 1e-5f) * ldin(bng1, cc + 1, f32m);
        float be0 = ldin(bnb1, cc, f32m), be1 = ldin(bnb1, cc + 1, f32m);
        for (int i = t; i < 16 * 64; i += 256) {
            int r = i >> 6;
            float2 v = ld_bf2_nt(aggp + (size_t)(p0 + r) * H + cc);
            st_bf2(&hpA[r][cc], make_float2(fmaxf(fmaf(v.x - m0, sc0, be0), 0.f),
                                            fmaxf(fmaf(v.y - m1, sc1, be1), 0.f)));
        }
    }
    {
        const int* off1 = off + NL + ND;
        const int* cnt1 = cnt + NL + ND;
        const int* off2 = off + NL + ND + NP;
        const int* cnt2 = cnt + NL + ND + NP;
        int qw = lane >> 4, ql = lane & 15;  // 16 quarter-waves; each owns ONE patient
        int p = p0 + w * 4 + qw;
        int cb = ql * 8;                     // this lane's 8 columns (16 B)
        float4 bb0 = *(const float4*)(b23 + cb);
        float4 bb1 = *(const float4*)(b23 + cb + 4);
        int s1 = off1[p] - EP, c1 = cnt1[p];
        const unsigned short* nb1 = nbrP + s1;
        float a0 = 0.f, a1 = 0.f, a2 = 0.f, a3 = 0.f, a4 = 0.f, a5 = 0.f, a6 = 0.f, a7 = 0.f;
        float g0 = 0.f, g1 = 0.f, g2 = 0.f, g3 = 0.f, g4 = 0.f, g5 = 0.f, g6 = 0.f, g7 = 0.f;
        int j = 0;
        int i0, i1, i2, i3;
        if (c1 >= 4) { i0 = nb1[0]; i1 = nb1[1]; i2 = nb1[2]; i3 = nb1[3]; }
        for (; j + 8 <= c1; j += 4) {
            uint4 v0 = *(const uint4*)(tlp + (size_t)i0 * H + cb);
            uint4 v1 = *(const uint4*)(tlp + (size_t)i1 * H + cb);
            uint4 v2 = *(const uint4*)(tlp + (size_t)i2 * H + cb);
            uint4 v3 = *(const uint4*)(tlp + (size_t)i3 * H + cb);
            int n0 = nb1[j + 4], n1 = nb1[j + 5], n2 = nb1[j + 6], n3 = nb1[j + 7];
            bfacc2(a0, a1, v0.x); bfacc2(a2, a3, v0.y); bfacc2(a4, a5, v0.z); bfacc2(a6, a7, v0.w);
            bfacc2(g0, g1, v1.x); bfacc2(g2, g3, v1.y); bfacc2(g4, g5, v1.z); bfacc2(g6, g7, v1.w);
            bfacc2(a0, a1, v2.x); bfacc2(a2, a3, v2.y); bfacc2(a4, a5, v2.z); bfacc2(a6, a7, v2.w);
            bfacc2(g0, g1, v3.x); bfacc2(g2, g3, v3.y); bfacc2(g4, g5, v3.z); bfacc2(g6, g7, v3.w);
            i0 = n0; i1 = n1; i2 = n2; i3 = n3;
        }
        if (j + 4 <= c1) {
            uint4 v0 = *(const uint4*)(tlp + (size_t)i0 * H + cb);
            uint4 v1 = *(const uint4*)(tlp + (size_t)i1 * H + cb);
            uint4 v2 = *(const uint4*)(tlp + (size_t)i2 * H + cb);
            uint4 v3 = *(const uint4*)(tlp + (size_t)i3 * H + cb);
            bfacc2(a0, a1, v0.x); bfacc2(a2, a3, v0.y); bfacc2(a4, a5, v0.z); bfacc2(a6, a7, v0.w);
            bfacc2(g0, g1, v1.x); bfacc2(g2, g3, v1.y); bfacc2(g4, g5, v1.z); bfacc2(g6, g7, v1.w);
            bfacc2(a0, a1, v2.x); bfacc2(a2, a3, v2.y); bfacc2(a4, a5, v2.z); bfacc2(a6, a7, v2.w);
            bfacc2(g0, g1, v3.x); bfacc2(g2, g3, v3.y); bfacc2(g4, g5, v3.z); bfacc2(g6, g7, v3.w);
            j += 4;
        }
        for (; j < c1; ++j) {
            uint4 v = *(const uint4*)(tlp + (size_t)nb1[j] * H + cb);
            bfacc2(a0, a1, v.x); bfacc2(a2, a3, v.y); bfacc2(a4, a5, v.z); bfacc2(a6, a7, v.w);
        }
        a0 += g0; a1 += g1; a2 += g2; a3 += g3;
        a4 += g4; a5 += g5; a6 += g6; a7 += g7;
        int s2 = off2[p] - EP, c2 = cnt2[p];
        const unsigned short* nb2 = nbrP + s2;
        float d0 = 0.f, d1 = 0.f, d2 = 0.f, d3 = 0.f, d4 = 0.f, d5 = 0.f, d6 = 0.f, d7 = 0.f;
        float e0 = 0.f, e1 = 0.f, e2 = 0.f, e3 = 0.f, e4 = 0.f, e5 = 0.f, e6 = 0.f, e7 = 0.f;
        j = 0;
        int k0, k1;
        if (c2 >= 2) { k0 = nb2[0]; k1 = nb2[1]; }
        for (; j + 4 <= c2; j += 2) {
            uint4 v0 = *(const uint4*)(tdp + (size_t)k0 * H + cb);
            uint4 v1 = *(const uint4*)(tdp + (size_t)k1 * H + cb);
            int n0 = nb2[j + 2], n1 = nb2[j + 3];
            bfacc2(d0, d1, v0.x); bfacc2(d2, d3, v0.y); bfacc2(d4, d5, v0.z); bfacc2(d6, d7, v0.w);
            bfacc2(e0, e1, v1.x); bfacc2(e2, e3, v1.y); bfacc2(e4, e5, v1.z); bfacc2(e6, e7, v1.w);
            k0 = n0; k1 = n1;
        }
        if (j + 2 <= c2) {
            uint4 v0 = *(const uint4*)(tdp + (size_t)k0 * H + cb);
            uint4 v1 = *(const uint4*)(tdp + (size_t)k1 * H + cb);
            bfacc2(d0, d1, v0.x); bfacc2(d2, d3, v0.y); bfacc2(d4, d5, v0.z); bfacc2(d6, d7, v0.w);
            bfacc2(e0, e1, v1.x); bfacc2(e2, e3, v1.y); bfacc2(e4, e5, v1.z); bfacc2(e6, e7, v1.w);
            j += 2;
        }
        if (j < c2) {
            uint4 v = *(const uint4*)(tdp + (size_t)nb2[j] * H + cb);
            bfacc2(d0, d1, v.x); bfacc2(d2, d3, v.y); bfacc2(d4, d5, v.z); bfacc2(d6, d7, v.w);
        }
        d0 += e0; d1 += e1; d2 += e2; d3 += e3;
        d4 += e4; d5 += e5; d6 += e6; d7 += e7;
        float i1f = 1.f / fmaxf((float)c1, 1.f), i2f = 1.f / fmaxf((float)c2, 1.f);
        float4 r0v, r1v;
        r0v.x = a0 * i1f + d0 * i2f + bb0.x;
        r0v.y = a1 * i1f + d1 * i2f + bb0.y;
        r0v.z = a2 * i1f + d2 * i2f + bb0.z;
        r0v.w = a3 * i1f + d3 * i2f + bb0.w;
        r1v.x = a4 * i1f + d4 * i2f + bb1.x;
        r1v.y = a5 * i1f + d5 * i2f + bb1.y;
        r1v.z = a6 * i1f + d6 * i2f + bb1.z;
        r1v.w = a7 * i1f + d7 * i2f + bb1.w;
        *(float4*)&accf[w * 4 + qw][cb] = r0v;
        *(float4*)&accf[w * 4 + qw][cb + 4] = r1v;
    }
    __syncthreads();
    {
        int m = lane & 15, kg = lane >> 4;
        bf16x8 afr[4];
#pragma unroll
        for (int ks = 0; ks < 4; ++ks)
            afr[ks] = *(const bf16x8*)&hpA[m][ks * 32 + kg * 8];
        int n0 = w * 32;
#pragma unroll
        for (int tt = 0; tt < 2; ++tt) {
            int nc = n0 + tt * 16 + m;
            f32x4 acc = {0.f, 0.f, 0.f, 0.f};
#pragma unroll
            for (int ks = 0; ks < 4; ++ks) {
                bf16x8 bfr = *(const bf16x8*)&w23bT[(size_t)nc * H + ks * 32 + kg * 8];
                acc = __builtin_amdgcn_mfma_f32_16x16x32_bf16(afr[ks], bfr, acc, 0, 0, 0);
            }
#pragma unroll
            for (int rg = 0; rg < 4; ++rg)
                accf[kg * 4 + rg][nc] += acc[rg];
        }
    }
    __syncthreads();
    for (int i = t; i < 16 * 64; i += 256) {
        int r = i >> 6, cc = (i & 63) * 2;
        st_bf2(aggp + (size_t)(p0 + r) * H + cc, make_float2(accf[r][cc], accf[r][cc + 1]));
    }
    if (t < 128) {
        float s = 0.f, q = 0.f;
#pragma unroll
        for (int r = 0; r < 16; ++r) {
            float v = accf[r][t];
            s += v;
            q = fmaf(v, v, q);
        }
        blocksums[(size_t)blockIdx.x * 256 + t] = s;
        blocksums[(size_t)blockIdx.x * 256 + 128 + t] = q;
    }
}

// ---------------- head: fused L2 patient BN+ReLU -> MFMA FC1 -> FC2 -> log_softmax ------
__global__ void k_head(const bf16* __restrict__ aggp, const float* __restrict__ sums,
                       const void* __restrict__ bng, const void* __restrict__ bnb,
                       const bf16* __restrict__ w1T, const void* __restrict__ b1,
                       const void* __restrict__ W2, const void* __restrict__ b2f,
                       void* __restrict__ out, const int* __restrict__ flags) {
    int f32m = flags[0];
    __shared__ bf16 hpA[16][HPAD];
    __shared__ float h1s[16][68];
    __shared__ float lgs[16][16];
    __shared__ float W2s[64 * NOUT];
    __shared__ float b1s[64], b2s[NOUT];
    int t = threadIdx.x;
    int w = t >> 6, lane = t & 63;
    for (int i = t; i < 64 * NOUT; i += 256) W2s[i] = ldin(W2, i, f32m);
    if (t < 64) b1s[t] = ldin(b1, t, f32m);
    else if (t >= 64 && t < 64 + NOUT) b2s[t - 64] = ldin(b2f, t - 64, f32m);
    int p0 = blockIdx.x * 16;
    {
        int cc = (t & 63) * 2;
        const float invN = 1.f / NP;
        float m0 = sums[cc] * invN, m1 = sums[cc + 1] * invN;
        float v0 = fmaf(-m0, m0, sums[128 + cc] * invN);
        float v1 = fmaf(-m1, m1, sums[128 + cc + 1] * invN);
        float sc0 = rsqrtf(v0 + 1e-5f) * ldin(bng, cc, f32m);
        float sc1 = rsqrtf(v1 + 1e-5f) * ldin(bng, cc + 1, f32m);
        float be0 = ldin(bnb, cc, f32m), be1 = ldin(bnb, cc + 1, f32m);
        for (int i = t; i < 16 * 64; i += 256) {
            int r = i >> 6;
            float2 v = ld_bf2_nt(aggp + (size_t)(p0 + r) * H + cc);
            st_bf2(&hpA[r][cc], make_float2(fmaxf(fmaf(v.x - m0, sc0, be0), 0.f),
                                            fmaxf(fmaf(v.y - m1, sc1, be1), 0.f)));
        }
    }
    __syncthreads();
    {
        // MFMA FC1: wave w computes output cols [w*16, w*16+16); K=128 over 4 ksteps.
        int m = lane & 15, kg = lane >> 4;
        bf16x8 afr[4];
#pragma unroll
        for (int ks = 0; ks < 4; ++ks)
            afr[ks] = *(const bf16x8*)&hpA[m][ks * 32 + kg * 8];
        int nc = w * 16 + m;
        f32x4 acc = {0.f, 0.f, 0.f, 0.f};
#pragma unroll
        for (int ks = 0; ks < 4; ++ks) {
            bf16x8 bfr = *(const bf16x8*)&w1T[(size_t)nc * H + ks * 32 + kg * 8];
            acc = __builtin_amdgcn_mfma_f32_16x16x32_bf16(afr[ks], bfr, acc, 0, 0, 0);
        }
        float bv = b1s[nc];
#pragma unroll
        for (int rg = 0; rg < 4; ++rg)
            h1s[kg * 4 + rg][nc] = fmaxf(acc[rg] + bv, 0.f);
    }
    __syncthreads();
    int pat = lane >> 4, oidx = lane & 15;
    int prow = 4 * w + pat;
    float lg = 0.f;
    if (oidx < NOUT) {
        lg = b2s[oidx];
        const float* hh = h1s[prow];
#pragma unroll 8
        for (int k = 0; k < 64; ++k) lg = fmaf(hh[k], W2s[k * NOUT + oidx], lg);
        lgs[prow][oidx] = lg;
    }
    __syncthreads();
    if (oidx < NOUT) {
        float m = -1e30f;
#pragma unroll
        for (int k = 0; k < NOUT; ++k) m = fmaxf(m, lgs[prow][k]);
        float s = 0.f;
#pragma unroll
        for (int k = 0; k < NOUT; ++k) s += __expf(lgs[prow][k] - m);
        float r = lg - m - __logf(s);
        if (f32m)
            ((float*)out)[(size_t)(p0 + prow) * NOUT + oidx] = r;
        else
            ((bf16*)out)[(size_t)(p0 + prow) * NOUT + oidx] = __float2bfloat16(r);
    }
}

extern "C" void kernel_launch(void* const* d_in, const int* in_sizes, int n_in, void* d_out,
                              int out_size, void* d_ws, size_t ws_size, hipStream_t stream) {
    const int* e1s = (const int*)d_in[23];
    const int* e1d = (const int*)d_in[24];
    const int* e2s = (const int*)d_in[25];
    const int* e2d = (const int*)d_in[26];

    char* wsb = (char*)d_ws;
    size_t o = 0;
    auto af = [&](size_t nwords) { void* p = wsb + o * 4; o += nwords; return p; };
    int* flags = (int*)af(16);
    bf16* w23bT = (bf16*)af(HH / 2);
    bf16* w23bT1 = (bf16*)af(HH / 2);
    bf16* w1T = (bf16*)af(64 * H / 2);
    float* b23 = (float*)af(H);
    float* bns = (float*)af(8 * H);
    int* bsums = (int*)af(256);
    float* WpWl0 = (float*)af(16 * H);
    float* WpWl1 = (float*)af(16 * H);
    float* vecs = (float*)af(13 * 128);
    int* cnt = (int*)af(NCNT);
    int* off = (int*)af(NCNT);
    int* nbr = (int*)af(EP);                      // lab/dis CSR (u32 patient ids)
    unsigned short* nbrP = (unsigned short*)af(EP / 2);  // patient CSR (u16 lab/dis ids)
    bf16* hp = (bf16*)af((size_t)NP * H / 2);
    bf16* xpb = (bf16*)af((size_t)NP * 16 / 2);
    size_t arena = o;
    unsigned char* r1s = (unsigned char*)af(E1 / 4);
    unsigned char* r2s = (unsigned char*)af(E2 / 4);
    unsigned int* labHistP = (unsigned int*)af((size_t)NCH1 * NPW);
    unsigned int* disHistP = (unsigned int*)af((size_t)NCH2 * NPW);
    unsigned int* labHist = (unsigned int*)af((size_t)LABHB * NL);
    unsigned int* disHist = (unsigned int*)af((size_t)DISHB * ND);
    size_t endA = o;
    o = arena;
    float* bufL = (float*)af((size_t)NL * H);
    float* bufD = (float*)af((size_t)ND * H);
    bf16* tlp = (bf16*)af((size_t)NL * H / 2);
    bf16* tdp = (bf16*)af((size_t)ND * H / 2);
    bf16* aggp = (bf16*)af((size_t)NP * H / 2);
    float* mxp = (float*)af((size_t)NROW * 16);
    float* blocksums = (float*)af((size_t)PAT_BLOCKS * 256);
    size_t endB = o;
    o = endA > endB ? endA : endB;
    (void)ws_size;

    k_hist<<<HB3 + 1, 1024, 0, stream>>>(e1s, e1d, e2s, e2d, labHistP, disHistP, r1s, r2s,
                                         labHist, disHist, (const unsigned short*)d_in[0],
                                         flags);
    k_reduce<<<RB7, 256, 0, stream>>>(labHist, disHist, labHistP, disHistP, cnt, d_in[0],
                                      d_in[3], d_in[4], d_in[5], d_in[6], d_in[7], d_in[8],
                                      d_in[9], d_in[10], d_in[11], hp, WpWl0, WpWl1, vecs,
                                      w23bT1, xpb, flags);
    int nb = (NCNT + SCAN_ELEMS - 1) / SCAN_ELEMS;
    k_scan1<<<nb, 256, 0, stream>>>(cnt, off, bsums, NCNT);
    k_scan2<<<1, 256, 0, stream>>>(bsums, nb);
    k_scan3<<<(NCNT + 255) / 256, 256, 0, stream>>>(off, bsums, NCNT);
    k_fill<<<CNT_BLOCKS + LABHB + DISHB + 1, 256, 0, stream>>>(
        e1s, e1d, e2s, e2d, off, r1s, r2s, (const unsigned char*)labHistP,
        (const unsigned char*)disHistP, labHist, disHist, nbr, nbrP, bns);

    // ---- layer 1 (algebraically collapsed) ----
    k_stage1_L1<<<(NROW + 3) / 4, 256, 0, stream>>>(xpb, off, cnt, nbr, mxp);
    k_patmm_L1<<<PAT_BLOCKS + LD1_BLOCKS, 256, 0, stream>>>(hp, d_in[1], d_in[2], off, cnt,
                                                            nbrP, w23bT1, vecs, WpWl0, WpWl1,
                                                            mxp, aggp, bufL, bufD, blocksums,
                                                            flags);
    k_bnred<<<384, 256, 0, stream>>>(blocksums, bufL, bufD, bns);

    // ---- layer 2: all BN applications fused into consumers ----
    k_stage1_L2<<<S2_TOTAL, 256, 0, stream>>>(bufL, bufD, bns, d_in[15], d_in[16], d_in[12],
                                              tlp, tdp, d_in[14], d_in[13], w23bT, b23,
                                              d_in[19], w1T, flags);
    k_patmm_L2<<<PAT_BLOCKS, 256, 0, stream>>>(aggp, tlp, tdp, off, cnt, nbrP, w23bT, b23, bns,
                                               d_in[15], d_in[16], blocksums, flags);
    k_bnred<<<64, 256, 0, stream>>>(blocksums, bufL, bufD, bns + 6 * H);
    k_head<<<NP / 16, 256, 0, stream>>>(aggp, bns + 6 * H, d_in[17], d_in[18], w1T,
                                        d_in[20], d_in[21], d_in[22], d_out, flags);
}